// Round 1
// baseline (7278.759 us; speedup 1.0000x reference)
//
#include <hip/hip_runtime.h>

// ---------------------------------------------------------------------------
// FlatSquare7x7NNUEv4: 16 4x4 patches -> 3 shared conv stacks -> quantized sum
// -> exact-integer value MLP.  Round 1: fp32 baseline (correctness-first).
// ---------------------------------------------------------------------------

#define TS 8                      // chunk-samples per workgroup tile

// chunk tables: (y0, x0, rot_k, transpose); groups: [0..3]=g0, [4..11]=g1, [12..15]=g2
static __device__ __constant__ int CH_Y0[16] = {0,0,3,3, 0,1,3,2, 1,0,2,3, 1,1,2,2};
static __device__ __constant__ int CH_X0[16] = {0,3,3,0, 1,3,2,0, 0,2,3,1, 1,2,2,1};
static __device__ __constant__ int CH_K [16] = {0,1,2,3, 0,1,2,3, 0,1,2,3, 0,1,2,3};
static __device__ __constant__ int CH_T [16] = {0,0,0,0, 0,0,0,0, 1,1,1,1, 0,0,0,0};

// workspace layout (float units unless noted)
#define PER_G   168960     // per-group transposed/folded weights
#define L0_OFF  0          // [k=8][c=128]            1024
#define L1_OFF  1024       // [k=128][c=128]         16384
#define L2_OFF  17408      // 4 x [k=128][c=128]     65536
#define L3_OFF  82944      // [k=128][c=128]         16384
#define L4_OFF  99328      // 4 x [k=128][c=128]     65536
#define L5_OFF  164864     // [k=128][c=32]           4096
#define TB_OFF  506880     // folded biases: [3][6][128]
#define MLP_OFF 509184     // int32 region: wq0(1024) bq0(32) wq1(1024) bq1(32) wq2(96) bq2(3)
#define FEAT_OFF_BYTES (2*1024*1024)   // int8 features [16][B][32]

__device__ inline float bninv(const float* bn, int g, int C, int c) {
  float ga = bn[(g*4+0)*C + c];
  float va = bn[(g*4+3)*C + c];
  return ga / sqrtf(va + 1e-5f);
}
__device__ inline int clampi(int v, int lo, int hi) { return v < lo ? lo : (v > hi ? hi : v); }
__device__ inline int q8(float x) { return clampi((int)rintf(x), -128, 127); }

// ---------------------------------------------------------------------------
// prep: fold BN into weights, transpose to [k][c], fold biases, quantize MLP
// ---------------------------------------------------------------------------
__global__ void prep_kernel(
    const float* __restrict__ w0, const float* __restrict__ b0,
    const float* __restrict__ w1, const float* __restrict__ b1,
    const float* __restrict__ w2, const float* __restrict__ b2,
    const float* __restrict__ w3, const float* __restrict__ b3,
    const float* __restrict__ w4, const float* __restrict__ b4,
    const float* __restrict__ w5, const float* __restrict__ b5,
    const float* __restrict__ bn1, const float* __restrict__ bn2,
    const float* __restrict__ bn3, const float* __restrict__ bn4,
    const float* __restrict__ bn5,
    const float* __restrict__ vw0, const float* __restrict__ vb0,
    const float* __restrict__ vw1, const float* __restrict__ vb1,
    const float* __restrict__ vw2, const float* __restrict__ vb2,
    float* __restrict__ ws)
{
  int idx = blockIdx.x * blockDim.x + threadIdx.x;
  if (idx < 3*PER_G) {
    int g = idx / PER_G;
    int r = idx - g*PER_G;
    float val;
    if (r < L1_OFF) {                       // conv0 [k=ic*4+dy*2+dx][c]
      int k = r >> 7, c = r & 127;
      int ic = k >> 2, dydx = k & 3;
      val = w0[((g*128 + c)*2 + ic)*4 + dydx];
    } else if (r < L2_OFF) {                // conv1
      int e = r - L1_OFF; int k = e >> 7, c = e & 127;
      val = w1[(g*128 + c)*128 + k] * bninv(bn1, g, 128, c);
    } else if (r < L3_OFF) {                // conv2, 4 blocks (dy,dx)
      int e = r - L2_OFF; int blk = e >> 14; int e2 = e & 16383;
      int k = e2 >> 7, c = e2 & 127;
      val = w2[((g*128 + c)*128 + k)*4 + blk] * bninv(bn2, g, 128, c);
    } else if (r < L4_OFF) {                // conv3
      int e = r - L3_OFF; int k = e >> 7, c = e & 127;
      val = w3[(g*128 + c)*128 + k] * bninv(bn3, g, 128, c);
    } else if (r < L5_OFF) {                // conv4, 4 blocks
      int e = r - L4_OFF; int blk = e >> 14; int e2 = e & 16383;
      int k = e2 >> 7, c = e2 & 127;
      val = w4[((g*128 + c)*128 + k)*4 + blk] * bninv(bn4, g, 128, c);
    } else {                                // conv5 [k=128][c=32]
      int e = r - L5_OFF; int k = e >> 5, c = e & 31;
      val = w5[(g*32 + c)*128 + k] * bninv(bn5, g, 32, c);
    }
    ws[idx] = val;
  } else if (idx < MLP_OFF) {
    int e = idx - TB_OFF;
    int g = e / 768; int r = e - g*768;
    int l = r >> 7, c = r & 127;
    float t;
    if (l == 0) {
      t = b0[g*128 + c];
    } else if (l < 5) {
      const float* bn = (l==1) ? bn1 : (l==2) ? bn2 : (l==3) ? bn3 : bn4;
      const float* bb = (l==1) ? b1  : (l==2) ? b2  : (l==3) ? b3  : b4;
      float inv = bninv(bn, g, 128, c);
      t = (bb[g*128 + c] - bn[(g*4+2)*128 + c]) * inv + bn[(g*4+1)*128 + c];
    } else {
      if (c < 32) {
        float inv = bninv(bn5, g, 32, c);
        t = (b5[g*32 + c] - bn5[(g*4+2)*32 + c]) * inv + bn5[(g*4+1)*32 + c];
      } else t = 0.f;
    }
    ws[idx] = t;
  } else if (idx < MLP_OFF + 2211) {
    int e = idx - MLP_OFF;
    int* wsI = (int*)ws;
    int val;
    if      (e < 1024) val = q8(vw0[e] * 256.f);
    else if (e < 1056) val = (int)rintf(vb0[e-1024] * 32768.f);
    else if (e < 2080) val = q8(vw1[e-1056] * 128.f);
    else if (e < 2112) val = (int)rintf(vb1[e-2080] * 16384.f);
    else if (e < 2208) val = q8(vw2[e-2112] * 128.f);
    else               val = (int)rintf(vb2[e-2208] * 16384.f);
    wsI[idx] = val;
  }
}

// ---------------------------------------------------------------------------
// fused conv stack
// ---------------------------------------------------------------------------
__device__ inline void stage_w(float* wb, const float* src, int n4, int tid) {
  const float4* s4 = (const float4*)src;
  float4* d4 = (float4*)wb;
  for (int j = tid; j < n4; j += 256) d4[j] = s4[j];
}

template<int NP>
__device__ inline void gemm1x1(const float* __restrict__ src, float* __restrict__ dst,
                               const float* __restrict__ wb, const float* __restrict__ tvec,
                               int s, int cq)
{
  float acc[NP][4];
#pragma unroll
  for (int p = 0; p < NP; ++p)
#pragma unroll
    for (int q = 0; q < 4; ++q) acc[p][q] = 0.f;
  const float4* A4 = (const float4*)(src + s*9*128);
  const float4* W4 = (const float4*)wb;
  for (int k4 = 0; k4 < 32; ++k4) {
    float av[NP][4];
#pragma unroll
    for (int p = 0; p < NP; ++p) {
      float4 t = A4[p*32 + k4];
      av[p][0]=t.x; av[p][1]=t.y; av[p][2]=t.z; av[p][3]=t.w;
    }
    float wv[4][4];
#pragma unroll
    for (int kk = 0; kk < 4; ++kk) {
      float4 t = W4[(k4*4+kk)*32 + cq];
      wv[kk][0]=t.x; wv[kk][1]=t.y; wv[kk][2]=t.z; wv[kk][3]=t.w;
    }
#pragma unroll
    for (int p = 0; p < NP; ++p)
#pragma unroll
      for (int kk = 0; kk < 4; ++kk)
#pragma unroll
        for (int q = 0; q < 4; ++q)
          acc[p][q] = fmaf(av[p][kk], wv[kk][q], acc[p][q]);
  }
  float4 tb = ((const float4*)tvec)[cq];
  float tbv[4] = {tb.x, tb.y, tb.z, tb.w};
#pragma unroll
  for (int p = 0; p < NP; ++p) {
    float hv[4];
#pragma unroll
    for (int q = 0; q < 4; ++q) hv[q] = fmaxf(acc[p][q] + tbv[q], 0.f);
    float4 h; h.x=hv[0]; h.y=hv[1]; h.z=hv[2]; h.w=hv[3];
    ((float4*)(dst + (s*9+p)*128))[cq] = h;
  }
}

__global__ __launch_bounds__(256) void conv_kernel(
    const float* __restrict__ x,
    const float* __restrict__ ws,
    signed char* __restrict__ feat,
    int B)
{
  extern __shared__ float lds[];
  float* bufA = lds;                 // [TS][9][128]  9216 floats
  float* bufB = bufA + TS*9*128;     // 9216
  float* wbuf = bufB + TS*9*128;     // 16384
  float* xsh  = wbuf + 16384;        // [TS][2][16]   256

  const int tid = threadIdx.x;
  const int wg  = blockIdx.x;

  const int tilesG0 = B / 2;         // 4*B/TS
  const int tilesG1 = B;             // 8*B/TS
  int g, tile, chunkBase;
  if (wg < tilesG0)                { g = 0; tile = wg;                    chunkBase = 0;  }
  else if (wg < tilesG0 + tilesG1) { g = 1; tile = wg - tilesG0;          chunkBase = 4;  }
  else                             { g = 2; tile = wg - tilesG0 - tilesG1; chunkBase = 12; }

  const int n0 = tile * TS;
  const int chunkLocal = n0 / B;
  const int b0s = n0 - chunkLocal * B;
  const int chunkG = chunkBase + chunkLocal;

  const float* W  = ws + g * PER_G;
  const float* Tg = ws + TB_OFF + g * 768;

  // ---- load chunk inputs (with rot/transpose) ----
  {
    int s = tid >> 5, v = tid & 31;
    int ic = v >> 4, pos = v & 15;
    int i = pos >> 2, j = pos & 3;
    int tt = CH_T[chunkG], kk = CH_K[chunkG];
    int a = tt ? j : i, bb = tt ? i : j;
    int py, px;
    if      (kk == 0) { py = a;    px = bb;   }
    else if (kk == 1) { py = bb;   px = 3-a;  }
    else if (kk == 2) { py = 3-a;  px = 3-bb; }
    else              { py = 3-bb; px = a;    }
    int sy = CH_Y0[chunkG] + py, sx = CH_X0[chunkG] + px;
    int bidx = b0s + s;
    xsh[s*32 + v] = x[(bidx*2 + ic)*49 + sy*7 + sx];
  }
  stage_w(wbuf, W + L0_OFF, 256, tid);
  __syncthreads();

  const int s  = tid >> 5;
  const int cq = tid & 31;

  // ---- conv0: K=8 (ic,dy,dx), 3x3 out, relu ----
  {
    float acc[9][4];
#pragma unroll
    for (int p = 0; p < 9; ++p)
#pragma unroll
      for (int q = 0; q < 4; ++q) acc[p][q] = 0.f;
    const float4* W4 = (const float4*)wbuf;
#pragma unroll
    for (int k = 0; k < 8; ++k) {
      int ic = k >> 2, dy = (k>>1)&1, dx = k&1;
      float4 w = W4[k*32 + cq];
      float wv[4] = {w.x, w.y, w.z, w.w};
#pragma unroll
      for (int oy = 0; oy < 3; ++oy)
#pragma unroll
        for (int ox = 0; ox < 3; ++ox) {
          float a = xsh[s*32 + ic*16 + (oy+dy)*4 + (ox+dx)];
          int p = oy*3 + ox;
#pragma unroll
          for (int q = 0; q < 4; ++q) acc[p][q] = fmaf(a, wv[q], acc[p][q]);
        }
    }
    float4 tb = ((const float4*)(Tg + 0*128))[cq];
    float tbv[4] = {tb.x, tb.y, tb.z, tb.w};
#pragma unroll
    for (int p = 0; p < 9; ++p) {
      float hv[4];
#pragma unroll
      for (int q = 0; q < 4; ++q) hv[q] = fmaxf(acc[p][q] + tbv[q], 0.f);
      float4 h; h.x=hv[0]; h.y=hv[1]; h.z=hv[2]; h.w=hv[3];
      ((float4*)(bufA + (s*9+p)*128))[cq] = h;
    }
  }
  __syncthreads();

  // ---- conv1: 1x1, 9 pos ----
  stage_w(wbuf, W + L1_OFF, 4096, tid);
  __syncthreads();
  gemm1x1<9>(bufA, bufB, wbuf, Tg + 1*128, s, cq);
  __syncthreads();

  // ---- conv2: 2x2 on 3x3 -> 2x2 (4 shifted GEMM blocks) ----
  {
    float acc[4][4];
#pragma unroll
    for (int p = 0; p < 4; ++p)
#pragma unroll
      for (int q = 0; q < 4; ++q) acc[p][q] = 0.f;
    for (int blk = 0; blk < 4; ++blk) {
      stage_w(wbuf, W + L2_OFF + blk*16384, 4096, tid);
      __syncthreads();
      int dy = blk >> 1, dx = blk & 1;
      const float4* A4 = (const float4*)(bufB + s*9*128);
      const float4* W4 = (const float4*)wbuf;
      for (int k4 = 0; k4 < 32; ++k4) {
        float av[4][4];
#pragma unroll
        for (int oy = 0; oy < 2; ++oy)
#pragma unroll
          for (int ox = 0; ox < 2; ++ox) {
            float4 t = A4[((oy+dy)*3 + ox+dx)*32 + k4];
            int p = oy*2 + ox;
            av[p][0]=t.x; av[p][1]=t.y; av[p][2]=t.z; av[p][3]=t.w;
          }
        float wv[4][4];
#pragma unroll
        for (int kk = 0; kk < 4; ++kk) {
          float4 t = W4[(k4*4+kk)*32 + cq];
          wv[kk][0]=t.x; wv[kk][1]=t.y; wv[kk][2]=t.z; wv[kk][3]=t.w;
        }
#pragma unroll
        for (int p = 0; p < 4; ++p)
#pragma unroll
          for (int kk = 0; kk < 4; ++kk)
#pragma unroll
            for (int q = 0; q < 4; ++q)
              acc[p][q] = fmaf(av[p][kk], wv[kk][q], acc[p][q]);
      }
      __syncthreads();
    }
    float4 tb = ((const float4*)(Tg + 2*128))[cq];
    float tbv[4] = {tb.x, tb.y, tb.z, tb.w};
#pragma unroll
    for (int p = 0; p < 4; ++p) {
      float hv[4];
#pragma unroll
      for (int q = 0; q < 4; ++q) hv[q] = fmaxf(acc[p][q] + tbv[q], 0.f);
      float4 h; h.x=hv[0]; h.y=hv[1]; h.z=hv[2]; h.w=hv[3];
      ((float4*)(bufA + (s*9+p)*128))[cq] = h;
    }
  }
  // note: no barrier needed here; conv3's post-stage barrier orders bufA writes

  // ---- conv3: 1x1, 4 pos ----
  stage_w(wbuf, W + L3_OFF, 4096, tid);
  __syncthreads();
  gemm1x1<4>(bufA, bufB, wbuf, Tg + 3*128, s, cq);
  __syncthreads();

  // ---- conv4: 2x2 on 2x2 -> 1x1 (4 blocks) ----
  {
    float acc[4] = {0.f, 0.f, 0.f, 0.f};
    for (int blk = 0; blk < 4; ++blk) {
      stage_w(wbuf, W + L4_OFF + blk*16384, 4096, tid);
      __syncthreads();
      const float4* A4 = (const float4*)(bufB + s*9*128);
      const float4* W4 = (const float4*)wbuf;
      for (int k4 = 0; k4 < 32; ++k4) {
        float4 a = A4[blk*32 + k4];
        float av[4] = {a.x, a.y, a.z, a.w};
        float wv[4][4];
#pragma unroll
        for (int kk = 0; kk < 4; ++kk) {
          float4 t = W4[(k4*4+kk)*32 + cq];
          wv[kk][0]=t.x; wv[kk][1]=t.y; wv[kk][2]=t.z; wv[kk][3]=t.w;
        }
#pragma unroll
        for (int kk = 0; kk < 4; ++kk)
#pragma unroll
          for (int q = 0; q < 4; ++q)
            acc[q] = fmaf(av[kk], wv[kk][q], acc[q]);
      }
      __syncthreads();
    }
    float4 tb = ((const float4*)(Tg + 4*128))[cq];
    float tbv[4] = {tb.x, tb.y, tb.z, tb.w};
    float hv[4];
#pragma unroll
    for (int q = 0; q < 4; ++q) hv[q] = fmaxf(acc[q] + tbv[q], 0.f);
    float4 h; h.x=hv[0]; h.y=hv[1]; h.z=hv[2]; h.w=hv[3];
    ((float4*)(bufA + s*9*128))[cq] = h;   // h5 at pos 0
  }

  // ---- conv5: 128 -> 32, clip + quantize to int8 ----
  stage_w(wbuf, W + L5_OFF, 1024, tid);
  __syncthreads();
  {
    int c = tid & 31;
    float acc = 0.f;
    const float4* A4 = (const float4*)(bufA + s*9*128);
    for (int k4 = 0; k4 < 32; ++k4) {
      float4 a = A4[k4];
      acc = fmaf(a.x, wbuf[(k4*4+0)*32 + c], acc);
      acc = fmaf(a.y, wbuf[(k4*4+1)*32 + c], acc);
      acc = fmaf(a.z, wbuf[(k4*4+2)*32 + c], acc);
      acc = fmaf(a.w, wbuf[(k4*4+3)*32 + c], acc);
    }
    float f = acc + Tg[5*128 + c];
    f = fminf(fmaxf(f, -1.0f), 127.0f/128.0f);
    int q = clampi((int)rintf(f * 128.0f), -128, 127);
    feat[((long)chunkG*B + (b0s + s))*32 + c] = (signed char)q;
  }
}

// ---------------------------------------------------------------------------
// value MLP: exact integer arithmetic (all scales are powers of two)
// ---------------------------------------------------------------------------
__global__ __launch_bounds__(256) void mlp_kernel(
    const signed char* __restrict__ feat,
    const int* __restrict__ mw,
    float* __restrict__ out, int B)
{
  int b = blockIdx.x * blockDim.x + threadIdx.x;
  if (b >= B) return;
  int S[32];
#pragma unroll
  for (int c = 0; c < 32; ++c) S[c] = 0;
  for (int ch = 0; ch < 16; ++ch) {
    const signed char* f = feat + ((long)ch*B + b)*32;
#pragma unroll
    for (int c = 0; c < 32; ++c) S[c] += f[c];
  }
  int x1[32];
#pragma unroll
  for (int c = 0; c < 32; ++c) x1[c] = clampi(S[c], -128, 127);

  const int* wq0 = mw;        const int* bq0 = mw + 1024;
  const int* wq1 = mw + 1056; const int* bq1 = mw + 2080;
  const int* wq2 = mw + 2112; const int* bq2 = mw + 2208;

  int x2[32];
#pragma unroll
  for (int o = 0; o < 32; ++o) {
    int acc = bq0[o];
    for (int i = 0; i < 32; ++i) acc += x1[i] * wq0[o*32 + i];
    acc = clampi(acc, 0, 32512);            // clip(0, 127/128) at /32768
    int r = acc >> 8, fr = acc & 255;       // round-half-even to /256
    r += (fr > 128 || (fr == 128 && (r & 1))) ? 1 : 0;
    x2[o] = r;
  }
  int x3[32];
#pragma unroll
  for (int o = 0; o < 32; ++o) {
    int acc = bq1[o];
    for (int i = 0; i < 32; ++i) acc += x2[i] * wq1[o*32 + i];
    acc = clampi(acc, 0, 16256);            // clip(0, 127/128) at /16384
    int r = acc >> 7, fr = acc & 127;       // round-half-even to /128
    r += (fr > 64 || (fr == 64 && (r & 1))) ? 1 : 0;
    x3[o] = r;
  }
  for (int o = 0; o < 3; ++o) {
    int acc = bq2[o];
    for (int i = 0; i < 32; ++i) acc += x3[i] * wq2[o*32 + i];
    out[b*3 + o] = (float)acc / 16384.0f;
  }
}

__global__ void zero_kernel(float4* __restrict__ p, int n4) {
  int i = blockIdx.x * blockDim.x + threadIdx.x;
  if (i < n4) p[i] = make_float4(0.f, 0.f, 0.f, 0.f);
}

// ---------------------------------------------------------------------------
extern "C" void kernel_launch(void* const* d_in, const int* in_sizes, int n_in,
                              void* d_out, int out_size, void* d_ws, size_t ws_size,
                              hipStream_t stream)
{
  const float* x   = (const float*)d_in[0];
  const float* w0  = (const float*)d_in[1];
  const float* b0  = (const float*)d_in[2];
  const float* w1  = (const float*)d_in[3];
  const float* b1  = (const float*)d_in[4];
  const float* w2  = (const float*)d_in[5];
  const float* b2  = (const float*)d_in[6];
  const float* w3  = (const float*)d_in[7];
  const float* b3  = (const float*)d_in[8];
  const float* w4  = (const float*)d_in[9];
  const float* b4  = (const float*)d_in[10];
  const float* w5  = (const float*)d_in[11];
  const float* b5  = (const float*)d_in[12];
  const float* bn1 = (const float*)d_in[13];
  const float* bn2 = (const float*)d_in[14];
  const float* bn3 = (const float*)d_in[15];
  const float* bn4 = (const float*)d_in[16];
  const float* bn5 = (const float*)d_in[17];
  const float* vw0 = (const float*)d_in[18];
  const float* vb0 = (const float*)d_in[19];
  const float* vw1 = (const float*)d_in[20];
  const float* vb1 = (const float*)d_in[21];
  const float* vw2 = (const float*)d_in[22];
  const float* vb2 = (const float*)d_in[23];

  const int B = in_sizes[0] / 98;          // x: [B,2,7,7]
  float* ws = (float*)d_ws;
  signed char* feat = (signed char*)d_ws + FEAT_OFF_BYTES;
  float* out = (float*)d_out;

  (void)hipFuncSetAttribute((const void*)conv_kernel,
                            hipFuncAttributeMaxDynamicSharedMemorySize,
                            (TS*9*128*2 + 16384 + 256) * 4);

  {
    int total = MLP_OFF + 2211;
    prep_kernel<<<(total + 255)/256, 256, 0, stream>>>(
        w0,b0,w1,b1,w2,b2,w3,b3,w4,b4,w5,b5,
        bn1,bn2,bn3,bn4,bn5, vw0,vb0,vw1,vb1,vw2,vb2, ws);
  }

  {
    int nTiles = 2*B;                      // 16*B / TS
    size_t smem = (size_t)(TS*9*128*2 + 16384 + 256) * 4;
    conv_kernel<<<nTiles, 256, smem, stream>>>(x, ws, feat, B);
  }

  mlp_kernel<<<(B + 255)/256, 256, 0, stream>>>(feat, (const int*)ws + MLP_OFF, out, B);

  {
    int n4 = B*49/4;
    zero_kernel<<<(n4 + 255)/256, 256, 0, stream>>>((float4*)(out + 3*B), n4);
  }
}

// Round 2
// 2070.378 us; speedup vs baseline: 3.5157x; 3.5157x over previous
//
#include <hip/hip_runtime.h>
#include <stdint.h>

// ---------------------------------------------------------------------------
// FlatSquare7x7NNUEv4 — round 2: f16 hi/lo split MFMA conv stack.
//   A·W = Ah·Wh + 2^-11*(Als·Wh + Ah·Wls),  Als=(A-Ah)*2^11, Wls=(W-Wh)*2^11
// Two f32 accumulators (acc1, acc2), recombined at writeback. Error ~2^-22.
// ---------------------------------------------------------------------------

typedef _Float16 f16x8 __attribute__((ext_vector_type(8)));
typedef float f32x4 __attribute__((ext_vector_type(4)));

// chunk tables: groups: [0..3]=g0, [4..11]=g1, [12..15]=g2
static __device__ __constant__ int CH_Y0[16] = {0,0,3,3, 0,1,3,2, 1,0,2,3, 1,1,2,2};
static __device__ __constant__ int CH_X0[16] = {0,3,3,0, 1,3,2,0, 0,2,3,1, 1,2,2,1};
static __device__ __constant__ int CH_K [16] = {0,1,2,3, 0,1,2,3, 0,1,2,3, 0,1,2,3};
static __device__ __constant__ int CH_T [16] = {0,0,0,0, 0,0,0,0, 1,1,1,1, 0,0,0,0};

// ---- LDS layout (bytes) ----
#define AH_OFF   0         // Ah  [144][128] f16 = 36864
#define AL_OFF   36864     // Als [144][128] f16 = 36864
#define WH_OFF   73728     // weight half H, 32KB
#define WL_OFF   106496    // weight half L, 32KB
#define XIN_OFF  139264    // [16][2][16] f32 = 2048
#define W0_OFF   141312    // [8][128] f32 = 4096
#define BIAS_OFF 145408    // [6][128] f32 = 3072
#define LDS_TOTAL 148480

// ---- global weight image (bytes within group) ----
#define G_STRIDE 678912
#define GW1   0
#define GW2   65536
#define GW3   327680
#define GW4   393216
#define GW5   655360
#define GW0   671744
#define GBIAS 675840
#define G_WORDS   167936     // f16 region words per group (656KB/4)
#define G_STRIDE_W 169728    // group stride in words
#define MLP_WORD_OFF 509184
#define FEAT_OFF_BYTES (2*1024*1024)

#define LO_SCALE 2048.0f
#define LO_INV   (1.0f/2048.0f)

__device__ __forceinline__ int swz(int b) { return b ^ (((b>>8)&7)<<4); }
__device__ __forceinline__ int base3(int z){ return (z>>1)*3 + (z&1); }
__device__ __forceinline__ int clampi(int v, int lo, int hi) { return v < lo ? lo : (v > hi ? hi : v); }

__device__ inline float bninv(const float* bn, int g, int C, int c) {
  float ga = bn[(g*4+0)*C + c];
  float va = bn[(g*4+3)*C + c];
  return ga / sqrtf(va + 1e-5f);
}
__device__ inline int q8(float x) { return clampi((int)rintf(x), -128, 127); }

// ---------------------------------------------------------------------------
// prep: fold BN, transpose to [oc][k], split f16 hi / lo*2^11, pre-swizzle
// ---------------------------------------------------------------------------
__global__ void prep_kernel(
    const float* __restrict__ w0, const float* __restrict__ b0,
    const float* __restrict__ w1, const float* __restrict__ b1,
    const float* __restrict__ w2, const float* __restrict__ b2,
    const float* __restrict__ w3, const float* __restrict__ b3,
    const float* __restrict__ w4, const float* __restrict__ b4,
    const float* __restrict__ w5, const float* __restrict__ b5,
    const float* __restrict__ bn1, const float* __restrict__ bn2,
    const float* __restrict__ bn3, const float* __restrict__ bn4,
    const float* __restrict__ bn5,
    const float* __restrict__ vw0, const float* __restrict__ vb0,
    const float* __restrict__ vw1, const float* __restrict__ vb1,
    const float* __restrict__ vw2, const float* __restrict__ vb2,
    float* __restrict__ ws)
{
  int idx = blockIdx.x * blockDim.x + threadIdx.x;
  if (idx < 3*G_WORDS) {
    uint32_t* wsU = (uint32_t*)ws;
    int g = idx / G_WORDS;
    int q = idx - g*G_WORDS;
    int stage, blk = 0, sub;
    if      (q < 16384)  { stage = 1; sub = q; }
    else if (q < 81920)  { stage = 2; blk = (q-16384)>>14; sub = (q-16384)&16383; }
    else if (q < 98304)  { stage = 3; sub = q-81920; }
    else if (q < 163840) { stage = 4; blk = (q-98304)>>14; sub = (q-98304)&16383; }
    else                 { stage = 5; sub = q-163840; }
    int isLo, r;
    if (stage == 5) { isLo = sub>>11; r = sub&2047; }
    else            { isLo = sub>>13; r = sub&8191; }
    int pb = r*4;
    int lb = pb ^ (((pb>>8)&7)<<4);     // inverse of kernel-side swizzle
    int oc = lb>>8;
    int k0 = (lb&255)>>1;               // even f16 index; word = (k0, k0+1)
    float inv, v0, v1;
    if (stage == 1) {
      inv = bninv(bn1,g,128,oc);
      v0 = w1[(g*128+oc)*128+k0]; v1 = w1[(g*128+oc)*128+k0+1];
    } else if (stage == 2) {
      inv = bninv(bn2,g,128,oc);
      v0 = w2[((g*128+oc)*128+k0)*4+blk]; v1 = w2[((g*128+oc)*128+k0+1)*4+blk];
    } else if (stage == 3) {
      inv = bninv(bn3,g,128,oc);
      v0 = w3[(g*128+oc)*128+k0]; v1 = w3[(g*128+oc)*128+k0+1];
    } else if (stage == 4) {
      inv = bninv(bn4,g,128,oc);
      v0 = w4[((g*128+oc)*128+k0)*4+blk]; v1 = w4[((g*128+oc)*128+k0+1)*4+blk];
    } else {
      inv = bninv(bn5,g,32,oc);
      v0 = w5[(g*32+oc)*128+k0]; v1 = w5[(g*32+oc)*128+k0+1];
    }
    v0 *= inv; v1 *= inv;
    _Float16 h0 = (_Float16)v0, h1 = (_Float16)v1;
    if (isLo) {
      h0 = (_Float16)((v0 - (float)h0) * LO_SCALE);
      h1 = (_Float16)((v1 - (float)h1) * LO_SCALE);
    }
    union { _Float16 h[2]; uint32_t u; } uu;
    uu.h[0] = h0; uu.h[1] = h1;
    wsU[g*G_STRIDE_W + q] = uu.u;
  } else if (idx < 506880) {            // w0: [k=8][c=128] fp32
    int e = idx - 503808; int g = e>>10; int t2 = e&1023;
    int k = t2>>7, c = t2&127;
    ws[g*G_STRIDE_W + 167936 + t2] = w0[((g*128 + c)*2 + (k>>2))*4 + (k&3)];
  } else if (idx < 509184) {            // folded biases [6][128] fp32
    int e = idx - 506880; int g = e/768; int r = e - g*768;
    int l = r>>7, c = r&127;
    float t;
    if (l == 0) {
      t = b0[g*128 + c];
    } else if (l < 5) {
      const float* bn = (l==1) ? bn1 : (l==2) ? bn2 : (l==3) ? bn3 : bn4;
      const float* bb = (l==1) ? b1  : (l==2) ? b2  : (l==3) ? b3  : b4;
      float inv = bninv(bn, g, 128, c);
      t = (bb[g*128 + c] - bn[(g*4+2)*128 + c]) * inv + bn[(g*4+1)*128 + c];
    } else {
      if (c < 32) {
        float inv = bninv(bn5, g, 32, c);
        t = (b5[g*32 + c] - bn5[(g*4+2)*32 + c]) * inv + bn5[(g*4+1)*32 + c];
      } else t = 0.f;
    }
    ws[g*G_STRIDE_W + 168960 + r] = t;
  } else if (idx < 511395) {            // quantized MLP ints
    int e = idx - MLP_WORD_OFF;
    int* wsI = (int*)ws;
    int val;
    if      (e < 1024) val = q8(vw0[e] * 256.f);
    else if (e < 1056) val = (int)rintf(vb0[e-1024] * 32768.f);
    else if (e < 2080) val = q8(vw1[e-1056] * 128.f);
    else if (e < 2112) val = (int)rintf(vb1[e-2080] * 16384.f);
    else if (e < 2208) val = q8(vw2[e-2112] * 128.f);
    else               val = (int)rintf(vb2[e-2208] * 16384.f);
    wsI[idx] = val;
  }
}

// ---------------------------------------------------------------------------
// fused MFMA conv stack
// ---------------------------------------------------------------------------
__device__ __forceinline__ f16x8 rdfrag(const char* base, int row, int ko) {
  return *(const f16x8*)(base + swz(row*256 + ko*2));
}

__device__ __forceinline__ void gl16(void* l, const void* g) {
  __builtin_amdgcn_global_load_lds(
      (const __attribute__((address_space(1))) void*)(uintptr_t)g,
      (__attribute__((address_space(3))) void*)(uint32_t)(uintptr_t)l,
      16, 0, 0);
}

__device__ __forceinline__ void stage(char* ldsbase, const char* gsrc, int bytes, int tid) {
  for (int off = tid*16; off < bytes; off += 8192)
    gl16(ldsbase + off, gsrc + off);
}

template<int MODE> __device__ __forceinline__ int arow(int r, int blk) {
  if (MODE == 0) return r;                                    // 1x1 convs
  if (MODE == 2) return (r>>2)*9 + base3(r&3) + base3(blk);   // conv2 gather
  return r*4 + blk;                                           // conv4 gather
}

#define MFMA(a,b,c) __builtin_amdgcn_mfma_f32_16x16x32_f16((a),(b),(c),0,0,0)

template<int MT, int NT, int MODE>
__device__ __forceinline__ void phaseH(const char* AHb, const char* ALb, const char* Wb,
    int m0, int n0, int lane, int blk, f32x4 acc1[][NT], f32x4 acc2[][NT])
{
  const int l15 = lane & 15, kq = (lane >> 4) & 3;
#pragma unroll
  for (int kb = 0; kb < 4; ++kb) {
    const int ko = kb*32 + kq*8;
    f16x8 Ah_[MT], Al_[MT], Bh_[NT];
#pragma unroll
    for (int m = 0; m < MT; ++m) {
      int ra = arow<MODE>((m0+m)*16 + l15, blk);
      Ah_[m] = rdfrag(AHb, ra, ko);
      Al_[m] = rdfrag(ALb, ra, ko);
    }
#pragma unroll
    for (int n = 0; n < NT; ++n) Bh_[n] = rdfrag(Wb, (n0+n)*16 + l15, ko);
#pragma unroll
    for (int m = 0; m < MT; ++m)
#pragma unroll
      for (int n = 0; n < NT; ++n)
        acc1[m][n] = MFMA(Ah_[m], Bh_[n], acc1[m][n]);
#pragma unroll
    for (int m = 0; m < MT; ++m)
#pragma unroll
      for (int n = 0; n < NT; ++n)
        acc2[m][n] = MFMA(Al_[m], Bh_[n], acc2[m][n]);
  }
}

template<int MT, int NT, int MODE>
__device__ __forceinline__ void phaseL(const char* AHb, const char* Wb,
    int m0, int n0, int lane, int blk, f32x4 acc2[][NT])
{
  const int l15 = lane & 15, kq = (lane >> 4) & 3;
#pragma unroll
  for (int kb = 0; kb < 4; ++kb) {
    const int ko = kb*32 + kq*8;
    f16x8 Ah_[MT], Bl_[NT];
#pragma unroll
    for (int m = 0; m < MT; ++m)
      Ah_[m] = rdfrag(AHb, arow<MODE>((m0+m)*16 + l15, blk), ko);
#pragma unroll
    for (int n = 0; n < NT; ++n) Bl_[n] = rdfrag(Wb, (n0+n)*16 + l15, ko);
#pragma unroll
    for (int m = 0; m < MT; ++m)
#pragma unroll
      for (int n = 0; n < NT; ++n)
        acc2[m][n] = MFMA(Ah_[m], Bl_[n], acc2[m][n]);
  }
}

__device__ __forceinline__ void wbval(char* ah, char* al, int row, int col, float v) {
  _Float16 h = (_Float16)v;
  _Float16 l = (_Float16)((v - (float)h) * LO_SCALE);
  int sb = swz(row*256 + col*2);
  *(_Float16*)(ah + sb) = h;
  *(_Float16*)(al + sb) = l;
}

template<int MT, int NT>
__device__ __forceinline__ void writeback(char* AHb, char* ALb, const float* bias,
    int layer, int m0, int n0, int lane, f32x4 acc1[][NT], f32x4 acc2[][NT])
{
  const int l15 = lane & 15, rq = (lane >> 4) & 3;
#pragma unroll
  for (int m = 0; m < MT; ++m)
#pragma unroll
    for (int n = 0; n < NT; ++n) {
      int col = (n0+n)*16 + l15;
      float bb = bias[layer*128 + col];
#pragma unroll
      for (int q = 0; q < 4; ++q) {
        int row = (m0+m)*16 + rq*4 + q;
        float v = acc1[m][n][q] + acc2[m][n][q]*LO_INV + bb;
        v = fmaxf(v, 0.f);
        wbval(AHb, ALb, row, col, v);
      }
    }
}

__global__ __launch_bounds__(512, 2) void conv_mfma(
    const float* __restrict__ x, const char* __restrict__ wsb,
    signed char* __restrict__ feat, int B, int wgPerChunk)
{
  extern __shared__ char lds[];
  char* AHb = lds + AH_OFF;
  char* ALb = lds + AL_OFF;
  char* WHb = lds + WH_OFF;
  char* WLb = lds + WL_OFF;
  const float* bias = (const float*)(lds + BIAS_OFF);

  const int tid  = threadIdx.x;
  const int lane = tid & 63;
  const int wave = tid >> 6;

  const int wg = blockIdx.x;
  const int chunkG = wg / wgPerChunk;
  const int b0 = (wg - chunkG*wgPerChunk) * 16;
  const int g = (chunkG < 4) ? 0 : (chunkG < 12) ? 1 : 2;
  const char* gw = wsb + g*G_STRIDE;

  // ---- prologue staging ----
  {
    int s = tid >> 5, v = tid & 31;
    int ic = v >> 4, pos = v & 15;
    int i = pos >> 2, j = pos & 3;
    int tt = CH_T[chunkG], kk = CH_K[chunkG];
    int a = tt ? j : i, bb2 = tt ? i : j;
    int py, px;
    if      (kk == 0) { py = a;     px = bb2;   }
    else if (kk == 1) { py = bb2;   px = 3-a;   }
    else if (kk == 2) { py = 3-a;   px = 3-bb2; }
    else              { py = 3-bb2; px = a;     }
    int sy = CH_Y0[chunkG] + py, sx = CH_X0[chunkG] + px;
    ((float*)(lds+XIN_OFF))[s*32 + v] = x[((b0+s)*2 + ic)*49 + sy*7 + sx];
  }
  if (tid < 256) ((float4*)(lds+W0_OFF))[tid]   = ((const float4*)(gw+GW0))[tid];
  if (tid < 192) ((float4*)(lds+BIAS_OFF))[tid] = ((const float4*)(gw+GBIAS))[tid];
  stage(WHb, gw+GW1,       32768, tid);   // w1 hi
  stage(WLb, gw+GW1+32768, 32768, tid);   // w1 lo
  __syncthreads();

  // ---- conv0 (VALU, K=8) ----
  {
    const float* xin = (const float*)(lds+XIN_OFF);
    const float* w0s = (const float*)(lds+W0_OFF);
    int c = tid & 127;
    float wr[8];
#pragma unroll
    for (int k = 0; k < 8; ++k) wr[k] = w0s[k*128 + c];
    float b0c = bias[c];
    int sg = tid >> 7;
#pragma unroll
    for (int si = 0; si < 4; ++si) {
      int s = sg*4 + si;
      float xv[32];
#pragma unroll
      for (int t2 = 0; t2 < 32; ++t2) xv[t2] = xin[s*32 + t2];
#pragma unroll
      for (int oy = 0; oy < 3; ++oy)
#pragma unroll
        for (int ox = 0; ox < 3; ++ox) {
          float acc0 = b0c;
#pragma unroll
          for (int ic2 = 0; ic2 < 2; ++ic2)
#pragma unroll
            for (int dy = 0; dy < 2; ++dy)
#pragma unroll
              for (int dx = 0; dx < 2; ++dx)
                acc0 = fmaf(xv[ic2*16 + (oy+dy)*4 + ox+dx], wr[ic2*4+dy*2+dx], acc0);
          wbval(AHb, ALb, s*9 + oy*3 + ox, c, fmaxf(acc0, 0.f));
        }
    }
  }
  __syncthreads();                              // act ready, w1 ready

  // ---- conv1: rows 144 (9 M-tiles), wave grid 2x4 (tile 4 overlaps: benign) ----
  {
    const int m0 = (wave >> 2) * 4;
    const int n0 = (wave & 3) * 2;
    f32x4 acc1[5][2] = {}; f32x4 acc2[5][2] = {};
    phaseH<5,2,0>(AHb, ALb, WHb, m0, n0, lane, 0, acc1, acc2);
    __syncthreads();
    stage(WHb, gw+GW2, 32768, tid);             // w2 blk0 hi
    phaseL<5,2,0>(AHb, WLb, m0, n0, lane, 0, acc2);
    __syncthreads();
    stage(WLb, gw+GW2+32768, 32768, tid);       // w2 blk0 lo
    writeback<5,2>(AHb, ALb, bias, 1, m0, n0, lane, acc1, acc2);
  }
  __syncthreads();

  // ---- conv2: out 64 rows, K=512 (4 gathered blocks) ----
  {
    const int m0 = (wave >> 2) * 2;
    const int n0 = (wave & 3) * 2;
    f32x4 acc1[2][2] = {}; f32x4 acc2[2][2] = {};
#pragma unroll
    for (int blk = 0; blk < 4; ++blk) {
      phaseH<2,2,2>(AHb, ALb, WHb, m0, n0, lane, blk, acc1, acc2);
      __syncthreads();
      if (blk < 3) stage(WHb, gw+GW2+(blk+1)*65536, 32768, tid);
      else         stage(WHb, gw+GW3, 32768, tid);
      phaseL<2,2,2>(AHb, WLb, m0, n0, lane, blk, acc2);
      __syncthreads();
      if (blk < 3) stage(WLb, gw+GW2+(blk+1)*65536+32768, 32768, tid);
      else         stage(WLb, gw+GW3+32768, 32768, tid);
    }
    writeback<2,2>(AHb, ALb, bias, 2, m0, n0, lane, acc1, acc2);
  }
  __syncthreads();

  // ---- conv3: rows 64, 1x1 ----
  {
    const int m0 = (wave >> 2) * 2;
    const int n0 = (wave & 3) * 2;
    f32x4 acc1[2][2] = {}; f32x4 acc2[2][2] = {};
    phaseH<2,2,0>(AHb, ALb, WHb, m0, n0, lane, 0, acc1, acc2);
    __syncthreads();
    stage(WHb, gw+GW4, 32768, tid);             // w4 blk0 hi
    phaseL<2,2,0>(AHb, WLb, m0, n0, lane, 0, acc2);
    __syncthreads();
    stage(WLb, gw+GW4+32768, 32768, tid);       // w4 blk0 lo
    writeback<2,2>(AHb, ALb, bias, 3, m0, n0, lane, acc1, acc2);
  }
  __syncthreads();

  // ---- conv4: out 16 rows, K=512 (4 gathered blocks), 1 tile/wave ----
  {
    const int n0 = wave;
    f32x4 acc1[1][1] = {}; f32x4 acc2[1][1] = {};
#pragma unroll
    for (int blk = 0; blk < 4; ++blk) {
      phaseH<1,1,4>(AHb, ALb, WHb, 0, n0, lane, blk, acc1, acc2);
      __syncthreads();
      if (blk < 3) stage(WHb, gw+GW4+(blk+1)*65536, 32768, tid);
      else         stage(WHb, gw+GW5, 8192, tid);        // w5 hi (8KB)
      phaseL<1,1,4>(AHb, WLb, 0, n0, lane, blk, acc2);
      __syncthreads();
      if (blk < 3) stage(WLb, gw+GW4+(blk+1)*65536+32768, 32768, tid);
      else         stage(WLb, gw+GW5+8192, 8192, tid);   // w5 lo (8KB)
    }
    writeback<1,1>(AHb, ALb, bias, 4, 0, n0, lane, acc1, acc2);
  }
  __syncthreads();

  // ---- conv5: 128 -> 32, quantize features (waves 0,1 only; no barriers) ----
  if (wave < 2) {
    f32x4 acc1[1][1] = {}; f32x4 acc2[1][1] = {};
    phaseH<1,1,0>(AHb, ALb, WHb, 0, wave, lane, 0, acc1, acc2);
    phaseL<1,1,0>(AHb, WLb, 0, wave, lane, 0, acc2);
    int c = wave*16 + (lane & 15);
    float bb = bias[5*128 + c];
#pragma unroll
    for (int q = 0; q < 4; ++q) {
      int s = ((lane >> 4) & 3)*4 + q;
      float f = acc1[0][0][q] + acc2[0][0][q]*LO_INV + bb;
      f = fminf(fmaxf(f, -1.0f), 127.0f/128.0f);
      int qi = clampi((int)rintf(f * 128.0f), -128, 127);
      feat[((long)chunkG*B + b0 + s)*32 + c] = (signed char)qi;
    }
  }
}

// ---------------------------------------------------------------------------
// value MLP: exact integer arithmetic (unchanged, verified round 1)
// ---------------------------------------------------------------------------
__global__ __launch_bounds__(256) void mlp_kernel(
    const signed char* __restrict__ feat,
    const int* __restrict__ mw,
    float* __restrict__ out, int B)
{
  int b = blockIdx.x * blockDim.x + threadIdx.x;
  if (b >= B) return;
  int S[32];
#pragma unroll
  for (int c = 0; c < 32; ++c) S[c] = 0;
  for (int ch = 0; ch < 16; ++ch) {
    const signed char* f = feat + ((long)ch*B + b)*32;
#pragma unroll
    for (int c = 0; c < 32; ++c) S[c] += f[c];
  }
  int x1[32];
#pragma unroll
  for (int c = 0; c < 32; ++c) x1[c] = clampi(S[c], -128, 127);

  const int* wq0 = mw;        const int* bq0 = mw + 1024;
  const int* wq1 = mw + 1056; const int* bq1 = mw + 2080;
  const int* wq2 = mw + 2112; const int* bq2 = mw + 2208;

  int x2[32];
#pragma unroll
  for (int o = 0; o < 32; ++o) {
    int acc = bq0[o];
    for (int i = 0; i < 32; ++i) acc += x1[i] * wq0[o*32 + i];
    acc = clampi(acc, 0, 32512);
    int r = acc >> 8, fr = acc & 255;
    r += (fr > 128 || (fr == 128 && (r & 1))) ? 1 : 0;
    x2[o] = r;
  }
  int x3[32];
#pragma unroll
  for (int o = 0; o < 32; ++o) {
    int acc = bq1[o];
    for (int i = 0; i < 32; ++i) acc += x2[i] * wq1[o*32 + i];
    acc = clampi(acc, 0, 16256);
    int r = acc >> 7, fr = acc & 127;
    r += (fr > 64 || (fr == 64 && (r & 1))) ? 1 : 0;
    x3[o] = r;
  }
  for (int o = 0; o < 3; ++o) {
    int acc = bq2[o];
    for (int i = 0; i < 32; ++i) acc += x3[i] * wq2[o*32 + i];
    out[b*3 + o] = (float)acc / 16384.0f;
  }
}

__global__ void zero_kernel(float4* __restrict__ p, int n4) {
  int i = blockIdx.x * blockDim.x + threadIdx.x;
  if (i < n4) p[i] = make_float4(0.f, 0.f, 0.f, 0.f);
}

// ---------------------------------------------------------------------------
extern "C" void kernel_launch(void* const* d_in, const int* in_sizes, int n_in,
                              void* d_out, int out_size, void* d_ws, size_t ws_size,
                              hipStream_t stream)
{
  const float* x   = (const float*)d_in[0];
  const float* w0  = (const float*)d_in[1];
  const float* b0  = (const float*)d_in[2];
  const float* w1  = (const float*)d_in[3];
  const float* b1  = (const float*)d_in[4];
  const float* w2  = (const float*)d_in[5];
  const float* b2  = (const float*)d_in[6];
  const float* w3  = (const float*)d_in[7];
  const float* b3  = (const float*)d_in[8];
  const float* w4  = (const float*)d_in[9];
  const float* b4  = (const float*)d_in[10];
  const float* w5  = (const float*)d_in[11];
  const float* b5  = (const float*)d_in[12];
  const float* bn1 = (const float*)d_in[13];
  const float* bn2 = (const float*)d_in[14];
  const float* bn3 = (const float*)d_in[15];
  const float* bn4 = (const float*)d_in[16];
  const float* bn5 = (const float*)d_in[17];
  const float* vw0 = (const float*)d_in[18];
  const float* vb0 = (const float*)d_in[19];
  const float* vw1 = (const float*)d_in[20];
  const float* vb1 = (const float*)d_in[21];
  const float* vw2 = (const float*)d_in[22];
  const float* vb2 = (const float*)d_in[23];

  const int B = in_sizes[0] / 98;
  float* ws = (float*)d_ws;
  signed char* feat = (signed char*)d_ws + FEAT_OFF_BYTES;
  float* out = (float*)d_out;

  (void)hipFuncSetAttribute((const void*)conv_mfma,
                            hipFuncAttributeMaxDynamicSharedMemorySize, LDS_TOTAL);

  prep_kernel<<<(511395 + 255)/256, 256, 0, stream>>>(
      w0,b0,w1,b1,w2,b2,w3,b3,w4,b4,w5,b5,
      bn1,bn2,bn3,bn4,bn5, vw0,vb0,vw1,vb1,vw2,vb2, ws);

  conv_mfma<<<B, 512, LDS_TOTAL, stream>>>(
      x, (const char*)d_ws, feat, B, B/16);

  mlp_kernel<<<(B + 255)/256, 256, 0, stream>>>(feat, (const int*)d_ws + MLP_WORD_OFF, out, B);

  {
    int n4 = B*49/4;
    zero_kernel<<<(n4 + 255)/256, 256, 0, stream>>>((float4*)(out + 3*B), n4);
  }
}

// Round 4
// 2051.188 us; speedup vs baseline: 3.5486x; 1.0094x over previous
//
#include <hip/hip_runtime.h>
#include <stdint.h>

// ---------------------------------------------------------------------------
// FlatSquare7x7NNUEv4 — round 4: identical to round 3 (container died before
// benching it). Single change vs round 2: VGPR cap raised 128 -> 256
// (LDS already limits to 1 WG/CU, so regs are free) to eliminate the scratch
// spills seen as 1.65 GB WRITE_SIZE in round 2.
//   A·W = Ah·Wh + 2^-11*(Als·Wh + Ah·Wls)
// ---------------------------------------------------------------------------

typedef _Float16 f16x8 __attribute__((ext_vector_type(8)));
typedef float f32x4 __attribute__((ext_vector_type(4)));

// chunk tables: groups: [0..3]=g0, [4..11]=g1, [12..15]=g2
static __device__ __constant__ int CH_Y0[16] = {0,0,3,3, 0,1,3,2, 1,0,2,3, 1,1,2,2};
static __device__ __constant__ int CH_X0[16] = {0,3,3,0, 1,3,2,0, 0,2,3,1, 1,2,2,1};
static __device__ __constant__ int CH_K [16] = {0,1,2,3, 0,1,2,3, 0,1,2,3, 0,1,2,3};
static __device__ __constant__ int CH_T [16] = {0,0,0,0, 0,0,0,0, 1,1,1,1, 0,0,0,0};

// ---- LDS layout (bytes) ----
#define AH_OFF   0         // Ah  [144][128] f16 = 36864
#define AL_OFF   36864     // Als [144][128] f16 = 36864
#define WH_OFF   73728     // weight half H, 32KB
#define WL_OFF   106496    // weight half L, 32KB
#define XIN_OFF  139264    // [16][2][16] f32 = 2048
#define W0_OFF   141312    // [8][128] f32 = 4096
#define BIAS_OFF 145408    // [6][128] f32 = 3072
#define LDS_TOTAL 148480

// ---- global weight image (bytes within group) ----
#define G_STRIDE 678912
#define GW1   0
#define GW2   65536
#define GW3   327680
#define GW4   393216
#define GW5   655360
#define GW0   671744
#define GBIAS 675840
#define G_WORDS   167936     // f16 region words per group (656KB/4)
#define G_STRIDE_W 169728    // group stride in words
#define MLP_WORD_OFF 509184
#define FEAT_OFF_BYTES (2*1024*1024)

#define LO_SCALE 2048.0f
#define LO_INV   (1.0f/2048.0f)

__device__ __forceinline__ int swz(int b) { return b ^ (((b>>8)&7)<<4); }
__device__ __forceinline__ int base3(int z){ return (z>>1)*3 + (z&1); }
__device__ __forceinline__ int clampi(int v, int lo, int hi) { return v < lo ? lo : (v > hi ? hi : v); }

__device__ inline float bninv(const float* bn, int g, int C, int c) {
  float ga = bn[(g*4+0)*C + c];
  float va = bn[(g*4+3)*C + c];
  return ga / sqrtf(va + 1e-5f);
}
__device__ inline int q8(float x) { return clampi((int)rintf(x), -128, 127); }

// ---------------------------------------------------------------------------
// prep: fold BN, transpose to [oc][k], split f16 hi / lo*2^11, pre-swizzle
// ---------------------------------------------------------------------------
__global__ void prep_kernel(
    const float* __restrict__ w0, const float* __restrict__ b0,
    const float* __restrict__ w1, const float* __restrict__ b1,
    const float* __restrict__ w2, const float* __restrict__ b2,
    const float* __restrict__ w3, const float* __restrict__ b3,
    const float* __restrict__ w4, const float* __restrict__ b4,
    const float* __restrict__ w5, const float* __restrict__ b5,
    const float* __restrict__ bn1, const float* __restrict__ bn2,
    const float* __restrict__ bn3, const float* __restrict__ bn4,
    const float* __restrict__ bn5,
    const float* __restrict__ vw0, const float* __restrict__ vb0,
    const float* __restrict__ vw1, const float* __restrict__ vb1,
    const float* __restrict__ vw2, const float* __restrict__ vb2,
    float* __restrict__ ws)
{
  int idx = blockIdx.x * blockDim.x + threadIdx.x;
  if (idx < 3*G_WORDS) {
    uint32_t* wsU = (uint32_t*)ws;
    int g = idx / G_WORDS;
    int q = idx - g*G_WORDS;
    int stage, blk = 0, sub;
    if      (q < 16384)  { stage = 1; sub = q; }
    else if (q < 81920)  { stage = 2; blk = (q-16384)>>14; sub = (q-16384)&16383; }
    else if (q < 98304)  { stage = 3; sub = q-81920; }
    else if (q < 163840) { stage = 4; blk = (q-98304)>>14; sub = (q-98304)&16383; }
    else                 { stage = 5; sub = q-163840; }
    int isLo, r;
    if (stage == 5) { isLo = sub>>11; r = sub&2047; }
    else            { isLo = sub>>13; r = sub&8191; }
    int pb = r*4;
    int lb = pb ^ (((pb>>8)&7)<<4);     // inverse of kernel-side swizzle
    int oc = lb>>8;
    int k0 = (lb&255)>>1;               // even f16 index; word = (k0, k0+1)
    float inv, v0, v1;
    if (stage == 1) {
      inv = bninv(bn1,g,128,oc);
      v0 = w1[(g*128+oc)*128+k0]; v1 = w1[(g*128+oc)*128+k0+1];
    } else if (stage == 2) {
      inv = bninv(bn2,g,128,oc);
      v0 = w2[((g*128+oc)*128+k0)*4+blk]; v1 = w2[((g*128+oc)*128+k0+1)*4+blk];
    } else if (stage == 3) {
      inv = bninv(bn3,g,128,oc);
      v0 = w3[(g*128+oc)*128+k0]; v1 = w3[(g*128+oc)*128+k0+1];
    } else if (stage == 4) {
      inv = bninv(bn4,g,128,oc);
      v0 = w4[((g*128+oc)*128+k0)*4+blk]; v1 = w4[((g*128+oc)*128+k0+1)*4+blk];
    } else {
      inv = bninv(bn5,g,32,oc);
      v0 = w5[(g*32+oc)*128+k0]; v1 = w5[(g*32+oc)*128+k0+1];
    }
    v0 *= inv; v1 *= inv;
    _Float16 h0 = (_Float16)v0, h1 = (_Float16)v1;
    if (isLo) {
      h0 = (_Float16)((v0 - (float)h0) * LO_SCALE);
      h1 = (_Float16)((v1 - (float)h1) * LO_SCALE);
    }
    union { _Float16 h[2]; uint32_t u; } uu;
    uu.h[0] = h0; uu.h[1] = h1;
    wsU[g*G_STRIDE_W + q] = uu.u;
  } else if (idx < 506880) {            // w0: [k=8][c=128] fp32
    int e = idx - 503808; int g = e>>10; int t2 = e&1023;
    int k = t2>>7, c = t2&127;
    ws[g*G_STRIDE_W + 167936 + t2] = w0[((g*128 + c)*2 + (k>>2))*4 + (k&3)];
  } else if (idx < 509184) {            // folded biases [6][128] fp32
    int e = idx - 506880; int g = e/768; int r = e - g*768;
    int l = r>>7, c = r&127;
    float t;
    if (l == 0) {
      t = b0[g*128 + c];
    } else if (l < 5) {
      const float* bn = (l==1) ? bn1 : (l==2) ? bn2 : (l==3) ? bn3 : bn4;
      const float* bb = (l==1) ? b1  : (l==2) ? b2  : (l==3) ? b3  : b4;
      float inv = bninv(bn, g, 128, c);
      t = (bb[g*128 + c] - bn[(g*4+2)*128 + c]) * inv + bn[(g*4+1)*128 + c];
    } else {
      if (c < 32) {
        float inv = bninv(bn5, g, 32, c);
        t = (b5[g*32 + c] - bn5[(g*4+2)*32 + c]) * inv + bn5[(g*4+1)*32 + c];
      } else t = 0.f;
    }
    ws[g*G_STRIDE_W + 168960 + r] = t;
  } else if (idx < 511395) {            // quantized MLP ints
    int e = idx - MLP_WORD_OFF;
    int* wsI = (int*)ws;
    int val;
    if      (e < 1024) val = q8(vw0[e] * 256.f);
    else if (e < 1056) val = (int)rintf(vb0[e-1024] * 32768.f);
    else if (e < 2080) val = q8(vw1[e-1056] * 128.f);
    else if (e < 2112) val = (int)rintf(vb1[e-2080] * 16384.f);
    else if (e < 2208) val = q8(vw2[e-2112] * 128.f);
    else               val = (int)rintf(vb2[e-2208] * 16384.f);
    wsI[idx] = val;
  }
}

// ---------------------------------------------------------------------------
// fused MFMA conv stack
// ---------------------------------------------------------------------------
__device__ __forceinline__ f16x8 rdfrag(const char* base, int row, int ko) {
  return *(const f16x8*)(base + swz(row*256 + ko*2));
}

__device__ __forceinline__ void gl16(void* l, const void* g) {
  __builtin_amdgcn_global_load_lds(
      (const __attribute__((address_space(1))) void*)(uintptr_t)g,
      (__attribute__((address_space(3))) void*)(uint32_t)(uintptr_t)l,
      16, 0, 0);
}

__device__ __forceinline__ void stage(char* ldsbase, const char* gsrc, int bytes, int tid) {
  for (int off = tid*16; off < bytes; off += 8192)
    gl16(ldsbase + off, gsrc + off);
}

template<int MODE> __device__ __forceinline__ int arow(int r, int blk) {
  if (MODE == 0) return r;                                    // 1x1 convs
  if (MODE == 2) return (r>>2)*9 + base3(r&3) + base3(blk);   // conv2 gather
  return r*4 + blk;                                           // conv4 gather
}

#define MFMA(a,b,c) __builtin_amdgcn_mfma_f32_16x16x32_f16((a),(b),(c),0,0,0)

// Liveness-staged: Bh -> Ah -> acc1 MFMAs -> Al -> acc2 MFMAs, per kb.
template<int MT, int NT, int MODE>
__device__ __forceinline__ void phaseH(const char* AHb, const char* ALb, const char* Wb,
    int m0, int n0, int lane, int blk, f32x4 acc1[][NT], f32x4 acc2[][NT])
{
  const int l15 = lane & 15, kq = (lane >> 4) & 3;
#pragma unroll
  for (int kb = 0; kb < 4; ++kb) {
    const int ko = kb*32 + kq*8;
    f16x8 Bh_[NT];
#pragma unroll
    for (int n = 0; n < NT; ++n) Bh_[n] = rdfrag(Wb, (n0+n)*16 + l15, ko);
    {
      f16x8 Ah_[MT];
#pragma unroll
      for (int m = 0; m < MT; ++m)
        Ah_[m] = rdfrag(AHb, arow<MODE>((m0+m)*16 + l15, blk), ko);
#pragma unroll
      for (int m = 0; m < MT; ++m)
#pragma unroll
        for (int n = 0; n < NT; ++n)
          acc1[m][n] = MFMA(Ah_[m], Bh_[n], acc1[m][n]);
    }
    {
      f16x8 Al_[MT];
#pragma unroll
      for (int m = 0; m < MT; ++m)
        Al_[m] = rdfrag(ALb, arow<MODE>((m0+m)*16 + l15, blk), ko);
#pragma unroll
      for (int m = 0; m < MT; ++m)
#pragma unroll
        for (int n = 0; n < NT; ++n)
          acc2[m][n] = MFMA(Al_[m], Bh_[n], acc2[m][n]);
    }
  }
}

template<int MT, int NT, int MODE>
__device__ __forceinline__ void phaseL(const char* AHb, const char* Wb,
    int m0, int n0, int lane, int blk, f32x4 acc2[][NT])
{
  const int l15 = lane & 15, kq = (lane >> 4) & 3;
#pragma unroll
  for (int kb = 0; kb < 4; ++kb) {
    const int ko = kb*32 + kq*8;
    f16x8 Ah_[MT], Bl_[NT];
#pragma unroll
    for (int n = 0; n < NT; ++n) Bl_[n] = rdfrag(Wb, (n0+n)*16 + l15, ko);
#pragma unroll
    for (int m = 0; m < MT; ++m)
      Ah_[m] = rdfrag(AHb, arow<MODE>((m0+m)*16 + l15, blk), ko);
#pragma unroll
    for (int m = 0; m < MT; ++m)
#pragma unroll
      for (int n = 0; n < NT; ++n)
        acc2[m][n] = MFMA(Ah_[m], Bl_[n], acc2[m][n]);
  }
}

__device__ __forceinline__ void wbval(char* ah, char* al, int row, int col, float v) {
  _Float16 h = (_Float16)v;
  _Float16 l = (_Float16)((v - (float)h) * LO_SCALE);
  int sb = swz(row*256 + col*2);
  *(_Float16*)(ah + sb) = h;
  *(_Float16*)(al + sb) = l;
}

template<int MT, int NT>
__device__ __forceinline__ void writeback(char* AHb, char* ALb, const float* bias,
    int layer, int m0, int n0, int lane, f32x4 acc1[][NT], f32x4 acc2[][NT])
{
  const int l15 = lane & 15, rq = (lane >> 4) & 3;
#pragma unroll
  for (int m = 0; m < MT; ++m)
#pragma unroll
    for (int n = 0; n < NT; ++n) {
      int col = (n0+n)*16 + l15;
      float bb = bias[layer*128 + col];
#pragma unroll
      for (int q = 0; q < 4; ++q) {
        int row = (m0+m)*16 + rq*4 + q;
        float v = acc1[m][n][q] + acc2[m][n][q]*LO_INV + bb;
        v = fmaxf(v, 0.f);
        wbval(AHb, ALb, row, col, v);
      }
    }
}

__global__ __launch_bounds__(512) __attribute__((amdgpu_waves_per_eu(2)))
void conv_mfma(
    const float* __restrict__ x, const char* __restrict__ wsb,
    signed char* __restrict__ feat, int B, int wgPerChunk)
{
  extern __shared__ char lds[];
  char* AHb = lds + AH_OFF;
  char* ALb = lds + AL_OFF;
  char* WHb = lds + WH_OFF;
  char* WLb = lds + WL_OFF;
  const float* bias = (const float*)(lds + BIAS_OFF);

  const int tid  = threadIdx.x;
  const int lane = tid & 63;
  const int wave = tid >> 6;

  const int wg = blockIdx.x;
  const int chunkG = wg / wgPerChunk;
  const int b0 = (wg - chunkG*wgPerChunk) * 16;
  const int g = (chunkG < 4) ? 0 : (chunkG < 12) ? 1 : 2;
  const char* gw = wsb + g*G_STRIDE;

  // ---- prologue staging ----
  {
    int s = tid >> 5, v = tid & 31;
    int ic = v >> 4, pos = v & 15;
    int i = pos >> 2, j = pos & 3;
    int tt = CH_T[chunkG], kk = CH_K[chunkG];
    int a = tt ? j : i, bb2 = tt ? i : j;
    int py, px;
    if      (kk == 0) { py = a;     px = bb2;   }
    else if (kk == 1) { py = bb2;   px = 3-a;   }
    else if (kk == 2) { py = 3-a;   px = 3-bb2; }
    else              { py = 3-bb2; px = a;     }
    int sy = CH_Y0[chunkG] + py, sx = CH_X0[chunkG] + px;
    ((float*)(lds+XIN_OFF))[s*32 + v] = x[((b0+s)*2 + ic)*49 + sy*7 + sx];
  }
  if (tid < 256) ((float4*)(lds+W0_OFF))[tid]   = ((const float4*)(gw+GW0))[tid];
  if (tid < 192) ((float4*)(lds+BIAS_OFF))[tid] = ((const float4*)(gw+GBIAS))[tid];
  stage(WHb, gw+GW1,       32768, tid);   // w1 hi
  stage(WLb, gw+GW1+32768, 32768, tid);   // w1 lo
  __syncthreads();

  // ---- conv0 (VALU, K=8) ----
  {
    const float* xin = (const float*)(lds+XIN_OFF);
    const float* w0s = (const float*)(lds+W0_OFF);
    int c = tid & 127;
    float wr[8];
#pragma unroll
    for (int k = 0; k < 8; ++k) wr[k] = w0s[k*128 + c];
    float b0c = bias[c];
    int sg = tid >> 7;
#pragma unroll
    for (int si = 0; si < 4; ++si) {
      int s = sg*4 + si;
      float xv[32];
#pragma unroll
      for (int t2 = 0; t2 < 32; ++t2) xv[t2] = xin[s*32 + t2];
#pragma unroll
      for (int oy = 0; oy < 3; ++oy)
#pragma unroll
        for (int ox = 0; ox < 3; ++ox) {
          float acc0 = b0c;
#pragma unroll
          for (int ic2 = 0; ic2 < 2; ++ic2)
#pragma unroll
            for (int dy = 0; dy < 2; ++dy)
#pragma unroll
              for (int dx = 0; dx < 2; ++dx)
                acc0 = fmaf(xv[ic2*16 + (oy+dy)*4 + ox+dx], wr[ic2*4+dy*2+dx], acc0);
          wbval(AHb, ALb, s*9 + oy*3 + ox, c, fmaxf(acc0, 0.f));
        }
    }
  }
  __syncthreads();                              // act ready, w1 ready

  // ---- conv1: rows 144 (9 M-tiles), wave grid 2x4 (tile 4 overlaps: benign) ----
  {
    const int m0 = (wave >> 2) * 4;
    const int n0 = (wave & 3) * 2;
    f32x4 acc1[5][2] = {}; f32x4 acc2[5][2] = {};
    phaseH<5,2,0>(AHb, ALb, WHb, m0, n0, lane, 0, acc1, acc2);
    __syncthreads();
    stage(WHb, gw+GW2, 32768, tid);             // w2 blk0 hi
    phaseL<5,2,0>(AHb, WLb, m0, n0, lane, 0, acc2);
    __syncthreads();
    stage(WLb, gw+GW2+32768, 32768, tid);       // w2 blk0 lo
    writeback<5,2>(AHb, ALb, bias, 1, m0, n0, lane, acc1, acc2);
  }
  __syncthreads();

  // ---- conv2: out 64 rows, K=512 (4 gathered blocks) ----
  {
    const int m0 = (wave >> 2) * 2;
    const int n0 = (wave & 3) * 2;
    f32x4 acc1[2][2] = {}; f32x4 acc2[2][2] = {};
#pragma unroll
    for (int blk = 0; blk < 4; ++blk) {
      phaseH<2,2,2>(AHb, ALb, WHb, m0, n0, lane, blk, acc1, acc2);
      __syncthreads();
      if (blk < 3) stage(WHb, gw+GW2+(blk+1)*65536, 32768, tid);
      else         stage(WHb, gw+GW3, 32768, tid);
      phaseL<2,2,2>(AHb, WLb, m0, n0, lane, blk, acc2);
      __syncthreads();
      if (blk < 3) stage(WLb, gw+GW2+(blk+1)*65536+32768, 32768, tid);
      else         stage(WLb, gw+GW3+32768, 32768, tid);
    }
    writeback<2,2>(AHb, ALb, bias, 2, m0, n0, lane, acc1, acc2);
  }
  __syncthreads();

  // ---- conv3: rows 64, 1x1 ----
  {
    const int m0 = (wave >> 2) * 2;
    const int n0 = (wave & 3) * 2;
    f32x4 acc1[2][2] = {}; f32x4 acc2[2][2] = {};
    phaseH<2,2,0>(AHb, ALb, WHb, m0, n0, lane, 0, acc1, acc2);
    __syncthreads();
    stage(WHb, gw+GW4, 32768, tid);             // w4 blk0 hi
    phaseL<2,2,0>(AHb, WLb, m0, n0, lane, 0, acc2);
    __syncthreads();
    stage(WLb, gw+GW4+32768, 32768, tid);       // w4 blk0 lo
    writeback<2,2>(AHb, ALb, bias, 3, m0, n0, lane, acc1, acc2);
  }
  __syncthreads();

  // ---- conv4: out 16 rows, K=512 (4 gathered blocks), 1 tile/wave ----
  {
    const int n0 = wave;
    f32x4 acc1[1][1] = {}; f32x4 acc2[1][1] = {};
#pragma unroll
    for (int blk = 0; blk < 4; ++blk) {
      phaseH<1,1,4>(AHb, ALb, WHb, 0, n0, lane, blk, acc1, acc2);
      __syncthreads();
      if (blk < 3) stage(WHb, gw+GW4+(blk+1)*65536, 32768, tid);
      else         stage(WHb, gw+GW5, 8192, tid);        // w5 hi (8KB)
      phaseL<1,1,4>(AHb, WLb, 0, n0, lane, blk, acc2);
      __syncthreads();
      if (blk < 3) stage(WLb, gw+GW4+(blk+1)*65536+32768, 32768, tid);
      else         stage(WLb, gw+GW5+8192, 8192, tid);   // w5 lo (8KB)
    }
    writeback<1,1>(AHb, ALb, bias, 4, 0, n0, lane, acc1, acc2);
  }
  __syncthreads();

  // ---- conv5: 128 -> 32, quantize features (waves 0,1 only; no barriers) ----
  if (wave < 2) {
    f32x4 acc1[1][1] = {}; f32x4 acc2[1][1] = {};
    phaseH<1,1,0>(AHb, ALb, WHb, 0, wave, lane, 0, acc1, acc2);
    phaseL<1,1,0>(AHb, WLb, 0, wave, lane, 0, acc2);
    int c = wave*16 + (lane & 15);
    float bb = bias[5*128 + c];
#pragma unroll
    for (int q = 0; q < 4; ++q) {
      int s = ((lane >> 4) & 3)*4 + q;
      float f = acc1[0][0][q] + acc2[0][0][q]*LO_INV + bb;
      f = fminf(fmaxf(f, -1.0f), 127.0f/128.0f);
      int qi = clampi((int)rintf(f * 128.0f), -128, 127);
      feat[((long)chunkG*B + b0 + s)*32 + c] = (signed char)qi;
    }
  }
}

// ---------------------------------------------------------------------------
// value MLP: exact integer arithmetic (unchanged, verified round 1)
// ---------------------------------------------------------------------------
__global__ __launch_bounds__(256) void mlp_kernel(
    const signed char* __restrict__ feat,
    const int* __restrict__ mw,
    float* __restrict__ out, int B)
{
  int b = blockIdx.x * blockDim.x + threadIdx.x;
  if (b >= B) return;
  int S[32];
#pragma unroll
  for (int c = 0; c < 32; ++c) S[c] = 0;
  for (int ch = 0; ch < 16; ++ch) {
    const signed char* f = feat + ((long)ch*B + b)*32;
#pragma unroll
    for (int c = 0; c < 32; ++c) S[c] += f[c];
  }
  int x1[32];
#pragma unroll
  for (int c = 0; c < 32; ++c) x1[c] = clampi(S[c], -128, 127);

  const int* wq0 = mw;        const int* bq0 = mw + 1024;
  const int* wq1 = mw + 1056; const int* bq1 = mw + 2080;
  const int* wq2 = mw + 2112; const int* bq2 = mw + 2208;

  int x2[32];
#pragma unroll
  for (int o = 0; o < 32; ++o) {
    int acc = bq0[o];
    for (int i = 0; i < 32; ++i) acc += x1[i] * wq0[o*32 + i];
    acc = clampi(acc, 0, 32512);
    int r = acc >> 8, fr = acc & 255;
    r += (fr > 128 || (fr == 128 && (r & 1))) ? 1 : 0;
    x2[o] = r;
  }
  int x3[32];
#pragma unroll
  for (int o = 0; o < 32; ++o) {
    int acc = bq1[o];
    for (int i = 0; i < 32; ++i) acc += x2[i] * wq1[o*32 + i];
    acc = clampi(acc, 0, 16256);
    int r = acc >> 7, fr = acc & 127;
    r += (fr > 64 || (fr == 64 && (r & 1))) ? 1 : 0;
    x3[o] = r;
  }
  for (int o = 0; o < 3; ++o) {
    int acc = bq2[o];
    for (int i = 0; i < 32; ++i) acc += x3[i] * wq2[o*32 + i];
    out[b*3 + o] = (float)acc / 16384.0f;
  }
}

__global__ void zero_kernel(float4* __restrict__ p, int n4) {
  int i = blockIdx.x * blockDim.x + threadIdx.x;
  if (i < n4) p[i] = make_float4(0.f, 0.f, 0.f, 0.f);
}

// ---------------------------------------------------------------------------
extern "C" void kernel_launch(void* const* d_in, const int* in_sizes, int n_in,
                              void* d_out, int out_size, void* d_ws, size_t ws_size,
                              hipStream_t stream)
{
  const float* x   = (const float*)d_in[0];
  const float* w0  = (const float*)d_in[1];
  const float* b0  = (const float*)d_in[2];
  const float* w1  = (const float*)d_in[3];
  const float* b1  = (const float*)d_in[4];
  const float* w2  = (const float*)d_in[5];
  const float* b2  = (const float*)d_in[6];
  const float* w3  = (const float*)d_in[7];
  const float* b3  = (const float*)d_in[8];
  const float* w4  = (const float*)d_in[9];
  const float* b4  = (const float*)d_in[10];
  const float* w5  = (const float*)d_in[11];
  const float* b5  = (const float*)d_in[12];
  const float* bn1 = (const float*)d_in[13];
  const float* bn2 = (const float*)d_in[14];
  const float* bn3 = (const float*)d_in[15];
  const float* bn4 = (const float*)d_in[16];
  const float* bn5 = (const float*)d_in[17];
  const float* vw0 = (const float*)d_in[18];
  const float* vb0 = (const float*)d_in[19];
  const float* vw1 = (const float*)d_in[20];
  const float* vb1 = (const float*)d_in[21];
  const float* vw2 = (const float*)d_in[22];
  const float* vb2 = (const float*)d_in[23];

  const int B = in_sizes[0] / 98;
  float* ws = (float*)d_ws;
  signed char* feat = (signed char*)d_ws + FEAT_OFF_BYTES;
  float* out = (float*)d_out;

  (void)hipFuncSetAttribute((const void*)conv_mfma,
                            hipFuncAttributeMaxDynamicSharedMemorySize, LDS_TOTAL);

  prep_kernel<<<(511395 + 255)/256, 256, 0, stream>>>(
      w0,b0,w1,b1,w2,b2,w3,b3,w4,b4,w5,b5,
      bn1,bn2,bn3,bn4,bn5, vw0,vb0,vw1,vb1,vw2,vb2, ws);

  conv_mfma<<<B, 512, LDS_TOTAL, stream>>>(
      x, (const char*)d_ws, feat, B, B/16);

  mlp_kernel<<<(B + 255)/256, 256, 0, stream>>>(feat, (const int*)d_ws + MLP_WORD_OFF, out, B);

  {
    int n4 = B*49/4;
    zero_kernel<<<(n4 + 255)/256, 256, 0, stream>>>((float4*)(out + 3*B), n4);
  }
}

// Round 5
// 2051.007 us; speedup vs baseline: 3.5489x; 1.0001x over previous
//
#include <hip/hip_runtime.h>
#include <stdint.h>

// ---------------------------------------------------------------------------
// FlatSquare7x7NNUEv4 — round 5: identical to round 4 except the launch
// attribute: __launch_bounds__(512, 1). Evidence-fitted model: hipcc lowers
// the 2nd arg as blocks/CU (arg 2 -> 4 waves/SIMD -> 128 VGPR cap, matching
// rounds 2/4); arg 1 -> 2 waves/SIMD -> 256 VGPR cap. LDS (148KB) already
// limits to 1 WG/CU = 2 waves/SIMD, so the cap raise is occupancy-free and
// should eliminate the ~1.6 GB/dispatch scratch spill traffic.
//   A·W = Ah·Wh + 2^-11*(Als·Wh + Ah·Wls)
// ---------------------------------------------------------------------------

typedef _Float16 f16x8 __attribute__((ext_vector_type(8)));
typedef float f32x4 __attribute__((ext_vector_type(4)));

// chunk tables: groups: [0..3]=g0, [4..11]=g1, [12..15]=g2
static __device__ __constant__ int CH_Y0[16] = {0,0,3,3, 0,1,3,2, 1,0,2,3, 1,1,2,2};
static __device__ __constant__ int CH_X0[16] = {0,3,3,0, 1,3,2,0, 0,2,3,1, 1,2,2,1};
static __device__ __constant__ int CH_K [16] = {0,1,2,3, 0,1,2,3, 0,1,2,3, 0,1,2,3};
static __device__ __constant__ int CH_T [16] = {0,0,0,0, 0,0,0,0, 1,1,1,1, 0,0,0,0};

// ---- LDS layout (bytes) ----
#define AH_OFF   0         // Ah  [144][128] f16 = 36864
#define AL_OFF   36864     // Als [144][128] f16 = 36864
#define WH_OFF   73728     // weight half H, 32KB
#define WL_OFF   106496    // weight half L, 32KB
#define XIN_OFF  139264    // [16][2][16] f32 = 2048
#define W0_OFF   141312    // [8][128] f32 = 4096
#define BIAS_OFF 145408    // [6][128] f32 = 3072
#define LDS_TOTAL 148480

// ---- global weight image (bytes within group) ----
#define G_STRIDE 678912
#define GW1   0
#define GW2   65536
#define GW3   327680
#define GW4   393216
#define GW5   655360
#define GW0   671744
#define GBIAS 675840
#define G_WORDS   167936     // f16 region words per group (656KB/4)
#define G_STRIDE_W 169728    // group stride in words
#define MLP_WORD_OFF 509184
#define FEAT_OFF_BYTES (2*1024*1024)

#define LO_SCALE 2048.0f
#define LO_INV   (1.0f/2048.0f)

__device__ __forceinline__ int swz(int b) { return b ^ (((b>>8)&7)<<4); }
__device__ __forceinline__ int base3(int z){ return (z>>1)*3 + (z&1); }
__device__ __forceinline__ int clampi(int v, int lo, int hi) { return v < lo ? lo : (v > hi ? hi : v); }

__device__ inline float bninv(const float* bn, int g, int C, int c) {
  float ga = bn[(g*4+0)*C + c];
  float va = bn[(g*4+3)*C + c];
  return ga / sqrtf(va + 1e-5f);
}
__device__ inline int q8(float x) { return clampi((int)rintf(x), -128, 127); }

// ---------------------------------------------------------------------------
// prep: fold BN, transpose to [oc][k], split f16 hi / lo*2^11, pre-swizzle
// ---------------------------------------------------------------------------
__global__ void prep_kernel(
    const float* __restrict__ w0, const float* __restrict__ b0,
    const float* __restrict__ w1, const float* __restrict__ b1,
    const float* __restrict__ w2, const float* __restrict__ b2,
    const float* __restrict__ w3, const float* __restrict__ b3,
    const float* __restrict__ w4, const float* __restrict__ b4,
    const float* __restrict__ w5, const float* __restrict__ b5,
    const float* __restrict__ bn1, const float* __restrict__ bn2,
    const float* __restrict__ bn3, const float* __restrict__ bn4,
    const float* __restrict__ bn5,
    const float* __restrict__ vw0, const float* __restrict__ vb0,
    const float* __restrict__ vw1, const float* __restrict__ vb1,
    const float* __restrict__ vw2, const float* __restrict__ vb2,
    float* __restrict__ ws)
{
  int idx = blockIdx.x * blockDim.x + threadIdx.x;
  if (idx < 3*G_WORDS) {
    uint32_t* wsU = (uint32_t*)ws;
    int g = idx / G_WORDS;
    int q = idx - g*G_WORDS;
    int stage, blk = 0, sub;
    if      (q < 16384)  { stage = 1; sub = q; }
    else if (q < 81920)  { stage = 2; blk = (q-16384)>>14; sub = (q-16384)&16383; }
    else if (q < 98304)  { stage = 3; sub = q-81920; }
    else if (q < 163840) { stage = 4; blk = (q-98304)>>14; sub = (q-98304)&16383; }
    else                 { stage = 5; sub = q-163840; }
    int isLo, r;
    if (stage == 5) { isLo = sub>>11; r = sub&2047; }
    else            { isLo = sub>>13; r = sub&8191; }
    int pb = r*4;
    int lb = pb ^ (((pb>>8)&7)<<4);     // inverse of kernel-side swizzle
    int oc = lb>>8;
    int k0 = (lb&255)>>1;               // even f16 index; word = (k0, k0+1)
    float inv, v0, v1;
    if (stage == 1) {
      inv = bninv(bn1,g,128,oc);
      v0 = w1[(g*128+oc)*128+k0]; v1 = w1[(g*128+oc)*128+k0+1];
    } else if (stage == 2) {
      inv = bninv(bn2,g,128,oc);
      v0 = w2[((g*128+oc)*128+k0)*4+blk]; v1 = w2[((g*128+oc)*128+k0+1)*4+blk];
    } else if (stage == 3) {
      inv = bninv(bn3,g,128,oc);
      v0 = w3[(g*128+oc)*128+k0]; v1 = w3[(g*128+oc)*128+k0+1];
    } else if (stage == 4) {
      inv = bninv(bn4,g,128,oc);
      v0 = w4[((g*128+oc)*128+k0)*4+blk]; v1 = w4[((g*128+oc)*128+k0+1)*4+blk];
    } else {
      inv = bninv(bn5,g,32,oc);
      v0 = w5[(g*32+oc)*128+k0]; v1 = w5[(g*32+oc)*128+k0+1];
    }
    v0 *= inv; v1 *= inv;
    _Float16 h0 = (_Float16)v0, h1 = (_Float16)v1;
    if (isLo) {
      h0 = (_Float16)((v0 - (float)h0) * LO_SCALE);
      h1 = (_Float16)((v1 - (float)h1) * LO_SCALE);
    }
    union { _Float16 h[2]; uint32_t u; } uu;
    uu.h[0] = h0; uu.h[1] = h1;
    wsU[g*G_STRIDE_W + q] = uu.u;
  } else if (idx < 506880) {            // w0: [k=8][c=128] fp32
    int e = idx - 503808; int g = e>>10; int t2 = e&1023;
    int k = t2>>7, c = t2&127;
    ws[g*G_STRIDE_W + 167936 + t2] = w0[((g*128 + c)*2 + (k>>2))*4 + (k&3)];
  } else if (idx < 509184) {            // folded biases [6][128] fp32
    int e = idx - 506880; int g = e/768; int r = e - g*768;
    int l = r>>7, c = r&127;
    float t;
    if (l == 0) {
      t = b0[g*128 + c];
    } else if (l < 5) {
      const float* bn = (l==1) ? bn1 : (l==2) ? bn2 : (l==3) ? bn3 : bn4;
      const float* bb = (l==1) ? b1  : (l==2) ? b2  : (l==3) ? b3  : b4;
      float inv = bninv(bn, g, 128, c);
      t = (bb[g*128 + c] - bn[(g*4+2)*128 + c]) * inv + bn[(g*4+1)*128 + c];
    } else {
      if (c < 32) {
        float inv = bninv(bn5, g, 32, c);
        t = (b5[g*32 + c] - bn5[(g*4+2)*32 + c]) * inv + bn5[(g*4+1)*32 + c];
      } else t = 0.f;
    }
    ws[g*G_STRIDE_W + 168960 + r] = t;
  } else if (idx < 511395) {            // quantized MLP ints
    int e = idx - MLP_WORD_OFF;
    int* wsI = (int*)ws;
    int val;
    if      (e < 1024) val = q8(vw0[e] * 256.f);
    else if (e < 1056) val = (int)rintf(vb0[e-1024] * 32768.f);
    else if (e < 2080) val = q8(vw1[e-1056] * 128.f);
    else if (e < 2112) val = (int)rintf(vb1[e-2080] * 16384.f);
    else if (e < 2208) val = q8(vw2[e-2112] * 128.f);
    else               val = (int)rintf(vb2[e-2208] * 16384.f);
    wsI[idx] = val;
  }
}

// ---------------------------------------------------------------------------
// fused MFMA conv stack
// ---------------------------------------------------------------------------
__device__ __forceinline__ f16x8 rdfrag(const char* base, int row, int ko) {
  return *(const f16x8*)(base + swz(row*256 + ko*2));
}

__device__ __forceinline__ void gl16(void* l, const void* g) {
  __builtin_amdgcn_global_load_lds(
      (const __attribute__((address_space(1))) void*)(uintptr_t)g,
      (__attribute__((address_space(3))) void*)(uint32_t)(uintptr_t)l,
      16, 0, 0);
}

__device__ __forceinline__ void stage(char* ldsbase, const char* gsrc, int bytes, int tid) {
  for (int off = tid*16; off < bytes; off += 8192)
    gl16(ldsbase + off, gsrc + off);
}

template<int MODE> __device__ __forceinline__ int arow(int r, int blk) {
  if (MODE == 0) return r;                                    // 1x1 convs
  if (MODE == 2) return (r>>2)*9 + base3(r&3) + base3(blk);   // conv2 gather
  return r*4 + blk;                                           // conv4 gather
}

#define MFMA(a,b,c) __builtin_amdgcn_mfma_f32_16x16x32_f16((a),(b),(c),0,0,0)

// Liveness-staged: Bh -> Ah -> acc1 MFMAs -> Al -> acc2 MFMAs, per kb.
template<int MT, int NT, int MODE>
__device__ __forceinline__ void phaseH(const char* AHb, const char* ALb, const char* Wb,
    int m0, int n0, int lane, int blk, f32x4 acc1[][NT], f32x4 acc2[][NT])
{
  const int l15 = lane & 15, kq = (lane >> 4) & 3;
#pragma unroll
  for (int kb = 0; kb < 4; ++kb) {
    const int ko = kb*32 + kq*8;
    f16x8 Bh_[NT];
#pragma unroll
    for (int n = 0; n < NT; ++n) Bh_[n] = rdfrag(Wb, (n0+n)*16 + l15, ko);
    {
      f16x8 Ah_[MT];
#pragma unroll
      for (int m = 0; m < MT; ++m)
        Ah_[m] = rdfrag(AHb, arow<MODE>((m0+m)*16 + l15, blk), ko);
#pragma unroll
      for (int m = 0; m < MT; ++m)
#pragma unroll
        for (int n = 0; n < NT; ++n)
          acc1[m][n] = MFMA(Ah_[m], Bh_[n], acc1[m][n]);
    }
    {
      f16x8 Al_[MT];
#pragma unroll
      for (int m = 0; m < MT; ++m)
        Al_[m] = rdfrag(ALb, arow<MODE>((m0+m)*16 + l15, blk), ko);
#pragma unroll
      for (int m = 0; m < MT; ++m)
#pragma unroll
        for (int n = 0; n < NT; ++n)
          acc2[m][n] = MFMA(Al_[m], Bh_[n], acc2[m][n]);
    }
  }
}

template<int MT, int NT, int MODE>
__device__ __forceinline__ void phaseL(const char* AHb, const char* Wb,
    int m0, int n0, int lane, int blk, f32x4 acc2[][NT])
{
  const int l15 = lane & 15, kq = (lane >> 4) & 3;
#pragma unroll
  for (int kb = 0; kb < 4; ++kb) {
    const int ko = kb*32 + kq*8;
    f16x8 Ah_[MT], Bl_[NT];
#pragma unroll
    for (int n = 0; n < NT; ++n) Bl_[n] = rdfrag(Wb, (n0+n)*16 + l15, ko);
#pragma unroll
    for (int m = 0; m < MT; ++m)
      Ah_[m] = rdfrag(AHb, arow<MODE>((m0+m)*16 + l15, blk), ko);
#pragma unroll
    for (int m = 0; m < MT; ++m)
#pragma unroll
      for (int n = 0; n < NT; ++n)
        acc2[m][n] = MFMA(Ah_[m], Bl_[n], acc2[m][n]);
  }
}

__device__ __forceinline__ void wbval(char* ah, char* al, int row, int col, float v) {
  _Float16 h = (_Float16)v;
  _Float16 l = (_Float16)((v - (float)h) * LO_SCALE);
  int sb = swz(row*256 + col*2);
  *(_Float16*)(ah + sb) = h;
  *(_Float16*)(al + sb) = l;
}

template<int MT, int NT>
__device__ __forceinline__ void writeback(char* AHb, char* ALb, const float* bias,
    int layer, int m0, int n0, int lane, f32x4 acc1[][NT], f32x4 acc2[][NT])
{
  const int l15 = lane & 15, rq = (lane >> 4) & 3;
#pragma unroll
  for (int m = 0; m < MT; ++m)
#pragma unroll
    for (int n = 0; n < NT; ++n) {
      int col = (n0+n)*16 + l15;
      float bb = bias[layer*128 + col];
#pragma unroll
      for (int q = 0; q < 4; ++q) {
        int row = (m0+m)*16 + rq*4 + q;
        float v = acc1[m][n][q] + acc2[m][n][q]*LO_INV + bb;
        v = fmaxf(v, 0.f);
        wbval(AHb, ALb, row, col, v);
      }
    }
}

__global__ __launch_bounds__(512, 1)
void conv_mfma(
    const float* __restrict__ x, const char* __restrict__ wsb,
    signed char* __restrict__ feat, int B, int wgPerChunk)
{
  extern __shared__ char lds[];
  char* AHb = lds + AH_OFF;
  char* ALb = lds + AL_OFF;
  char* WHb = lds + WH_OFF;
  char* WLb = lds + WL_OFF;
  const float* bias = (const float*)(lds + BIAS_OFF);

  const int tid  = threadIdx.x;
  const int lane = tid & 63;
  const int wave = tid >> 6;

  const int wg = blockIdx.x;
  const int chunkG = wg / wgPerChunk;
  const int b0 = (wg - chunkG*wgPerChunk) * 16;
  const int g = (chunkG < 4) ? 0 : (chunkG < 12) ? 1 : 2;
  const char* gw = wsb + g*G_STRIDE;

  // ---- prologue staging ----
  {
    int s = tid >> 5, v = tid & 31;
    int ic = v >> 4, pos = v & 15;
    int i = pos >> 2, j = pos & 3;
    int tt = CH_T[chunkG], kk = CH_K[chunkG];
    int a = tt ? j : i, bb2 = tt ? i : j;
    int py, px;
    if      (kk == 0) { py = a;     px = bb2;   }
    else if (kk == 1) { py = bb2;   px = 3-a;   }
    else if (kk == 2) { py = 3-a;   px = 3-bb2; }
    else              { py = 3-bb2; px = a;     }
    int sy = CH_Y0[chunkG] + py, sx = CH_X0[chunkG] + px;
    ((float*)(lds+XIN_OFF))[s*32 + v] = x[((b0+s)*2 + ic)*49 + sy*7 + sx];
  }
  if (tid < 256) ((float4*)(lds+W0_OFF))[tid]   = ((const float4*)(gw+GW0))[tid];
  if (tid < 192) ((float4*)(lds+BIAS_OFF))[tid] = ((const float4*)(gw+GBIAS))[tid];
  stage(WHb, gw+GW1,       32768, tid);   // w1 hi
  stage(WLb, gw+GW1+32768, 32768, tid);   // w1 lo
  __syncthreads();

  // ---- conv0 (VALU, K=8) ----
  {
    const float* xin = (const float*)(lds+XIN_OFF);
    const float* w0s = (const float*)(lds+W0_OFF);
    int c = tid & 127;
    float wr[8];
#pragma unroll
    for (int k = 0; k < 8; ++k) wr[k] = w0s[k*128 + c];
    float b0c = bias[c];
    int sg = tid >> 7;
#pragma unroll
    for (int si = 0; si < 4; ++si) {
      int s = sg*4 + si;
      float xv[32];
#pragma unroll
      for (int t2 = 0; t2 < 32; ++t2) xv[t2] = xin[s*32 + t2];
#pragma unroll
      for (int oy = 0; oy < 3; ++oy)
#pragma unroll
        for (int ox = 0; ox < 3; ++ox) {
          float acc0 = b0c;
#pragma unroll
          for (int ic2 = 0; ic2 < 2; ++ic2)
#pragma unroll
            for (int dy = 0; dy < 2; ++dy)
#pragma unroll
              for (int dx = 0; dx < 2; ++dx)
                acc0 = fmaf(xv[ic2*16 + (oy+dy)*4 + ox+dx], wr[ic2*4+dy*2+dx], acc0);
          wbval(AHb, ALb, s*9 + oy*3 + ox, c, fmaxf(acc0, 0.f));
        }
    }
  }
  __syncthreads();                              // act ready, w1 ready

  // ---- conv1: rows 144 (9 M-tiles), wave grid 2x4 (tile 4 overlaps: benign) ----
  {
    const int m0 = (wave >> 2) * 4;
    const int n0 = (wave & 3) * 2;
    f32x4 acc1[5][2] = {}; f32x4 acc2[5][2] = {};
    phaseH<5,2,0>(AHb, ALb, WHb, m0, n0, lane, 0, acc1, acc2);
    __syncthreads();
    stage(WHb, gw+GW2, 32768, tid);             // w2 blk0 hi
    phaseL<5,2,0>(AHb, WLb, m0, n0, lane, 0, acc2);
    __syncthreads();
    stage(WLb, gw+GW2+32768, 32768, tid);       // w2 blk0 lo
    writeback<5,2>(AHb, ALb, bias, 1, m0, n0, lane, acc1, acc2);
  }
  __syncthreads();

  // ---- conv2: out 64 rows, K=512 (4 gathered blocks) ----
  {
    const int m0 = (wave >> 2) * 2;
    const int n0 = (wave & 3) * 2;
    f32x4 acc1[2][2] = {}; f32x4 acc2[2][2] = {};
#pragma unroll
    for (int blk = 0; blk < 4; ++blk) {
      phaseH<2,2,2>(AHb, ALb, WHb, m0, n0, lane, blk, acc1, acc2);
      __syncthreads();
      if (blk < 3) stage(WHb, gw+GW2+(blk+1)*65536, 32768, tid);
      else         stage(WHb, gw+GW3, 32768, tid);
      phaseL<2,2,2>(AHb, WLb, m0, n0, lane, blk, acc2);
      __syncthreads();
      if (blk < 3) stage(WLb, gw+GW2+(blk+1)*65536+32768, 32768, tid);
      else         stage(WLb, gw+GW3+32768, 32768, tid);
    }
    writeback<2,2>(AHb, ALb, bias, 2, m0, n0, lane, acc1, acc2);
  }
  __syncthreads();

  // ---- conv3: rows 64, 1x1 ----
  {
    const int m0 = (wave >> 2) * 2;
    const int n0 = (wave & 3) * 2;
    f32x4 acc1[2][2] = {}; f32x4 acc2[2][2] = {};
    phaseH<2,2,0>(AHb, ALb, WHb, m0, n0, lane, 0, acc1, acc2);
    __syncthreads();
    stage(WHb, gw+GW4, 32768, tid);             // w4 blk0 hi
    phaseL<2,2,0>(AHb, WLb, m0, n0, lane, 0, acc2);
    __syncthreads();
    stage(WLb, gw+GW4+32768, 32768, tid);       // w4 blk0 lo
    writeback<2,2>(AHb, ALb, bias, 3, m0, n0, lane, acc1, acc2);
  }
  __syncthreads();

  // ---- conv4: out 16 rows, K=512 (4 gathered blocks), 1 tile/wave ----
  {
    const int n0 = wave;
    f32x4 acc1[1][1] = {}; f32x4 acc2[1][1] = {};
#pragma unroll
    for (int blk = 0; blk < 4; ++blk) {
      phaseH<1,1,4>(AHb, ALb, WHb, 0, n0, lane, blk, acc1, acc2);
      __syncthreads();
      if (blk < 3) stage(WHb, gw+GW4+(blk+1)*65536, 32768, tid);
      else         stage(WHb, gw+GW5, 8192, tid);        // w5 hi (8KB)
      phaseL<1,1,4>(AHb, WLb, 0, n0, lane, blk, acc2);
      __syncthreads();
      if (blk < 3) stage(WLb, gw+GW4+(blk+1)*65536+32768, 32768, tid);
      else         stage(WLb, gw+GW5+8192, 8192, tid);   // w5 lo (8KB)
    }
    writeback<1,1>(AHb, ALb, bias, 4, 0, n0, lane, acc1, acc2);
  }
  __syncthreads();

  // ---- conv5: 128 -> 32, quantize features (waves 0,1 only; no barriers) ----
  if (wave < 2) {
    f32x4 acc1[1][1] = {}; f32x4 acc2[1][1] = {};
    phaseH<1,1,0>(AHb, ALb, WHb, 0, wave, lane, 0, acc1, acc2);
    phaseL<1,1,0>(AHb, WLb, 0, wave, lane, 0, acc2);
    int c = wave*16 + (lane & 15);
    float bb = bias[5*128 + c];
#pragma unroll
    for (int q = 0; q < 4; ++q) {
      int s = ((lane >> 4) & 3)*4 + q;
      float f = acc1[0][0][q] + acc2[0][0][q]*LO_INV + bb;
      f = fminf(fmaxf(f, -1.0f), 127.0f/128.0f);
      int qi = clampi((int)rintf(f * 128.0f), -128, 127);
      feat[((long)chunkG*B + b0 + s)*32 + c] = (signed char)qi;
    }
  }
}

// ---------------------------------------------------------------------------
// value MLP: exact integer arithmetic (unchanged, verified round 1)
// ---------------------------------------------------------------------------
__global__ __launch_bounds__(256) void mlp_kernel(
    const signed char* __restrict__ feat,
    const int* __restrict__ mw,
    float* __restrict__ out, int B)
{
  int b = blockIdx.x * blockDim.x + threadIdx.x;
  if (b >= B) return;
  int S[32];
#pragma unroll
  for (int c = 0; c < 32; ++c) S[c] = 0;
  for (int ch = 0; ch < 16; ++ch) {
    const signed char* f = feat + ((long)ch*B + b)*32;
#pragma unroll
    for (int c = 0; c < 32; ++c) S[c] += f[c];
  }
  int x1[32];
#pragma unroll
  for (int c = 0; c < 32; ++c) x1[c] = clampi(S[c], -128, 127);

  const int* wq0 = mw;        const int* bq0 = mw + 1024;
  const int* wq1 = mw + 1056; const int* bq1 = mw + 2080;
  const int* wq2 = mw + 2112; const int* bq2 = mw + 2208;

  int x2[32];
#pragma unroll
  for (int o = 0; o < 32; ++o) {
    int acc = bq0[o];
    for (int i = 0; i < 32; ++i) acc += x1[i] * wq0[o*32 + i];
    acc = clampi(acc, 0, 32512);
    int r = acc >> 8, fr = acc & 255;
    r += (fr > 128 || (fr == 128 && (r & 1))) ? 1 : 0;
    x2[o] = r;
  }
  int x3[32];
#pragma unroll
  for (int o = 0; o < 32; ++o) {
    int acc = bq1[o];
    for (int i = 0; i < 32; ++i) acc += x2[i] * wq1[o*32 + i];
    acc = clampi(acc, 0, 16256);
    int r = acc >> 7, fr = acc & 127;
    r += (fr > 64 || (fr == 64 && (r & 1))) ? 1 : 0;
    x3[o] = r;
  }
  for (int o = 0; o < 3; ++o) {
    int acc = bq2[o];
    for (int i = 0; i < 32; ++i) acc += x3[i] * wq2[o*32 + i];
    out[b*3 + o] = (float)acc / 16384.0f;
  }
}

__global__ void zero_kernel(float4* __restrict__ p, int n4) {
  int i = blockIdx.x * blockDim.x + threadIdx.x;
  if (i < n4) p[i] = make_float4(0.f, 0.f, 0.f, 0.f);
}

// ---------------------------------------------------------------------------
extern "C" void kernel_launch(void* const* d_in, const int* in_sizes, int n_in,
                              void* d_out, int out_size, void* d_ws, size_t ws_size,
                              hipStream_t stream)
{
  const float* x   = (const float*)d_in[0];
  const float* w0  = (const float*)d_in[1];
  const float* b0  = (const float*)d_in[2];
  const float* w1  = (const float*)d_in[3];
  const float* b1  = (const float*)d_in[4];
  const float* w2  = (const float*)d_in[5];
  const float* b2  = (const float*)d_in[6];
  const float* w3  = (const float*)d_in[7];
  const float* b3  = (const float*)d_in[8];
  const float* w4  = (const float*)d_in[9];
  const float* b4  = (const float*)d_in[10];
  const float* w5  = (const float*)d_in[11];
  const float* b5  = (const float*)d_in[12];
  const float* bn1 = (const float*)d_in[13];
  const float* bn2 = (const float*)d_in[14];
  const float* bn3 = (const float*)d_in[15];
  const float* bn4 = (const float*)d_in[16];
  const float* bn5 = (const float*)d_in[17];
  const float* vw0 = (const float*)d_in[18];
  const float* vb0 = (const float*)d_in[19];
  const float* vw1 = (const float*)d_in[20];
  const float* vb1 = (const float*)d_in[21];
  const float* vw2 = (const float*)d_in[22];
  const float* vb2 = (const float*)d_in[23];

  const int B = in_sizes[0] / 98;
  float* ws = (float*)d_ws;
  signed char* feat = (signed char*)d_ws + FEAT_OFF_BYTES;
  float* out = (float*)d_out;

  (void)hipFuncSetAttribute((const void*)conv_mfma,
                            hipFuncAttributeMaxDynamicSharedMemorySize, LDS_TOTAL);

  prep_kernel<<<(511395 + 255)/256, 256, 0, stream>>>(
      w0,b0,w1,b1,w2,b2,w3,b3,w4,b4,w5,b5,
      bn1,bn2,bn3,bn4,bn5, vw0,vb0,vw1,vb1,vw2,vb2, ws);

  conv_mfma<<<B, 512, LDS_TOTAL, stream>>>(
      x, (const char*)d_ws, feat, B, B/16);

  mlp_kernel<<<(B + 255)/256, 256, 0, stream>>>(feat, (const int*)d_ws + MLP_WORD_OFF, out, B);

  {
    int n4 = B*49/4;
    zero_kernel<<<(n4 + 255)/256, 256, 0, stream>>>((float4*)(out + 3*B), n4);
  }
}

// Round 6
// 1812.251 us; speedup vs baseline: 4.0164x; 1.1317x over previous
//
#include <hip/hip_runtime.h>
#include <stdint.h>

// ---------------------------------------------------------------------------
// FlatSquare7x7NNUEv4 — round 6: conv1 restructured into two disjoint-M
// passes (NT=1/wave, MT=5 then 4) to cut peak VGPR demand from ~125-150 to
// ~99 so it provably fits the 128-VGPR allocation seen in all profiles.
// Theory: round 2-5's 1.6 GB/dispatch WRITE_SIZE is conv1 spill traffic.
// Everything else identical to round 5.
//   A·W = Ah·Wh + 2^-11*(Als·Wh + Ah·Wls)
// ---------------------------------------------------------------------------

typedef _Float16 f16x8 __attribute__((ext_vector_type(8)));
typedef float f32x4 __attribute__((ext_vector_type(4)));

// chunk tables: groups: [0..3]=g0, [4..11]=g1, [12..15]=g2
static __device__ __constant__ int CH_Y0[16] = {0,0,3,3, 0,1,3,2, 1,0,2,3, 1,1,2,2};
static __device__ __constant__ int CH_X0[16] = {0,3,3,0, 1,3,2,0, 0,2,3,1, 1,2,2,1};
static __device__ __constant__ int CH_K [16] = {0,1,2,3, 0,1,2,3, 0,1,2,3, 0,1,2,3};
static __device__ __constant__ int CH_T [16] = {0,0,0,0, 0,0,0,0, 1,1,1,1, 0,0,0,0};

// ---- LDS layout (bytes) ----
#define AH_OFF   0         // Ah  [144][128] f16 = 36864
#define AL_OFF   36864     // Als [144][128] f16 = 36864
#define WH_OFF   73728     // weight half H, 32KB
#define WL_OFF   106496    // weight half L, 32KB
#define XIN_OFF  139264    // [16][2][16] f32 = 2048
#define W0_OFF   141312    // [8][128] f32 = 4096
#define BIAS_OFF 145408    // [6][128] f32 = 3072
#define LDS_TOTAL 148480

// ---- global weight image (bytes within group) ----
#define G_STRIDE 678912
#define GW1   0
#define GW2   65536
#define GW3   327680
#define GW4   393216
#define GW5   655360
#define GW0   671744
#define GBIAS 675840
#define G_WORDS   167936     // f16 region words per group (656KB/4)
#define G_STRIDE_W 169728    // group stride in words
#define MLP_WORD_OFF 509184
#define FEAT_OFF_BYTES (2*1024*1024)

#define LO_SCALE 2048.0f
#define LO_INV   (1.0f/2048.0f)

__device__ __forceinline__ int swz(int b) { return b ^ (((b>>8)&7)<<4); }
__device__ __forceinline__ int base3(int z){ return (z>>1)*3 + (z&1); }
__device__ __forceinline__ int clampi(int v, int lo, int hi) { return v < lo ? lo : (v > hi ? hi : v); }

__device__ inline float bninv(const float* bn, int g, int C, int c) {
  float ga = bn[(g*4+0)*C + c];
  float va = bn[(g*4+3)*C + c];
  return ga / sqrtf(va + 1e-5f);
}
__device__ inline int q8(float x) { return clampi((int)rintf(x), -128, 127); }

// ---------------------------------------------------------------------------
// prep: fold BN, transpose to [oc][k], split f16 hi / lo*2^11, pre-swizzle
// ---------------------------------------------------------------------------
__global__ void prep_kernel(
    const float* __restrict__ w0, const float* __restrict__ b0,
    const float* __restrict__ w1, const float* __restrict__ b1,
    const float* __restrict__ w2, const float* __restrict__ b2,
    const float* __restrict__ w3, const float* __restrict__ b3,
    const float* __restrict__ w4, const float* __restrict__ b4,
    const float* __restrict__ w5, const float* __restrict__ b5,
    const float* __restrict__ bn1, const float* __restrict__ bn2,
    const float* __restrict__ bn3, const float* __restrict__ bn4,
    const float* __restrict__ bn5,
    const float* __restrict__ vw0, const float* __restrict__ vb0,
    const float* __restrict__ vw1, const float* __restrict__ vb1,
    const float* __restrict__ vw2, const float* __restrict__ vb2,
    float* __restrict__ ws)
{
  int idx = blockIdx.x * blockDim.x + threadIdx.x;
  if (idx < 3*G_WORDS) {
    uint32_t* wsU = (uint32_t*)ws;
    int g = idx / G_WORDS;
    int q = idx - g*G_WORDS;
    int stage, blk = 0, sub;
    if      (q < 16384)  { stage = 1; sub = q; }
    else if (q < 81920)  { stage = 2; blk = (q-16384)>>14; sub = (q-16384)&16383; }
    else if (q < 98304)  { stage = 3; sub = q-81920; }
    else if (q < 163840) { stage = 4; blk = (q-98304)>>14; sub = (q-98304)&16383; }
    else                 { stage = 5; sub = q-163840; }
    int isLo, r;
    if (stage == 5) { isLo = sub>>11; r = sub&2047; }
    else            { isLo = sub>>13; r = sub&8191; }
    int pb = r*4;
    int lb = pb ^ (((pb>>8)&7)<<4);     // inverse of kernel-side swizzle
    int oc = lb>>8;
    int k0 = (lb&255)>>1;               // even f16 index; word = (k0, k0+1)
    float inv, v0, v1;
    if (stage == 1) {
      inv = bninv(bn1,g,128,oc);
      v0 = w1[(g*128+oc)*128+k0]; v1 = w1[(g*128+oc)*128+k0+1];
    } else if (stage == 2) {
      inv = bninv(bn2,g,128,oc);
      v0 = w2[((g*128+oc)*128+k0)*4+blk]; v1 = w2[((g*128+oc)*128+k0+1)*4+blk];
    } else if (stage == 3) {
      inv = bninv(bn3,g,128,oc);
      v0 = w3[(g*128+oc)*128+k0]; v1 = w3[(g*128+oc)*128+k0+1];
    } else if (stage == 4) {
      inv = bninv(bn4,g,128,oc);
      v0 = w4[((g*128+oc)*128+k0)*4+blk]; v1 = w4[((g*128+oc)*128+k0+1)*4+blk];
    } else {
      inv = bninv(bn5,g,32,oc);
      v0 = w5[(g*32+oc)*128+k0]; v1 = w5[(g*32+oc)*128+k0+1];
    }
    v0 *= inv; v1 *= inv;
    _Float16 h0 = (_Float16)v0, h1 = (_Float16)v1;
    if (isLo) {
      h0 = (_Float16)((v0 - (float)h0) * LO_SCALE);
      h1 = (_Float16)((v1 - (float)h1) * LO_SCALE);
    }
    union { _Float16 h[2]; uint32_t u; } uu;
    uu.h[0] = h0; uu.h[1] = h1;
    wsU[g*G_STRIDE_W + q] = uu.u;
  } else if (idx < 506880) {            // w0: [k=8][c=128] fp32
    int e = idx - 503808; int g = e>>10; int t2 = e&1023;
    int k = t2>>7, c = t2&127;
    ws[g*G_STRIDE_W + 167936 + t2] = w0[((g*128 + c)*2 + (k>>2))*4 + (k&3)];
  } else if (idx < 509184) {            // folded biases [6][128] fp32
    int e = idx - 506880; int g = e/768; int r = e - g*768;
    int l = r>>7, c = r&127;
    float t;
    if (l == 0) {
      t = b0[g*128 + c];
    } else if (l < 5) {
      const float* bn = (l==1) ? bn1 : (l==2) ? bn2 : (l==3) ? bn3 : bn4;
      const float* bb = (l==1) ? b1  : (l==2) ? b2  : (l==3) ? b3  : b4;
      float inv = bninv(bn, g, 128, c);
      t = (bb[g*128 + c] - bn[(g*4+2)*128 + c]) * inv + bn[(g*4+1)*128 + c];
    } else {
      if (c < 32) {
        float inv = bninv(bn5, g, 32, c);
        t = (b5[g*32 + c] - bn5[(g*4+2)*32 + c]) * inv + bn5[(g*4+1)*32 + c];
      } else t = 0.f;
    }
    ws[g*G_STRIDE_W + 168960 + r] = t;
  } else if (idx < 511395) {            // quantized MLP ints
    int e = idx - MLP_WORD_OFF;
    int* wsI = (int*)ws;
    int val;
    if      (e < 1024) val = q8(vw0[e] * 256.f);
    else if (e < 1056) val = (int)rintf(vb0[e-1024] * 32768.f);
    else if (e < 2080) val = q8(vw1[e-1056] * 128.f);
    else if (e < 2112) val = (int)rintf(vb1[e-2080] * 16384.f);
    else if (e < 2208) val = q8(vw2[e-2112] * 128.f);
    else               val = (int)rintf(vb2[e-2208] * 16384.f);
    wsI[idx] = val;
  }
}

// ---------------------------------------------------------------------------
// fused MFMA conv stack
// ---------------------------------------------------------------------------
__device__ __forceinline__ f16x8 rdfrag(const char* base, int row, int ko) {
  return *(const f16x8*)(base + swz(row*256 + ko*2));
}

__device__ __forceinline__ void gl16(void* l, const void* g) {
  __builtin_amdgcn_global_load_lds(
      (const __attribute__((address_space(1))) void*)(uintptr_t)g,
      (__attribute__((address_space(3))) void*)(uint32_t)(uintptr_t)l,
      16, 0, 0);
}

__device__ __forceinline__ void stage(char* ldsbase, const char* gsrc, int bytes, int tid) {
  for (int off = tid*16; off < bytes; off += 8192)
    gl16(ldsbase + off, gsrc + off);
}

template<int MODE> __device__ __forceinline__ int arow(int r, int blk) {
  if (MODE == 0) return r;                                    // 1x1 convs
  if (MODE == 2) return (r>>2)*9 + base3(r&3) + base3(blk);   // conv2 gather
  return r*4 + blk;                                           // conv4 gather
}

#define MFMA(a,b,c) __builtin_amdgcn_mfma_f32_16x16x32_f16((a),(b),(c),0,0,0)

// Liveness-staged: Bh -> Ah -> acc1 MFMAs -> Al -> acc2 MFMAs, per kb.
template<int MT, int NT, int MODE>
__device__ __forceinline__ void phaseH(const char* AHb, const char* ALb, const char* Wb,
    int m0, int n0, int lane, int blk, f32x4 acc1[][NT], f32x4 acc2[][NT])
{
  const int l15 = lane & 15, kq = (lane >> 4) & 3;
#pragma unroll
  for (int kb = 0; kb < 4; ++kb) {
    const int ko = kb*32 + kq*8;
    f16x8 Bh_[NT];
#pragma unroll
    for (int n = 0; n < NT; ++n) Bh_[n] = rdfrag(Wb, (n0+n)*16 + l15, ko);
    {
      f16x8 Ah_[MT];
#pragma unroll
      for (int m = 0; m < MT; ++m)
        Ah_[m] = rdfrag(AHb, arow<MODE>((m0+m)*16 + l15, blk), ko);
#pragma unroll
      for (int m = 0; m < MT; ++m)
#pragma unroll
        for (int n = 0; n < NT; ++n)
          acc1[m][n] = MFMA(Ah_[m], Bh_[n], acc1[m][n]);
    }
    {
      f16x8 Al_[MT];
#pragma unroll
      for (int m = 0; m < MT; ++m)
        Al_[m] = rdfrag(ALb, arow<MODE>((m0+m)*16 + l15, blk), ko);
#pragma unroll
      for (int m = 0; m < MT; ++m)
#pragma unroll
        for (int n = 0; n < NT; ++n)
          acc2[m][n] = MFMA(Al_[m], Bh_[n], acc2[m][n]);
    }
  }
}

template<int MT, int NT, int MODE>
__device__ __forceinline__ void phaseL(const char* AHb, const char* Wb,
    int m0, int n0, int lane, int blk, f32x4 acc2[][NT])
{
  const int l15 = lane & 15, kq = (lane >> 4) & 3;
#pragma unroll
  for (int kb = 0; kb < 4; ++kb) {
    const int ko = kb*32 + kq*8;
    f16x8 Ah_[MT], Bl_[NT];
#pragma unroll
    for (int n = 0; n < NT; ++n) Bl_[n] = rdfrag(Wb, (n0+n)*16 + l15, ko);
#pragma unroll
    for (int m = 0; m < MT; ++m)
      Ah_[m] = rdfrag(AHb, arow<MODE>((m0+m)*16 + l15, blk), ko);
#pragma unroll
    for (int m = 0; m < MT; ++m)
#pragma unroll
      for (int n = 0; n < NT; ++n)
        acc2[m][n] = MFMA(Ah_[m], Bl_[n], acc2[m][n]);
  }
}

__device__ __forceinline__ void wbval(char* ah, char* al, int row, int col, float v) {
  _Float16 h = (_Float16)v;
  _Float16 l = (_Float16)((v - (float)h) * LO_SCALE);
  int sb = swz(row*256 + col*2);
  *(_Float16*)(ah + sb) = h;
  *(_Float16*)(al + sb) = l;
}

template<int MT, int NT>
__device__ __forceinline__ void writeback(char* AHb, char* ALb, const float* bias,
    int layer, int m0, int n0, int lane, f32x4 acc1[][NT], f32x4 acc2[][NT])
{
  const int l15 = lane & 15, rq = (lane >> 4) & 3;
#pragma unroll
  for (int m = 0; m < MT; ++m)
#pragma unroll
    for (int n = 0; n < NT; ++n) {
      int col = (n0+n)*16 + l15;
      float bb = bias[layer*128 + col];
#pragma unroll
      for (int q = 0; q < 4; ++q) {
        int row = (m0+m)*16 + rq*4 + q;
        float v = acc1[m][n][q] + acc2[m][n][q]*LO_INV + bb;
        v = fmaxf(v, 0.f);
        wbval(AHb, ALb, row, col, v);
      }
    }
}

__global__ __launch_bounds__(512, 1)
void conv_mfma(
    const float* __restrict__ x, const char* __restrict__ wsb,
    signed char* __restrict__ feat, int B, int wgPerChunk)
{
  extern __shared__ char lds[];
  char* AHb = lds + AH_OFF;
  char* ALb = lds + AL_OFF;
  char* WHb = lds + WH_OFF;
  char* WLb = lds + WL_OFF;
  const float* bias = (const float*)(lds + BIAS_OFF);

  const int tid  = threadIdx.x;
  const int lane = tid & 63;
  const int wave = tid >> 6;

  const int wg = blockIdx.x;
  const int chunkG = wg / wgPerChunk;
  const int b0 = (wg - chunkG*wgPerChunk) * 16;
  const int g = (chunkG < 4) ? 0 : (chunkG < 12) ? 1 : 2;
  const char* gw = wsb + g*G_STRIDE;

  // ---- prologue staging ----
  {
    int s = tid >> 5, v = tid & 31;
    int ic = v >> 4, pos = v & 15;
    int i = pos >> 2, j = pos & 3;
    int tt = CH_T[chunkG], kk = CH_K[chunkG];
    int a = tt ? j : i, bb2 = tt ? i : j;
    int py, px;
    if      (kk == 0) { py = a;     px = bb2;   }
    else if (kk == 1) { py = bb2;   px = 3-a;   }
    else if (kk == 2) { py = 3-a;   px = 3-bb2; }
    else              { py = 3-bb2; px = a;     }
    int sy = CH_Y0[chunkG] + py, sx = CH_X0[chunkG] + px;
    ((float*)(lds+XIN_OFF))[s*32 + v] = x[((b0+s)*2 + ic)*49 + sy*7 + sx];
  }
  if (tid < 256) ((float4*)(lds+W0_OFF))[tid]   = ((const float4*)(gw+GW0))[tid];
  if (tid < 192) ((float4*)(lds+BIAS_OFF))[tid] = ((const float4*)(gw+GBIAS))[tid];
  stage(WHb, gw+GW1,       32768, tid);   // w1 hi
  stage(WLb, gw+GW1+32768, 32768, tid);   // w1 lo
  __syncthreads();

  // ---- conv0 (VALU, K=8) ----
  {
    const float* xin = (const float*)(lds+XIN_OFF);
    const float* w0s = (const float*)(lds+W0_OFF);
    int c = tid & 127;
    float wr[8];
#pragma unroll
    for (int k = 0; k < 8; ++k) wr[k] = w0s[k*128 + c];
    float b0c = bias[c];
    int sg = tid >> 7;
#pragma unroll
    for (int si = 0; si < 4; ++si) {
      int s = sg*4 + si;
      float xv[32];
#pragma unroll
      for (int t2 = 0; t2 < 32; ++t2) xv[t2] = xin[s*32 + t2];
#pragma unroll
      for (int oy = 0; oy < 3; ++oy)
#pragma unroll
        for (int ox = 0; ox < 3; ++ox) {
          float acc0 = b0c;
#pragma unroll
          for (int ic2 = 0; ic2 < 2; ++ic2)
#pragma unroll
            for (int dy = 0; dy < 2; ++dy)
#pragma unroll
              for (int dx = 0; dx < 2; ++dx)
                acc0 = fmaf(xv[ic2*16 + (oy+dy)*4 + ox+dx], wr[ic2*4+dy*2+dx], acc0);
          wbval(AHb, ALb, s*9 + oy*3 + ox, c, fmaxf(acc0, 0.f));
        }
    }
  }
  __syncthreads();                              // act ready, w1 ready

  // ---- conv1: two disjoint-M passes, NT=1 per wave (low reg pressure) ----
  // pass 0: M tiles 0-4 (rows 0-79); pass 1: M tiles 5-8 (rows 80-143).
  // In-place safety: barrier before each writeback orders all reads of that
  // pass; pass-1 reads rows 80-143, never touched by pass-0's writeback.
  // WHb/WLb restaging happens only after their last reader (phaseH1/phaseL1).
  {
    const int n0 = wave;                        // 8 N-tiles, one per wave
    {
      f32x4 acc1[5][1] = {}; f32x4 acc2[5][1] = {};
      phaseH<5,1,0>(AHb, ALb, WHb, 0, n0, lane, 0, acc1, acc2);
      phaseL<5,1,0>(AHb, WLb, 0, n0, lane, 0, acc2);
      __syncthreads();                          // all pass-0 reads done
      writeback<5,1>(AHb, ALb, bias, 1, 0, n0, lane, acc1, acc2);
    }
    {
      f32x4 acc1[4][1] = {}; f32x4 acc2[4][1] = {};
      phaseH<4,1,0>(AHb, ALb, WHb, 5, n0, lane, 0, acc1, acc2);  // last WHb use
      __syncthreads();
      stage(WHb, gw+GW2, 32768, tid);           // w2 blk0 hi
      phaseL<4,1,0>(AHb, WLb, 5, n0, lane, 0, acc2);             // last WLb use
      __syncthreads();
      stage(WLb, gw+GW2+32768, 32768, tid);     // w2 blk0 lo
      writeback<4,1>(AHb, ALb, bias, 1, 5, n0, lane, acc1, acc2);
    }
  }
  __syncthreads();

  // ---- conv2: out 64 rows, K=512 (4 gathered blocks) ----
  {
    const int m0 = (wave >> 2) * 2;
    const int n0 = (wave & 3) * 2;
    f32x4 acc1[2][2] = {}; f32x4 acc2[2][2] = {};
#pragma unroll
    for (int blk = 0; blk < 4; ++blk) {
      phaseH<2,2,2>(AHb, ALb, WHb, m0, n0, lane, blk, acc1, acc2);
      __syncthreads();
      if (blk < 3) stage(WHb, gw+GW2+(blk+1)*65536, 32768, tid);
      else         stage(WHb, gw+GW3, 32768, tid);
      phaseL<2,2,2>(AHb, WLb, m0, n0, lane, blk, acc2);
      __syncthreads();
      if (blk < 3) stage(WLb, gw+GW2+(blk+1)*65536+32768, 32768, tid);
      else         stage(WLb, gw+GW3+32768, 32768, tid);
    }
    writeback<2,2>(AHb, ALb, bias, 2, m0, n0, lane, acc1, acc2);
  }
  __syncthreads();

  // ---- conv3: rows 64, 1x1 ----
  {
    const int m0 = (wave >> 2) * 2;
    const int n0 = (wave & 3) * 2;
    f32x4 acc1[2][2] = {}; f32x4 acc2[2][2] = {};
    phaseH<2,2,0>(AHb, ALb, WHb, m0, n0, lane, 0, acc1, acc2);
    __syncthreads();
    stage(WHb, gw+GW4, 32768, tid);             // w4 blk0 hi
    phaseL<2,2,0>(AHb, WLb, m0, n0, lane, 0, acc2);
    __syncthreads();
    stage(WLb, gw+GW4+32768, 32768, tid);       // w4 blk0 lo
    writeback<2,2>(AHb, ALb, bias, 3, m0, n0, lane, acc1, acc2);
  }
  __syncthreads();

  // ---- conv4: out 16 rows, K=512 (4 gathered blocks), 1 tile/wave ----
  {
    const int n0 = wave;
    f32x4 acc1[1][1] = {}; f32x4 acc2[1][1] = {};
#pragma unroll
    for (int blk = 0; blk < 4; ++blk) {
      phaseH<1,1,4>(AHb, ALb, WHb, 0, n0, lane, blk, acc1, acc2);
      __syncthreads();
      if (blk < 3) stage(WHb, gw+GW4+(blk+1)*65536, 32768, tid);
      else         stage(WHb, gw+GW5, 8192, tid);        // w5 hi (8KB)
      phaseL<1,1,4>(AHb, WLb, 0, n0, lane, blk, acc2);
      __syncthreads();
      if (blk < 3) stage(WLb, gw+GW4+(blk+1)*65536+32768, 32768, tid);
      else         stage(WLb, gw+GW5+8192, 8192, tid);   // w5 lo (8KB)
    }
    writeback<1,1>(AHb, ALb, bias, 4, 0, n0, lane, acc1, acc2);
  }
  __syncthreads();

  // ---- conv5: 128 -> 32, quantize features (waves 0,1 only; no barriers) ----
  if (wave < 2) {
    f32x4 acc1[1][1] = {}; f32x4 acc2[1][1] = {};
    phaseH<1,1,0>(AHb, ALb, WHb, 0, wave, lane, 0, acc1, acc2);
    phaseL<1,1,0>(AHb, WLb, 0, wave, lane, 0, acc2);
    int c = wave*16 + (lane & 15);
    float bb = bias[5*128 + c];
#pragma unroll
    for (int q = 0; q < 4; ++q) {
      int s = ((lane >> 4) & 3)*4 + q;
      float f = acc1[0][0][q] + acc2[0][0][q]*LO_INV + bb;
      f = fminf(fmaxf(f, -1.0f), 127.0f/128.0f);
      int qi = clampi((int)rintf(f * 128.0f), -128, 127);
      feat[((long)chunkG*B + b0 + s)*32 + c] = (signed char)qi;
    }
  }
}

// ---------------------------------------------------------------------------
// value MLP: exact integer arithmetic (unchanged, verified round 1)
// ---------------------------------------------------------------------------
__global__ __launch_bounds__(256) void mlp_kernel(
    const signed char* __restrict__ feat,
    const int* __restrict__ mw,
    float* __restrict__ out, int B)
{
  int b = blockIdx.x * blockDim.x + threadIdx.x;
  if (b >= B) return;
  int S[32];
#pragma unroll
  for (int c = 0; c < 32; ++c) S[c] = 0;
  for (int ch = 0; ch < 16; ++ch) {
    const signed char* f = feat + ((long)ch*B + b)*32;
#pragma unroll
    for (int c = 0; c < 32; ++c) S[c] += f[c];
  }
  int x1[32];
#pragma unroll
  for (int c = 0; c < 32; ++c) x1[c] = clampi(S[c], -128, 127);

  const int* wq0 = mw;        const int* bq0 = mw + 1024;
  const int* wq1 = mw + 1056; const int* bq1 = mw + 2080;
  const int* wq2 = mw + 2112; const int* bq2 = mw + 2208;

  int x2[32];
#pragma unroll
  for (int o = 0; o < 32; ++o) {
    int acc = bq0[o];
    for (int i = 0; i < 32; ++i) acc += x1[i] * wq0[o*32 + i];
    acc = clampi(acc, 0, 32512);
    int r = acc >> 8, fr = acc & 255;
    r += (fr > 128 || (fr == 128 && (r & 1))) ? 1 : 0;
    x2[o] = r;
  }
  int x3[32];
#pragma unroll
  for (int o = 0; o < 32; ++o) {
    int acc = bq1[o];
    for (int i = 0; i < 32; ++i) acc += x2[i] * wq1[o*32 + i];
    acc = clampi(acc, 0, 16256);
    int r = acc >> 7, fr = acc & 127;
    r += (fr > 64 || (fr == 64 && (r & 1))) ? 1 : 0;
    x3[o] = r;
  }
  for (int o = 0; o < 3; ++o) {
    int acc = bq2[o];
    for (int i = 0; i < 32; ++i) acc += x3[i] * wq2[o*32 + i];
    out[b*3 + o] = (float)acc / 16384.0f;
  }
}

__global__ void zero_kernel(float4* __restrict__ p, int n4) {
  int i = blockIdx.x * blockDim.x + threadIdx.x;
  if (i < n4) p[i] = make_float4(0.f, 0.f, 0.f, 0.f);
}

// ---------------------------------------------------------------------------
extern "C" void kernel_launch(void* const* d_in, const int* in_sizes, int n_in,
                              void* d_out, int out_size, void* d_ws, size_t ws_size,
                              hipStream_t stream)
{
  const float* x   = (const float*)d_in[0];
  const float* w0  = (const float*)d_in[1];
  const float* b0  = (const float*)d_in[2];
  const float* w1  = (const float*)d_in[3];
  const float* b1  = (const float*)d_in[4];
  const float* w2  = (const float*)d_in[5];
  const float* b2  = (const float*)d_in[6];
  const float* w3  = (const float*)d_in[7];
  const float* b3  = (const float*)d_in[8];
  const float* w4  = (const float*)d_in[9];
  const float* b4  = (const float*)d_in[10];
  const float* w5  = (const float*)d_in[11];
  const float* b5  = (const float*)d_in[12];
  const float* bn1 = (const float*)d_in[13];
  const float* bn2 = (const float*)d_in[14];
  const float* bn3 = (const float*)d_in[15];
  const float* bn4 = (const float*)d_in[16];
  const float* bn5 = (const float*)d_in[17];
  const float* vw0 = (const float*)d_in[18];
  const float* vb0 = (const float*)d_in[19];
  const float* vw1 = (const float*)d_in[20];
  const float* vb1 = (const float*)d_in[21];
  const float* vw2 = (const float*)d_in[22];
  const float* vb2 = (const float*)d_in[23];

  const int B = in_sizes[0] / 98;
  float* ws = (float*)d_ws;
  signed char* feat = (signed char*)d_ws + FEAT_OFF_BYTES;
  float* out = (float*)d_out;

  (void)hipFuncSetAttribute((const void*)conv_mfma,
                            hipFuncAttributeMaxDynamicSharedMemorySize, LDS_TOTAL);

  prep_kernel<<<(511395 + 255)/256, 256, 0, stream>>>(
      w0,b0,w1,b1,w2,b2,w3,b3,w4,b4,w5,b5,
      bn1,bn2,bn3,bn4,bn5, vw0,vb0,vw1,vb1,vw2,vb2, ws);

  conv_mfma<<<B, 512, LDS_TOTAL, stream>>>(
      x, (const char*)d_ws, feat, B, B/16);

  mlp_kernel<<<(B + 255)/256, 256, 0, stream>>>(feat, (const int*)d_ws + MLP_WORD_OFF, out, B);

  {
    int n4 = B*49/4;
    zero_kernel<<<(n4 + 255)/256, 256, 0, stream>>>((float4*)(out + 3*B), n4);
  }
}

// Round 8
// 1629.413 us; speedup vs baseline: 4.4671x; 1.1122x over previous
//
#include <hip/hip_runtime.h>
#include <stdint.h>

// ---------------------------------------------------------------------------
// FlatSquare7x7NNUEv4 — round 8: identical to round 7 (container died before
// benching). Fused hi/lo MFMA phases (phaseF keeps Ah/Al/Bh/Bl resident,
// 3 MFMAs per fragment set) + per-layer wave grids with larger register
// tiles. Theory: round 6 is LDS-read-bound (54M ds_read_b128 = ~1054us +
// 537us conflicts); fused tiles cut reads to ~39M.
//   A·W = Ah·Wh + 2^-11*(Als·Wh + Ah·Wls)
// ---------------------------------------------------------------------------

typedef _Float16 f16x8 __attribute__((ext_vector_type(8)));
typedef float f32x4 __attribute__((ext_vector_type(4)));

// chunk tables: groups: [0..3]=g0, [4..11]=g1, [12..15]=g2
static __device__ __constant__ int CH_Y0[16] = {0,0,3,3, 0,1,3,2, 1,0,2,3, 1,1,2,2};
static __device__ __constant__ int CH_X0[16] = {0,3,3,0, 1,3,2,0, 0,2,3,1, 1,2,2,1};
static __device__ __constant__ int CH_K [16] = {0,1,2,3, 0,1,2,3, 0,1,2,3, 0,1,2,3};
static __device__ __constant__ int CH_T [16] = {0,0,0,0, 0,0,0,0, 1,1,1,1, 0,0,0,0};

// ---- LDS layout (bytes) ----
#define AH_OFF   0         // Ah  [144][128] f16 = 36864
#define AL_OFF   36864     // Als [144][128] f16 = 36864
#define WH_OFF   73728     // weight half H, 32KB
#define WL_OFF   106496    // weight half L, 32KB
#define XIN_OFF  139264    // [16][2][16] f32 = 2048
#define W0_OFF   141312    // [8][128] f32 = 4096
#define BIAS_OFF 145408    // [6][128] f32 = 3072
#define LDS_TOTAL 148480

// ---- global weight image (bytes within group) ----
#define G_STRIDE 678912
#define GW1   0
#define GW2   65536
#define GW3   327680
#define GW4   393216
#define GW5   655360
#define GW0   671744
#define GBIAS 675840
#define G_WORDS   167936     // f16 region words per group (656KB/4)
#define G_STRIDE_W 169728    // group stride in words
#define MLP_WORD_OFF 509184
#define FEAT_OFF_BYTES (2*1024*1024)

#define LO_SCALE 2048.0f
#define LO_INV   (1.0f/2048.0f)

__device__ __forceinline__ int swz(int b) { return b ^ (((b>>8)&7)<<4); }
__device__ __forceinline__ int base3(int z){ return (z>>1)*3 + (z&1); }
__device__ __forceinline__ int clampi(int v, int lo, int hi) { return v < lo ? lo : (v > hi ? hi : v); }

__device__ inline float bninv(const float* bn, int g, int C, int c) {
  float ga = bn[(g*4+0)*C + c];
  float va = bn[(g*4+3)*C + c];
  return ga / sqrtf(va + 1e-5f);
}
__device__ inline int q8(float x) { return clampi((int)rintf(x), -128, 127); }

// ---------------------------------------------------------------------------
// prep: fold BN, transpose to [oc][k], split f16 hi / lo*2^11, pre-swizzle
// ---------------------------------------------------------------------------
__global__ void prep_kernel(
    const float* __restrict__ w0, const float* __restrict__ b0,
    const float* __restrict__ w1, const float* __restrict__ b1,
    const float* __restrict__ w2, const float* __restrict__ b2,
    const float* __restrict__ w3, const float* __restrict__ b3,
    const float* __restrict__ w4, const float* __restrict__ b4,
    const float* __restrict__ w5, const float* __restrict__ b5,
    const float* __restrict__ bn1, const float* __restrict__ bn2,
    const float* __restrict__ bn3, const float* __restrict__ bn4,
    const float* __restrict__ bn5,
    const float* __restrict__ vw0, const float* __restrict__ vb0,
    const float* __restrict__ vw1, const float* __restrict__ vb1,
    const float* __restrict__ vw2, const float* __restrict__ vb2,
    float* __restrict__ ws)
{
  int idx = blockIdx.x * blockDim.x + threadIdx.x;
  if (idx < 3*G_WORDS) {
    uint32_t* wsU = (uint32_t*)ws;
    int g = idx / G_WORDS;
    int q = idx - g*G_WORDS;
    int stage, blk = 0, sub;
    if      (q < 16384)  { stage = 1; sub = q; }
    else if (q < 81920)  { stage = 2; blk = (q-16384)>>14; sub = (q-16384)&16383; }
    else if (q < 98304)  { stage = 3; sub = q-81920; }
    else if (q < 163840) { stage = 4; blk = (q-98304)>>14; sub = (q-98304)&16383; }
    else                 { stage = 5; sub = q-163840; }
    int isLo, r;
    if (stage == 5) { isLo = sub>>11; r = sub&2047; }
    else            { isLo = sub>>13; r = sub&8191; }
    int pb = r*4;
    int lb = pb ^ (((pb>>8)&7)<<4);     // inverse of kernel-side swizzle
    int oc = lb>>8;
    int k0 = (lb&255)>>1;               // even f16 index; word = (k0, k0+1)
    float inv, v0, v1;
    if (stage == 1) {
      inv = bninv(bn1,g,128,oc);
      v0 = w1[(g*128+oc)*128+k0]; v1 = w1[(g*128+oc)*128+k0+1];
    } else if (stage == 2) {
      inv = bninv(bn2,g,128,oc);
      v0 = w2[((g*128+oc)*128+k0)*4+blk]; v1 = w2[((g*128+oc)*128+k0+1)*4+blk];
    } else if (stage == 3) {
      inv = bninv(bn3,g,128,oc);
      v0 = w3[(g*128+oc)*128+k0]; v1 = w3[(g*128+oc)*128+k0+1];
    } else if (stage == 4) {
      inv = bninv(bn4,g,128,oc);
      v0 = w4[((g*128+oc)*128+k0)*4+blk]; v1 = w4[((g*128+oc)*128+k0+1)*4+blk];
    } else {
      inv = bninv(bn5,g,32,oc);
      v0 = w5[(g*32+oc)*128+k0]; v1 = w5[(g*32+oc)*128+k0+1];
    }
    v0 *= inv; v1 *= inv;
    _Float16 h0 = (_Float16)v0, h1 = (_Float16)v1;
    if (isLo) {
      h0 = (_Float16)((v0 - (float)h0) * LO_SCALE);
      h1 = (_Float16)((v1 - (float)h1) * LO_SCALE);
    }
    union { _Float16 h[2]; uint32_t u; } uu;
    uu.h[0] = h0; uu.h[1] = h1;
    wsU[g*G_STRIDE_W + q] = uu.u;
  } else if (idx < 506880) {            // w0: [k=8][c=128] fp32
    int e = idx - 503808; int g = e>>10; int t2 = e&1023;
    int k = t2>>7, c = t2&127;
    ws[g*G_STRIDE_W + 167936 + t2] = w0[((g*128 + c)*2 + (k>>2))*4 + (k&3)];
  } else if (idx < 509184) {            // folded biases [6][128] fp32
    int e = idx - 506880; int g = e/768; int r = e - g*768;
    int l = r>>7, c = r&127;
    float t;
    if (l == 0) {
      t = b0[g*128 + c];
    } else if (l < 5) {
      const float* bn = (l==1) ? bn1 : (l==2) ? bn2 : (l==3) ? bn3 : bn4;
      const float* bb = (l==1) ? b1  : (l==2) ? b2  : (l==3) ? b3  : b4;
      float inv = bninv(bn, g, 128, c);
      t = (bb[g*128 + c] - bn[(g*4+2)*128 + c]) * inv + bn[(g*4+1)*128 + c];
    } else {
      if (c < 32) {
        float inv = bninv(bn5, g, 32, c);
        t = (b5[g*32 + c] - bn5[(g*4+2)*32 + c]) * inv + bn5[(g*4+1)*32 + c];
      } else t = 0.f;
    }
    ws[g*G_STRIDE_W + 168960 + r] = t;
  } else if (idx < 511395) {            // quantized MLP ints
    int e = idx - MLP_WORD_OFF;
    int* wsI = (int*)ws;
    int val;
    if      (e < 1024) val = q8(vw0[e] * 256.f);
    else if (e < 1056) val = (int)rintf(vb0[e-1024] * 32768.f);
    else if (e < 2080) val = q8(vw1[e-1056] * 128.f);
    else if (e < 2112) val = (int)rintf(vb1[e-2080] * 16384.f);
    else if (e < 2208) val = q8(vw2[e-2112] * 128.f);
    else               val = (int)rintf(vb2[e-2208] * 16384.f);
    wsI[idx] = val;
  }
}

// ---------------------------------------------------------------------------
// fused MFMA conv stack
// ---------------------------------------------------------------------------
__device__ __forceinline__ f16x8 rdfrag(const char* base, int row, int ko) {
  return *(const f16x8*)(base + swz(row*256 + ko*2));
}

__device__ __forceinline__ void gl16(void* l, const void* g) {
  __builtin_amdgcn_global_load_lds(
      (const __attribute__((address_space(1))) void*)(uintptr_t)g,
      (__attribute__((address_space(3))) void*)(uint32_t)(uintptr_t)l,
      16, 0, 0);
}

__device__ __forceinline__ void stage(char* ldsbase, const char* gsrc, int bytes, int tid) {
  for (int off = tid*16; off < bytes; off += 8192)
    gl16(ldsbase + off, gsrc + off);
}

template<int MODE> __device__ __forceinline__ int arow(int r, int blk) {
  if (MODE == 0) return r;                                    // 1x1 convs
  if (MODE == 2) return (r>>2)*9 + base3(r&3) + base3(blk);   // conv2 gather
  return r*4 + blk;                                           // conv4 gather
}

#define MFMA(a,b,c) __builtin_amdgcn_mfma_f32_16x16x32_f16((a),(b),(c),0,0,0)

// Fused hi/lo phase: Bh/Bl resident, per-m Ah/Al read once, 3 MFMAs fired.
template<int MT, int NT, int MODE>
__device__ __forceinline__ void phaseF(const char* AHb, const char* ALb,
    const char* WHb, const char* WLb,
    int m0, int n0, int lane, int blk, f32x4 acc1[][NT], f32x4 acc2[][NT])
{
  const int l15 = lane & 15, kq = (lane >> 4) & 3;
#pragma unroll
  for (int kb = 0; kb < 4; ++kb) {
    const int ko = kb*32 + kq*8;
    f16x8 Bh_[NT], Bl_[NT];
#pragma unroll
    for (int n = 0; n < NT; ++n) {
      Bh_[n] = rdfrag(WHb, (n0+n)*16 + l15, ko);
      Bl_[n] = rdfrag(WLb, (n0+n)*16 + l15, ko);
    }
#pragma unroll
    for (int m = 0; m < MT; ++m) {
      const int ra = arow<MODE>((m0+m)*16 + l15, blk);
      f16x8 Ah = rdfrag(AHb, ra, ko);
      f16x8 Al = rdfrag(ALb, ra, ko);
#pragma unroll
      for (int n = 0; n < NT; ++n) {
        acc1[m][n] = MFMA(Ah, Bh_[n], acc1[m][n]);
        acc2[m][n] = MFMA(Al, Bh_[n], acc2[m][n]);
        acc2[m][n] = MFMA(Ah, Bl_[n], acc2[m][n]);
      }
    }
  }
}

__device__ __forceinline__ void wbval(char* ah, char* al, int row, int col, float v) {
  _Float16 h = (_Float16)v;
  _Float16 l = (_Float16)((v - (float)h) * LO_SCALE);
  int sb = swz(row*256 + col*2);
  *(_Float16*)(ah + sb) = h;
  *(_Float16*)(al + sb) = l;
}

template<int MT, int NT>
__device__ __forceinline__ void writeback(char* AHb, char* ALb, const float* bias,
    int layer, int m0, int n0, int lane, f32x4 acc1[][NT], f32x4 acc2[][NT])
{
  const int l15 = lane & 15, rq = (lane >> 4) & 3;
#pragma unroll
  for (int m = 0; m < MT; ++m)
#pragma unroll
    for (int n = 0; n < NT; ++n) {
      int col = (n0+n)*16 + l15;
      float bb = bias[layer*128 + col];
#pragma unroll
      for (int q = 0; q < 4; ++q) {
        int row = (m0+m)*16 + rq*4 + q;
        float v = acc1[m][n][q] + acc2[m][n][q]*LO_INV + bb;
        v = fmaxf(v, 0.f);
        wbval(AHb, ALb, row, col, v);
      }
    }
}

__global__ __launch_bounds__(512, 1)
void conv_mfma(
    const float* __restrict__ x, const char* __restrict__ wsb,
    signed char* __restrict__ feat, int B, int wgPerChunk)
{
  extern __shared__ char lds[];
  char* AHb = lds + AH_OFF;
  char* ALb = lds + AL_OFF;
  char* WHb = lds + WH_OFF;
  char* WLb = lds + WL_OFF;
  const float* bias = (const float*)(lds + BIAS_OFF);

  const int tid  = threadIdx.x;
  const int lane = tid & 63;
  const int wave = tid >> 6;
  const int mslot = wave >> 2;          // 0-1
  const int nslot = wave & 3;           // 0-3

  const int wg = blockIdx.x;
  const int chunkG = wg / wgPerChunk;
  const int b0 = (wg - chunkG*wgPerChunk) * 16;
  const int g = (chunkG < 4) ? 0 : (chunkG < 12) ? 1 : 2;
  const char* gw = wsb + g*G_STRIDE;

  // ---- prologue staging ----
  {
    int s = tid >> 5, v = tid & 31;
    int ic = v >> 4, pos = v & 15;
    int i = pos >> 2, j = pos & 3;
    int tt = CH_T[chunkG], kk = CH_K[chunkG];
    int a = tt ? j : i, bb2 = tt ? i : j;
    int py, px;
    if      (kk == 0) { py = a;     px = bb2;   }
    else if (kk == 1) { py = bb2;   px = 3-a;   }
    else if (kk == 2) { py = 3-a;   px = 3-bb2; }
    else              { py = 3-bb2; px = a;     }
    int sy = CH_Y0[chunkG] + py, sx = CH_X0[chunkG] + px;
    ((float*)(lds+XIN_OFF))[s*32 + v] = x[((b0+s)*2 + ic)*49 + sy*7 + sx];
  }
  if (tid < 256) ((float4*)(lds+W0_OFF))[tid]   = ((const float4*)(gw+GW0))[tid];
  if (tid < 192) ((float4*)(lds+BIAS_OFF))[tid] = ((const float4*)(gw+GBIAS))[tid];
  stage(WHb, gw+GW1,       32768, tid);   // w1 hi
  stage(WLb, gw+GW1+32768, 32768, tid);   // w1 lo
  __syncthreads();

  // ---- conv0 (VALU, K=8) ----
  {
    const float* xin = (const float*)(lds+XIN_OFF);
    const float* w0s = (const float*)(lds+W0_OFF);
    int c = tid & 127;
    float wr[8];
#pragma unroll
    for (int k = 0; k < 8; ++k) wr[k] = w0s[k*128 + c];
    float b0c = bias[c];
    int sg = tid >> 7;
#pragma unroll
    for (int si = 0; si < 4; ++si) {
      int s = sg*4 + si;
      float xv[32];
#pragma unroll
      for (int t2 = 0; t2 < 32; ++t2) xv[t2] = xin[s*32 + t2];
#pragma unroll
      for (int oy = 0; oy < 3; ++oy)
#pragma unroll
        for (int ox = 0; ox < 3; ++ox) {
          float acc0 = b0c;
#pragma unroll
          for (int ic2 = 0; ic2 < 2; ++ic2)
#pragma unroll
            for (int dy = 0; dy < 2; ++dy)
#pragma unroll
              for (int dx = 0; dx < 2; ++dx)
                acc0 = fmaf(xv[ic2*16 + (oy+dy)*4 + ox+dx], wr[ic2*4+dy*2+dx], acc0);
          wbval(AHb, ALb, s*9 + oy*3 + ox, c, fmaxf(acc0, 0.f));
        }
    }
  }
  __syncthreads();                              // act ready, w1 ready

  // ---- conv1: pass0 MT4/NT2 (tiles 0-7), pass1 MT1/NT1 (tile 8) ----
  {
    {
      f32x4 a1[4][2] = {}; f32x4 a2[4][2] = {};
      phaseF<4,2,0>(AHb, ALb, WHb, WLb, mslot*4, nslot*2, lane, 0, a1, a2);
      __syncthreads();                          // all pass0 reads done
      writeback<4,2>(AHb, ALb, bias, 1, mslot*4, nslot*2, lane, a1, a2);
    }
    {
      // pass1 reads rows 128-143 — disjoint from pass0 WB rows 0-127
      f32x4 a1[1][1] = {}; f32x4 a2[1][1] = {};
      phaseF<1,1,0>(AHb, ALb, WHb, WLb, 8, wave, lane, 0, a1, a2);
      __syncthreads();                          // pass1 reads + pass0 WB done
      writeback<1,1>(AHb, ALb, bias, 1, 8, wave, lane, a1, a2);
      stage(WHb, gw+GW2, 32768, tid);           // w2 blk0 hi (w1 fully read)
      stage(WLb, gw+GW2+32768, 32768, tid);     // w2 blk0 lo
      __syncthreads();                          // w2b0 + pass1 WB ready
    }
  }

  // ---- conv2: out 64 rows, K=512 (4 gathered blocks), MT2/NT2, acc held ----
  {
    f32x4 a1[2][2] = {}; f32x4 a2[2][2] = {};
#pragma unroll
    for (int blk = 0; blk < 4; ++blk) {
      phaseF<2,2,2>(AHb, ALb, WHb, WLb, mslot*2, nslot*2, lane, blk, a1, a2);
      __syncthreads();                          // blk reads done
      if (blk < 3) {
        stage(WHb, gw+GW2+(blk+1)*65536, 32768, tid);
        stage(WLb, gw+GW2+(blk+1)*65536+32768, 32768, tid);
      } else {
        stage(WHb, gw+GW3, 32768, tid);         // w3 hi
        stage(WLb, gw+GW3+32768, 32768, tid);   // w3 lo
        writeback<2,2>(AHb, ALb, bias, 2, mslot*2, nslot*2, lane, a1, a2);
      }
      __syncthreads();                          // staged (+WB on last) ready
    }
  }

  // ---- conv3: rows 64, 1x1, MT2/NT2 ----
  {
    f32x4 a1[2][2] = {}; f32x4 a2[2][2] = {};
    phaseF<2,2,0>(AHb, ALb, WHb, WLb, mslot*2, nslot*2, lane, 0, a1, a2);
    __syncthreads();                            // conv3 reads done (w3 done)
    stage(WHb, gw+GW4, 32768, tid);             // w4 blk0 hi
    stage(WLb, gw+GW4+32768, 32768, tid);       // w4 blk0 lo
    writeback<2,2>(AHb, ALb, bias, 3, mslot*2, nslot*2, lane, a1, a2);
    __syncthreads();
  }

  // ---- conv4: out 16 rows, K=512 (4 gathered blocks), MT1/NT1 ----
  {
    f32x4 a1[1][1] = {}; f32x4 a2[1][1] = {};
#pragma unroll
    for (int blk = 0; blk < 4; ++blk) {
      phaseF<1,1,4>(AHb, ALb, WHb, WLb, 0, wave, lane, blk, a1, a2);
      __syncthreads();                          // blk reads done
      if (blk < 3) {
        stage(WHb, gw+GW4+(blk+1)*65536, 32768, tid);
        stage(WLb, gw+GW4+(blk+1)*65536+32768, 32768, tid);
      } else {
        stage(WHb, gw+GW5, 8192, tid);          // w5 hi (8KB)
        stage(WLb, gw+GW5+8192, 8192, tid);     // w5 lo (8KB)
        writeback<1,1>(AHb, ALb, bias, 4, 0, wave, lane, a1, a2);
      }
      __syncthreads();
    }
  }

  // ---- conv5: 128 -> 32, quantize features (waves 0,1 only; no barriers) ----
  if (wave < 2) {
    f32x4 a1[1][1] = {}; f32x4 a2[1][1] = {};
    phaseF<1,1,0>(AHb, ALb, WHb, WLb, 0, wave, lane, 0, a1, a2);
    int c = wave*16 + (lane & 15);
    float bb = bias[5*128 + c];
#pragma unroll
    for (int q = 0; q < 4; ++q) {
      int s = ((lane >> 4) & 3)*4 + q;
      float f = a1[0][0][q] + a2[0][0][q]*LO_INV + bb;
      f = fminf(fmaxf(f, -1.0f), 127.0f/128.0f);
      int qi = clampi((int)rintf(f * 128.0f), -128, 127);
      feat[((long)chunkG*B + b0 + s)*32 + c] = (signed char)qi;
    }
  }
}

// ---------------------------------------------------------------------------
// value MLP: exact integer arithmetic (unchanged, verified round 1)
// ---------------------------------------------------------------------------
__global__ __launch_bounds__(256) void mlp_kernel(
    const signed char* __restrict__ feat,
    const int* __restrict__ mw,
    float* __restrict__ out, int B)
{
  int b = blockIdx.x * blockDim.x + threadIdx.x;
  if (b >= B) return;
  int S[32];
#pragma unroll
  for (int c = 0; c < 32; ++c) S[c] = 0;
  for (int ch = 0; ch < 16; ++ch) {
    const signed char* f = feat + ((long)ch*B + b)*32;
#pragma unroll
    for (int c = 0; c < 32; ++c) S[c] += f[c];
  }
  int x1[32];
#pragma unroll
  for (int c = 0; c < 32; ++c) x1[c] = clampi(S[c], -128, 127);

  const int* wq0 = mw;        const int* bq0 = mw + 1024;
  const int* wq1 = mw + 1056; const int* bq1 = mw + 2080;
  const int* wq2 = mw + 2112; const int* bq2 = mw + 2208;

  int x2[32];
#pragma unroll
  for (int o = 0; o < 32; ++o) {
    int acc = bq0[o];
    for (int i = 0; i < 32; ++i) acc += x1[i] * wq0[o*32 + i];
    acc = clampi(acc, 0, 32512);
    int r = acc >> 8, fr = acc & 255;
    r += (fr > 128 || (fr == 128 && (r & 1))) ? 1 : 0;
    x2[o] = r;
  }
  int x3[32];
#pragma unroll
  for (int o = 0; o < 32; ++o) {
    int acc = bq1[o];
    for (int i = 0; i < 32; ++i) acc += x2[i] * wq1[o*32 + i];
    acc = clampi(acc, 0, 16256);
    int r = acc >> 7, fr = acc & 127;
    r += (fr > 64 || (fr == 64 && (r & 1))) ? 1 : 0;
    x3[o] = r;
  }
  for (int o = 0; o < 3; ++o) {
    int acc = bq2[o];
    for (int i = 0; i < 32; ++i) acc += x3[i] * wq2[o*32 + i];
    out[b*3 + o] = (float)acc / 16384.0f;
  }
}

__global__ void zero_kernel(float4* __restrict__ p, int n4) {
  int i = blockIdx.x * blockDim.x + threadIdx.x;
  if (i < n4) p[i] = make_float4(0.f, 0.f, 0.f, 0.f);
}

// ---------------------------------------------------------------------------
extern "C" void kernel_launch(void* const* d_in, const int* in_sizes, int n_in,
                              void* d_out, int out_size, void* d_ws, size_t ws_size,
                              hipStream_t stream)
{
  const float* x   = (const float*)d_in[0];
  const float* w0  = (const float*)d_in[1];
  const float* b0  = (const float*)d_in[2];
  const float* w1  = (const float*)d_in[3];
  const float* b1  = (const float*)d_in[4];
  const float* w2  = (const float*)d_in[5];
  const float* b2  = (const float*)d_in[6];
  const float* w3  = (const float*)d_in[7];
  const float* b3  = (const float*)d_in[8];
  const float* w4  = (const float*)d_in[9];
  const float* b4  = (const float*)d_in[10];
  const float* w5  = (const float*)d_in[11];
  const float* b5  = (const float*)d_in[12];
  const float* bn1 = (const float*)d_in[13];
  const float* bn2 = (const float*)d_in[14];
  const float* bn3 = (const float*)d_in[15];
  const float* bn4 = (const float*)d_in[16];
  const float* bn5 = (const float*)d_in[17];
  const float* vw0 = (const float*)d_in[18];
  const float* vb0 = (const float*)d_in[19];
  const float* vw1 = (const float*)d_in[20];
  const float* vb1 = (const float*)d_in[21];
  const float* vw2 = (const float*)d_in[22];
  const float* vb2 = (const float*)d_in[23];

  const int B = in_sizes[0] / 98;
  float* ws = (float*)d_ws;
  signed char* feat = (signed char*)d_ws + FEAT_OFF_BYTES;
  float* out = (float*)d_out;

  (void)hipFuncSetAttribute((const void*)conv_mfma,
                            hipFuncAttributeMaxDynamicSharedMemorySize, LDS_TOTAL);

  prep_kernel<<<(511395 + 255)/256, 256, 0, stream>>>(
      w0,b0,w1,b1,w2,b2,w3,b3,w4,b4,w5,b5,
      bn1,bn2,bn3,bn4,bn5, vw0,vb0,vw1,vb1,vw2,vb2, ws);

  conv_mfma<<<B, 512, LDS_TOTAL, stream>>>(
      x, (const char*)d_ws, feat, B, B/16);

  mlp_kernel<<<(B + 255)/256, 256, 0, stream>>>(feat, (const int*)d_ws + MLP_WORD_OFF, out, B);

  {
    int n4 = B*49/4;
    zero_kernel<<<(n4 + 255)/256, 256, 0, stream>>>((float4*)(out + 3*B), n4);
  }
}

// Round 9
// 1528.520 us; speedup vs baseline: 4.7620x; 1.0660x over previous
//
#include <hip/hip_runtime.h>
#include <stdint.h>

// ---------------------------------------------------------------------------
// FlatSquare7x7NNUEv4 — round 9: layer-specific LDS swizzles. Round 8's
// 2.38e8 bank-conflict cycles (~6 cyc/read) come from gathered reads:
// conv2's 9s+{0,1,3,4} rows are row&7-nonuniform; conv4's 4r+blk rows hit
// only 2/8 bank groups (8-way). Since the act buffer is rewritten each
// layer, each generation gets a swizzle tuned to its reader:
//   gen0/2/4 (contiguous reads): f = row&7        (standard)
//   gen1 (conv2-in):             f = ((s&3)<<1)|(w&1), row = 9s+w
//   gen3 (conv4-in):             f = (row>>2)&7
// Everything else identical to round 8.
//   A·W = Ah·Wh + 2^-11*(Als·Wh + Ah·Wls)
// ---------------------------------------------------------------------------

typedef _Float16 f16x8 __attribute__((ext_vector_type(8)));
typedef float f32x4 __attribute__((ext_vector_type(4)));

// chunk tables: groups: [0..3]=g0, [4..11]=g1, [12..15]=g2
static __device__ __constant__ int CH_Y0[16] = {0,0,3,3, 0,1,3,2, 1,0,2,3, 1,1,2,2};
static __device__ __constant__ int CH_X0[16] = {0,3,3,0, 1,3,2,0, 0,2,3,1, 1,2,2,1};
static __device__ __constant__ int CH_K [16] = {0,1,2,3, 0,1,2,3, 0,1,2,3, 0,1,2,3};
static __device__ __constant__ int CH_T [16] = {0,0,0,0, 0,0,0,0, 1,1,1,1, 0,0,0,0};

// ---- LDS layout (bytes) ----
#define AH_OFF   0         // Ah  [144][128] f16 = 36864
#define AL_OFF   36864     // Als [144][128] f16 = 36864
#define WH_OFF   73728     // weight half H, 32KB
#define WL_OFF   106496    // weight half L, 32KB
#define XIN_OFF  139264    // [16][2][16] f32 = 2048
#define W0_OFF   141312    // [8][128] f32 = 4096
#define BIAS_OFF 145408    // [6][128] f32 = 3072
#define LDS_TOTAL 148480

// ---- global weight image (bytes within group) ----
#define G_STRIDE 678912
#define GW1   0
#define GW2   65536
#define GW3   327680
#define GW4   393216
#define GW5   655360
#define GW0   671744
#define GBIAS 675840
#define G_WORDS   167936     // f16 region words per group (656KB/4)
#define G_STRIDE_W 169728    // group stride in words
#define MLP_WORD_OFF 509184
#define FEAT_OFF_BYTES (2*1024*1024)

#define LO_SCALE 2048.0f
#define LO_INV   (1.0f/2048.0f)

__device__ __forceinline__ int swz(int b) { return b ^ (((b>>8)&7)<<4); }
__device__ __forceinline__ int base3(int z){ return (z>>1)*3 + (z&1); }
__device__ __forceinline__ int clampi(int v, int lo, int hi) { return v < lo ? lo : (v > hi ? hi : v); }

__device__ inline float bninv(const float* bn, int g, int C, int c) {
  float ga = bn[(g*4+0)*C + c];
  float va = bn[(g*4+3)*C + c];
  return ga / sqrtf(va + 1e-5f);
}
__device__ inline int q8(float x) { return clampi((int)rintf(x), -128, 127); }

// ---------------------------------------------------------------------------
// prep: fold BN, transpose to [oc][k], split f16 hi / lo*2^11, pre-swizzle
// (weights keep the standard row&7 swizzle — unchanged)
// ---------------------------------------------------------------------------
__global__ void prep_kernel(
    const float* __restrict__ w0, const float* __restrict__ b0,
    const float* __restrict__ w1, const float* __restrict__ b1,
    const float* __restrict__ w2, const float* __restrict__ b2,
    const float* __restrict__ w3, const float* __restrict__ b3,
    const float* __restrict__ w4, const float* __restrict__ b4,
    const float* __restrict__ w5, const float* __restrict__ b5,
    const float* __restrict__ bn1, const float* __restrict__ bn2,
    const float* __restrict__ bn3, const float* __restrict__ bn4,
    const float* __restrict__ bn5,
    const float* __restrict__ vw0, const float* __restrict__ vb0,
    const float* __restrict__ vw1, const float* __restrict__ vb1,
    const float* __restrict__ vw2, const float* __restrict__ vb2,
    float* __restrict__ ws)
{
  int idx = blockIdx.x * blockDim.x + threadIdx.x;
  if (idx < 3*G_WORDS) {
    uint32_t* wsU = (uint32_t*)ws;
    int g = idx / G_WORDS;
    int q = idx - g*G_WORDS;
    int stage, blk = 0, sub;
    if      (q < 16384)  { stage = 1; sub = q; }
    else if (q < 81920)  { stage = 2; blk = (q-16384)>>14; sub = (q-16384)&16383; }
    else if (q < 98304)  { stage = 3; sub = q-81920; }
    else if (q < 163840) { stage = 4; blk = (q-98304)>>14; sub = (q-98304)&16383; }
    else                 { stage = 5; sub = q-163840; }
    int isLo, r;
    if (stage == 5) { isLo = sub>>11; r = sub&2047; }
    else            { isLo = sub>>13; r = sub&8191; }
    int pb = r*4;
    int lb = pb ^ (((pb>>8)&7)<<4);     // inverse of kernel-side std swizzle
    int oc = lb>>8;
    int k0 = (lb&255)>>1;               // even f16 index; word = (k0, k0+1)
    float inv, v0, v1;
    if (stage == 1) {
      inv = bninv(bn1,g,128,oc);
      v0 = w1[(g*128+oc)*128+k0]; v1 = w1[(g*128+oc)*128+k0+1];
    } else if (stage == 2) {
      inv = bninv(bn2,g,128,oc);
      v0 = w2[((g*128+oc)*128+k0)*4+blk]; v1 = w2[((g*128+oc)*128+k0+1)*4+blk];
    } else if (stage == 3) {
      inv = bninv(bn3,g,128,oc);
      v0 = w3[(g*128+oc)*128+k0]; v1 = w3[(g*128+oc)*128+k0+1];
    } else if (stage == 4) {
      inv = bninv(bn4,g,128,oc);
      v0 = w4[((g*128+oc)*128+k0)*4+blk]; v1 = w4[((g*128+oc)*128+k0+1)*4+blk];
    } else {
      inv = bninv(bn5,g,32,oc);
      v0 = w5[(g*32+oc)*128+k0]; v1 = w5[(g*32+oc)*128+k0+1];
    }
    v0 *= inv; v1 *= inv;
    _Float16 h0 = (_Float16)v0, h1 = (_Float16)v1;
    if (isLo) {
      h0 = (_Float16)((v0 - (float)h0) * LO_SCALE);
      h1 = (_Float16)((v1 - (float)h1) * LO_SCALE);
    }
    union { _Float16 h[2]; uint32_t u; } uu;
    uu.h[0] = h0; uu.h[1] = h1;
    wsU[g*G_STRIDE_W + q] = uu.u;
  } else if (idx < 506880) {            // w0: [k=8][c=128] fp32
    int e = idx - 503808; int g = e>>10; int t2 = e&1023;
    int k = t2>>7, c = t2&127;
    ws[g*G_STRIDE_W + 167936 + t2] = w0[((g*128 + c)*2 + (k>>2))*4 + (k&3)];
  } else if (idx < 509184) {            // folded biases [6][128] fp32
    int e = idx - 506880; int g = e/768; int r = e - g*768;
    int l = r>>7, c = r&127;
    float t;
    if (l == 0) {
      t = b0[g*128 + c];
    } else if (l < 5) {
      const float* bn = (l==1) ? bn1 : (l==2) ? bn2 : (l==3) ? bn3 : bn4;
      const float* bb = (l==1) ? b1  : (l==2) ? b2  : (l==3) ? b3  : b4;
      float inv = bninv(bn, g, 128, c);
      t = (bb[g*128 + c] - bn[(g*4+2)*128 + c]) * inv + bn[(g*4+1)*128 + c];
    } else {
      if (c < 32) {
        float inv = bninv(bn5, g, 32, c);
        t = (b5[g*32 + c] - bn5[(g*4+2)*32 + c]) * inv + bn5[(g*4+1)*32 + c];
      } else t = 0.f;
    }
    ws[g*G_STRIDE_W + 168960 + r] = t;
  } else if (idx < 511395) {            // quantized MLP ints
    int e = idx - MLP_WORD_OFF;
    int* wsI = (int*)ws;
    int val;
    if      (e < 1024) val = q8(vw0[e] * 256.f);
    else if (e < 1056) val = (int)rintf(vb0[e-1024] * 32768.f);
    else if (e < 2080) val = q8(vw1[e-1056] * 128.f);
    else if (e < 2112) val = (int)rintf(vb1[e-2080] * 16384.f);
    else if (e < 2208) val = q8(vw2[e-2112] * 128.f);
    else               val = (int)rintf(vb2[e-2208] * 16384.f);
    wsI[idx] = val;
  }
}

// ---------------------------------------------------------------------------
// fused MFMA conv stack
// ---------------------------------------------------------------------------
__device__ __forceinline__ void gl16(void* l, const void* g) {
  __builtin_amdgcn_global_load_lds(
      (const __attribute__((address_space(1))) void*)(uintptr_t)g,
      (__attribute__((address_space(3))) void*)(uint32_t)(uintptr_t)l,
      16, 0, 0);
}

__device__ __forceinline__ void stage(char* ldsbase, const char* gsrc, int bytes, int tid) {
  for (int off = tid*16; off < bytes; off += 8192)
    gl16(ldsbase + off, gsrc + off);
}

#define MFMA(a,b,c) __builtin_amdgcn_mfma_f32_16x16x32_f16((a),(b),(c),0,0,0)

// Fused hi/lo phase: Bh/Bl resident, per-m Ah/Al read once, 3 MFMAs fired.
// MODE 0: contiguous rows, std swizzle f=row&7.
// MODE 2: conv2 gather from gen1 layout, f=((s&3)<<1)|(w&1), row=9s+w.
// MODE 4: conv4 gather from gen3 layout, f=(row>>2)&7 (== rr&7 since blk<4).
template<int MT, int NT, int MODE>
__device__ __forceinline__ void phaseF(const char* AHb, const char* ALb,
    const char* WHb, const char* WLb,
    int m0, int n0, int lane, int blk, f32x4 acc1[][NT], f32x4 acc2[][NT])
{
  const int l15 = lane & 15, kq = (lane >> 4) & 3;
#pragma unroll
  for (int kb = 0; kb < 4; ++kb) {
    const int ko2 = (kb*32 + kq*8)*2;
    f16x8 Bh_[NT], Bl_[NT];
#pragma unroll
    for (int n = 0; n < NT; ++n) {
      int brow = (n0+n)*16 + l15;
      int boff = (brow*256 + ko2) ^ ((brow&7)<<4);   // weights: std swizzle
      Bh_[n] = *(const f16x8*)(WHb + boff);
      Bl_[n] = *(const f16x8*)(WLb + boff);
    }
#pragma unroll
    for (int m = 0; m < MT; ++m) {
      const int rr = (m0+m)*16 + l15;
      int row, f;
      if (MODE == 0)      { row = rr; f = rr & 7; }
      else if (MODE == 2) { int s = rr>>2; int w = base3(rr&3) + base3(blk);
                            row = s*9 + w; f = ((s&3)<<1) | (w&1); }
      else                { row = rr*4 + blk; f = rr & 7; }
      const int aoff = (row*256 + ko2) ^ (f<<4);
      f16x8 Ah = *(const f16x8*)(AHb + aoff);
      f16x8 Al = *(const f16x8*)(ALb + aoff);
#pragma unroll
      for (int n = 0; n < NT; ++n) {
        acc1[m][n] = MFMA(Ah, Bh_[n], acc1[m][n]);
        acc2[m][n] = MFMA(Al, Bh_[n], acc2[m][n]);
        acc2[m][n] = MFMA(Ah, Bl_[n], acc2[m][n]);
      }
    }
  }
}

// GEN 0: f=row&7; GEN 2: f=((s&3)<<1)|(w&1) (row=9s+w, s=(row*57)>>9 exact
// for row<144); GEN 4: f=(row>>2)&7.
template<int GEN>
__device__ __forceinline__ void wbvalG(char* ah, char* al, int row, int col, float v) {
  _Float16 h = (_Float16)v;
  _Float16 l = (_Float16)((v - (float)h) * LO_SCALE);
  int f;
  if (GEN == 0)      f = row & 7;
  else if (GEN == 2) { int s = (row*57)>>9; int w = row - s*9; f = ((s&3)<<1) | (w&1); }
  else               f = (row >> 2) & 7;
  int sb = (row*256 + col*2) ^ (f<<4);
  *(_Float16*)(ah + sb) = h;
  *(_Float16*)(al + sb) = l;
}

template<int MT, int NT, int GEN>
__device__ __forceinline__ void writeback(char* AHb, char* ALb, const float* bias,
    int layer, int m0, int n0, int lane, f32x4 acc1[][NT], f32x4 acc2[][NT])
{
  const int l15 = lane & 15, rq = (lane >> 4) & 3;
#pragma unroll
  for (int m = 0; m < MT; ++m)
#pragma unroll
    for (int n = 0; n < NT; ++n) {
      int col = (n0+n)*16 + l15;
      float bb = bias[layer*128 + col];
#pragma unroll
      for (int q = 0; q < 4; ++q) {
        int row = (m0+m)*16 + rq*4 + q;
        float v = acc1[m][n][q] + acc2[m][n][q]*LO_INV + bb;
        v = fmaxf(v, 0.f);
        wbvalG<GEN>(AHb, ALb, row, col, v);
      }
    }
}

__global__ __launch_bounds__(512, 1)
void conv_mfma(
    const float* __restrict__ x, const char* __restrict__ wsb,
    signed char* __restrict__ feat, int B, int wgPerChunk)
{
  extern __shared__ char lds[];
  char* AHb = lds + AH_OFF;
  char* ALb = lds + AL_OFF;
  char* WHb = lds + WH_OFF;
  char* WLb = lds + WL_OFF;
  const float* bias = (const float*)(lds + BIAS_OFF);

  const int tid  = threadIdx.x;
  const int lane = tid & 63;
  const int wave = tid >> 6;
  const int mslot = wave >> 2;          // 0-1
  const int nslot = wave & 3;           // 0-3

  const int wg = blockIdx.x;
  const int chunkG = wg / wgPerChunk;
  const int b0 = (wg - chunkG*wgPerChunk) * 16;
  const int g = (chunkG < 4) ? 0 : (chunkG < 12) ? 1 : 2;
  const char* gw = wsb + g*G_STRIDE;

  // ---- prologue staging ----
  {
    int s = tid >> 5, v = tid & 31;
    int ic = v >> 4, pos = v & 15;
    int i = pos >> 2, j = pos & 3;
    int tt = CH_T[chunkG], kk = CH_K[chunkG];
    int a = tt ? j : i, bb2 = tt ? i : j;
    int py, px;
    if      (kk == 0) { py = a;     px = bb2;   }
    else if (kk == 1) { py = bb2;   px = 3-a;   }
    else if (kk == 2) { py = 3-a;   px = 3-bb2; }
    else              { py = 3-bb2; px = a;     }
    int sy = CH_Y0[chunkG] + py, sx = CH_X0[chunkG] + px;
    ((float*)(lds+XIN_OFF))[s*32 + v] = x[((b0+s)*2 + ic)*49 + sy*7 + sx];
  }
  if (tid < 256) ((float4*)(lds+W0_OFF))[tid]   = ((const float4*)(gw+GW0))[tid];
  if (tid < 192) ((float4*)(lds+BIAS_OFF))[tid] = ((const float4*)(gw+GBIAS))[tid];
  stage(WHb, gw+GW1,       32768, tid);   // w1 hi
  stage(WLb, gw+GW1+32768, 32768, tid);   // w1 lo
  __syncthreads();

  // ---- conv0 (VALU, K=8), writes gen0 (std swizzle) ----
  {
    const float* xin = (const float*)(lds+XIN_OFF);
    const float* w0s = (const float*)(lds+W0_OFF);
    int c = tid & 127;
    float wr[8];
#pragma unroll
    for (int k = 0; k < 8; ++k) wr[k] = w0s[k*128 + c];
    float b0c = bias[c];
    int sg = tid >> 7;
#pragma unroll
    for (int si = 0; si < 4; ++si) {
      int s = sg*4 + si;
      float xv[32];
#pragma unroll
      for (int t2 = 0; t2 < 32; ++t2) xv[t2] = xin[s*32 + t2];
#pragma unroll
      for (int oy = 0; oy < 3; ++oy)
#pragma unroll
        for (int ox = 0; ox < 3; ++ox) {
          float acc0 = b0c;
#pragma unroll
          for (int ic2 = 0; ic2 < 2; ++ic2)
#pragma unroll
            for (int dy = 0; dy < 2; ++dy)
#pragma unroll
              for (int dx = 0; dx < 2; ++dx)
                acc0 = fmaf(xv[ic2*16 + (oy+dy)*4 + ox+dx], wr[ic2*4+dy*2+dx], acc0);
          wbvalG<0>(AHb, ALb, s*9 + oy*3 + ox, c, fmaxf(acc0, 0.f));
        }
    }
  }
  __syncthreads();                              // act ready, w1 ready

  // ---- conv1: reads gen0 (MODE 0), writes gen1 (GEN 2, conv2-optimal) ----
  {
    {
      f32x4 a1[4][2] = {}; f32x4 a2[4][2] = {};
      phaseF<4,2,0>(AHb, ALb, WHb, WLb, mslot*4, nslot*2, lane, 0, a1, a2);
      __syncthreads();                          // all pass0 reads done
      writeback<4,2,2>(AHb, ALb, bias, 1, mslot*4, nslot*2, lane, a1, a2);
    }
    {
      // pass1 reads rows 128-143 (gen0) — disjoint from pass0 WB rows 0-127
      f32x4 a1[1][1] = {}; f32x4 a2[1][1] = {};
      phaseF<1,1,0>(AHb, ALb, WHb, WLb, 8, wave, lane, 0, a1, a2);
      __syncthreads();                          // pass1 reads + pass0 WB done
      writeback<1,1,2>(AHb, ALb, bias, 1, 8, wave, lane, a1, a2);
      stage(WHb, gw+GW2, 32768, tid);           // w2 blk0 hi (w1 fully read)
      stage(WLb, gw+GW2+32768, 32768, tid);     // w2 blk0 lo
      __syncthreads();                          // w2b0 + pass1 WB ready
    }
  }

  // ---- conv2: gathers gen1 (MODE 2), writes gen2 (GEN 0) ----
  {
    f32x4 a1[2][2] = {}; f32x4 a2[2][2] = {};
#pragma unroll
    for (int blk = 0; blk < 4; ++blk) {
      phaseF<2,2,2>(AHb, ALb, WHb, WLb, mslot*2, nslot*2, lane, blk, a1, a2);
      __syncthreads();                          // blk reads done
      if (blk < 3) {
        stage(WHb, gw+GW2+(blk+1)*65536, 32768, tid);
        stage(WLb, gw+GW2+(blk+1)*65536+32768, 32768, tid);
      } else {
        stage(WHb, gw+GW3, 32768, tid);         // w3 hi
        stage(WLb, gw+GW3+32768, 32768, tid);   // w3 lo
        writeback<2,2,0>(AHb, ALb, bias, 2, mslot*2, nslot*2, lane, a1, a2);
      }
      __syncthreads();                          // staged (+WB on last) ready
    }
  }

  // ---- conv3: reads gen2 (MODE 0), writes gen3 (GEN 4, conv4-optimal) ----
  {
    f32x4 a1[2][2] = {}; f32x4 a2[2][2] = {};
    phaseF<2,2,0>(AHb, ALb, WHb, WLb, mslot*2, nslot*2, lane, 0, a1, a2);
    __syncthreads();                            // conv3 reads done (w3 done)
    stage(WHb, gw+GW4, 32768, tid);             // w4 blk0 hi
    stage(WLb, gw+GW4+32768, 32768, tid);       // w4 blk0 lo
    writeback<2,2,4>(AHb, ALb, bias, 3, mslot*2, nslot*2, lane, a1, a2);
    __syncthreads();
  }

  // ---- conv4: gathers gen3 (MODE 4), writes gen4 (GEN 0) ----
  {
    f32x4 a1[1][1] = {}; f32x4 a2[1][1] = {};
#pragma unroll
    for (int blk = 0; blk < 4; ++blk) {
      phaseF<1,1,4>(AHb, ALb, WHb, WLb, 0, wave, lane, blk, a1, a2);
      __syncthreads();                          // blk reads done
      if (blk < 3) {
        stage(WHb, gw+GW4+(blk+1)*65536, 32768, tid);
        stage(WLb, gw+GW4+(blk+1)*65536+32768, 32768, tid);
      } else {
        stage(WHb, gw+GW5, 8192, tid);          // w5 hi (8KB)
        stage(WLb, gw+GW5+8192, 8192, tid);     // w5 lo (8KB)
        writeback<1,1,0>(AHb, ALb, bias, 4, 0, wave, lane, a1, a2);
      }
      __syncthreads();
    }
  }

  // ---- conv5: reads gen4 (MODE 0), quantize features (waves 0,1 only) ----
  if (wave < 2) {
    f32x4 a1[1][1] = {}; f32x4 a2[1][1] = {};
    phaseF<1,1,0>(AHb, ALb, WHb, WLb, 0, wave, lane, 0, a1, a2);
    int c = wave*16 + (lane & 15);
    float bb = bias[5*128 + c];
#pragma unroll
    for (int q = 0; q < 4; ++q) {
      int s = ((lane >> 4) & 3)*4 + q;
      float f = a1[0][0][q] + a2[0][0][q]*LO_INV + bb;
      f = fminf(fmaxf(f, -1.0f), 127.0f/128.0f);
      int qi = clampi((int)rintf(f * 128.0f), -128, 127);
      feat[((long)chunkG*B + b0 + s)*32 + c] = (signed char)qi;
    }
  }
}

// ---------------------------------------------------------------------------
// value MLP: exact integer arithmetic (unchanged, verified round 1)
// ---------------------------------------------------------------------------
__global__ __launch_bounds__(256) void mlp_kernel(
    const signed char* __restrict__ feat,
    const int* __restrict__ mw,
    float* __restrict__ out, int B)
{
  int b = blockIdx.x * blockDim.x + threadIdx.x;
  if (b >= B) return;
  int S[32];
#pragma unroll
  for (int c = 0; c < 32; ++c) S[c] = 0;
  for (int ch = 0; ch < 16; ++ch) {
    const signed char* f = feat + ((long)ch*B + b)*32;
#pragma unroll
    for (int c = 0; c < 32; ++c) S[c] += f[c];
  }
  int x1[32];
#pragma unroll
  for (int c = 0; c < 32; ++c) x1[c] = clampi(S[c], -128, 127);

  const int* wq0 = mw;        const int* bq0 = mw + 1024;
  const int* wq1 = mw + 1056; const int* bq1 = mw + 2080;
  const int* wq2 = mw + 2112; const int* bq2 = mw + 2208;

  int x2[32];
#pragma unroll
  for (int o = 0; o < 32; ++o) {
    int acc = bq0[o];
    for (int i = 0; i < 32; ++i) acc += x1[i] * wq0[o*32 + i];
    acc = clampi(acc, 0, 32512);
    int r = acc >> 8, fr = acc & 255;
    r += (fr > 128 || (fr == 128 && (r & 1))) ? 1 : 0;
    x2[o] = r;
  }
  int x3[32];
#pragma unroll
  for (int o = 0; o < 32; ++o) {
    int acc = bq1[o];
    for (int i = 0; i < 32; ++i) acc += x2[i] * wq1[o*32 + i];
    acc = clampi(acc, 0, 16256);
    int r = acc >> 7, fr = acc & 127;
    r += (fr > 64 || (fr == 64 && (r & 1))) ? 1 : 0;
    x3[o] = r;
  }
  for (int o = 0; o < 3; ++o) {
    int acc = bq2[o];
    for (int i = 0; i < 32; ++i) acc += x3[i] * wq2[o*32 + i];
    out[b*3 + o] = (float)acc / 16384.0f;
  }
}

__global__ void zero_kernel(float4* __restrict__ p, int n4) {
  int i = blockIdx.x * blockDim.x + threadIdx.x;
  if (i < n4) p[i] = make_float4(0.f, 0.f, 0.f, 0.f);
}

// ---------------------------------------------------------------------------
extern "C" void kernel_launch(void* const* d_in, const int* in_sizes, int n_in,
                              void* d_out, int out_size, void* d_ws, size_t ws_size,
                              hipStream_t stream)
{
  const float* x   = (const float*)d_in[0];
  const float* w0  = (const float*)d_in[1];
  const float* b0  = (const float*)d_in[2];
  const float* w1  = (const float*)d_in[3];
  const float* b1  = (const float*)d_in[4];
  const float* w2  = (const float*)d_in[5];
  const float* b2  = (const float*)d_in[6];
  const float* w3  = (const float*)d_in[7];
  const float* b3  = (const float*)d_in[8];
  const float* w4  = (const float*)d_in[9];
  const float* b4  = (const float*)d_in[10];
  const float* w5  = (const float*)d_in[11];
  const float* b5  = (const float*)d_in[12];
  const float* bn1 = (const float*)d_in[13];
  const float* bn2 = (const float*)d_in[14];
  const float* bn3 = (const float*)d_in[15];
  const float* bn4 = (const float*)d_in[16];
  const float* bn5 = (const float*)d_in[17];
  const float* vw0 = (const float*)d_in[18];
  const float* vb0 = (const float*)d_in[19];
  const float* vw1 = (const float*)d_in[20];
  const float* vb1 = (const float*)d_in[21];
  const float* vw2 = (const float*)d_in[22];
  const float* vb2 = (const float*)d_in[23];

  const int B = in_sizes[0] / 98;
  float* ws = (float*)d_ws;
  signed char* feat = (signed char*)d_ws + FEAT_OFF_BYTES;
  float* out = (float*)d_out;

  (void)hipFuncSetAttribute((const void*)conv_mfma,
                            hipFuncAttributeMaxDynamicSharedMemorySize, LDS_TOTAL);

  prep_kernel<<<(511395 + 255)/256, 256, 0, stream>>>(
      w0,b0,w1,b1,w2,b2,w3,b3,w4,b4,w5,b5,
      bn1,bn2,bn3,bn4,bn5, vw0,vb0,vw1,vb1,vw2,vb2, ws);

  conv_mfma<<<B, 512, LDS_TOTAL, stream>>>(
      x, (const char*)d_ws, feat, B, B/16);

  mlp_kernel<<<(B + 255)/256, 256, 0, stream>>>(feat, (const int*)d_ws + MLP_WORD_OFF, out, B);

  {
    int n4 = B*49/4;
    zero_kernel<<<(n4 + 255)/256, 256, 0, stream>>>((float4*)(out + 3*B), n4);
  }
}

// Round 10
// 1333.799 us; speedup vs baseline: 5.4572x; 1.1460x over previous
//
#include <hip/hip_runtime.h>
#include <stdint.h>

// ---------------------------------------------------------------------------
// FlatSquare7x7NNUEv4 — round 10: weights read directly from global (L2-hot,
// pre-swizzled image; same fragment offset math) instead of LDS staging.
// Effects: (a) LDS reads drop ~47% (B-share); (b) LDS 148K->74K => 2 WGs/CU,
// so barrier/latency stalls overlap across WGs; (c) 23 -> 10 barriers
// (conv2/conv4 inner loops barrier-free). __launch_bounds__(512,2) caps
// VGPR at 128 to guarantee 2-WG occupancy.
//   A·W = Ah·Wh + 2^-11*(Als·Wh + Ah·Wls)
// ---------------------------------------------------------------------------

typedef _Float16 f16x8 __attribute__((ext_vector_type(8)));
typedef float f32x4 __attribute__((ext_vector_type(4)));

// chunk tables: groups: [0..3]=g0, [4..11]=g1, [12..15]=g2
static __device__ __constant__ int CH_Y0[16] = {0,0,3,3, 0,1,3,2, 1,0,2,3, 1,1,2,2};
static __device__ __constant__ int CH_X0[16] = {0,3,3,0, 1,3,2,0, 0,2,3,1, 1,2,2,1};
static __device__ __constant__ int CH_K [16] = {0,1,2,3, 0,1,2,3, 0,1,2,3, 0,1,2,3};
static __device__ __constant__ int CH_T [16] = {0,0,0,0, 0,0,0,0, 1,1,1,1, 0,0,0,0};

// ---- LDS layout (bytes): activations + input stage only ----
#define AH_OFF   0         // Ah  [144][128] f16 = 36864
#define AL_OFF   36864     // Als [144][128] f16 = 36864
#define XIN_OFF  73728     // [16][2][16] f32 = 2048
#define LDS_TOTAL 75776

// ---- global weight image (bytes within group) ----
#define G_STRIDE 678912
#define GW1   0
#define GW2   65536
#define GW3   327680
#define GW4   393216
#define GW5   655360
#define GW0   671744
#define GBIAS 675840
#define G_WORDS   167936     // f16 region words per group (656KB/4)
#define G_STRIDE_W 169728    // group stride in words
#define MLP_WORD_OFF 509184
#define FEAT_OFF_BYTES (2*1024*1024)

#define LO_SCALE 2048.0f
#define LO_INV   (1.0f/2048.0f)

__device__ __forceinline__ int base3(int z){ return (z>>1)*3 + (z&1); }
__device__ __forceinline__ int clampi(int v, int lo, int hi) { return v < lo ? lo : (v > hi ? hi : v); }

__device__ inline float bninv(const float* bn, int g, int C, int c) {
  float ga = bn[(g*4+0)*C + c];
  float va = bn[(g*4+3)*C + c];
  return ga / sqrtf(va + 1e-5f);
}
__device__ inline int q8(float x) { return clampi((int)rintf(x), -128, 127); }

// ---------------------------------------------------------------------------
// prep: fold BN, transpose to [oc][k], split f16 hi / lo*2^11, pre-swizzle
// (row&7 XOR swizzle baked into the image; kernel reads with same math)
// ---------------------------------------------------------------------------
__global__ void prep_kernel(
    const float* __restrict__ w0, const float* __restrict__ b0,
    const float* __restrict__ w1, const float* __restrict__ b1,
    const float* __restrict__ w2, const float* __restrict__ b2,
    const float* __restrict__ w3, const float* __restrict__ b3,
    const float* __restrict__ w4, const float* __restrict__ b4,
    const float* __restrict__ w5, const float* __restrict__ b5,
    const float* __restrict__ bn1, const float* __restrict__ bn2,
    const float* __restrict__ bn3, const float* __restrict__ bn4,
    const float* __restrict__ bn5,
    const float* __restrict__ vw0, const float* __restrict__ vb0,
    const float* __restrict__ vw1, const float* __restrict__ vb1,
    const float* __restrict__ vw2, const float* __restrict__ vb2,
    float* __restrict__ ws)
{
  int idx = blockIdx.x * blockDim.x + threadIdx.x;
  if (idx < 3*G_WORDS) {
    uint32_t* wsU = (uint32_t*)ws;
    int g = idx / G_WORDS;
    int q = idx - g*G_WORDS;
    int stage, blk = 0, sub;
    if      (q < 16384)  { stage = 1; sub = q; }
    else if (q < 81920)  { stage = 2; blk = (q-16384)>>14; sub = (q-16384)&16383; }
    else if (q < 98304)  { stage = 3; sub = q-81920; }
    else if (q < 163840) { stage = 4; blk = (q-98304)>>14; sub = (q-98304)&16383; }
    else                 { stage = 5; sub = q-163840; }
    int isLo, r;
    if (stage == 5) { isLo = sub>>11; r = sub&2047; }
    else            { isLo = sub>>13; r = sub&8191; }
    int pb = r*4;
    int lb = pb ^ (((pb>>8)&7)<<4);     // inverse of kernel-side std swizzle
    int oc = lb>>8;
    int k0 = (lb&255)>>1;               // even f16 index; word = (k0, k0+1)
    float inv, v0, v1;
    if (stage == 1) {
      inv = bninv(bn1,g,128,oc);
      v0 = w1[(g*128+oc)*128+k0]; v1 = w1[(g*128+oc)*128+k0+1];
    } else if (stage == 2) {
      inv = bninv(bn2,g,128,oc);
      v0 = w2[((g*128+oc)*128+k0)*4+blk]; v1 = w2[((g*128+oc)*128+k0+1)*4+blk];
    } else if (stage == 3) {
      inv = bninv(bn3,g,128,oc);
      v0 = w3[(g*128+oc)*128+k0]; v1 = w3[(g*128+oc)*128+k0+1];
    } else if (stage == 4) {
      inv = bninv(bn4,g,128,oc);
      v0 = w4[((g*128+oc)*128+k0)*4+blk]; v1 = w4[((g*128+oc)*128+k0+1)*4+blk];
    } else {
      inv = bninv(bn5,g,32,oc);
      v0 = w5[(g*32+oc)*128+k0]; v1 = w5[(g*32+oc)*128+k0+1];
    }
    v0 *= inv; v1 *= inv;
    _Float16 h0 = (_Float16)v0, h1 = (_Float16)v1;
    if (isLo) {
      h0 = (_Float16)((v0 - (float)h0) * LO_SCALE);
      h1 = (_Float16)((v1 - (float)h1) * LO_SCALE);
    }
    union { _Float16 h[2]; uint32_t u; } uu;
    uu.h[0] = h0; uu.h[1] = h1;
    wsU[g*G_STRIDE_W + q] = uu.u;
  } else if (idx < 506880) {            // w0: [k=8][c=128] fp32
    int e = idx - 503808; int g = e>>10; int t2 = e&1023;
    int k = t2>>7, c = t2&127;
    ws[g*G_STRIDE_W + 167936 + t2] = w0[((g*128 + c)*2 + (k>>2))*4 + (k&3)];
  } else if (idx < 509184) {            // folded biases [6][128] fp32
    int e = idx - 506880; int g = e/768; int r = e - g*768;
    int l = r>>7, c = r&127;
    float t;
    if (l == 0) {
      t = b0[g*128 + c];
    } else if (l < 5) {
      const float* bn = (l==1) ? bn1 : (l==2) ? bn2 : (l==3) ? bn3 : bn4;
      const float* bb = (l==1) ? b1  : (l==2) ? b2  : (l==3) ? b3  : b4;
      float inv = bninv(bn, g, 128, c);
      t = (bb[g*128 + c] - bn[(g*4+2)*128 + c]) * inv + bn[(g*4+1)*128 + c];
    } else {
      if (c < 32) {
        float inv = bninv(bn5, g, 32, c);
        t = (b5[g*32 + c] - bn5[(g*4+2)*32 + c]) * inv + bn5[(g*4+1)*32 + c];
      } else t = 0.f;
    }
    ws[g*G_STRIDE_W + 168960 + r] = t;
  } else if (idx < 511395) {            // quantized MLP ints
    int e = idx - MLP_WORD_OFF;
    int* wsI = (int*)ws;
    int val;
    if      (e < 1024) val = q8(vw0[e] * 256.f);
    else if (e < 1056) val = (int)rintf(vb0[e-1024] * 32768.f);
    else if (e < 2080) val = q8(vw1[e-1056] * 128.f);
    else if (e < 2112) val = (int)rintf(vb1[e-2080] * 16384.f);
    else if (e < 2208) val = q8(vw2[e-2112] * 128.f);
    else               val = (int)rintf(vb2[e-2208] * 16384.f);
    wsI[idx] = val;
  }
}

// ---------------------------------------------------------------------------
// fused MFMA conv stack — B operand direct from global
// ---------------------------------------------------------------------------
#define MFMA(a,b,c) __builtin_amdgcn_mfma_f32_16x16x32_f16((a),(b),(c),0,0,0)

// Fused hi/lo phase. A from LDS, B from global (pre-swizzled image).
// MODE 0: contiguous rows, f=row&7.
// MODE 2: conv2 gather from gen1 layout, f=((s&3)<<1)|(w&1), row=9s+w.
// MODE 4: conv4 gather from gen3 layout, f=rr&7 on rr (row=rr*4+blk).
template<int MT, int NT, int MODE>
__device__ __forceinline__ void phaseF(const char* AHb, const char* ALb,
    const char* __restrict__ gwH, const char* __restrict__ gwL,
    int m0, int n0, int lane, int blk, f32x4 acc1[][NT], f32x4 acc2[][NT])
{
  const int l15 = lane & 15, kq = (lane >> 4) & 3;
#pragma unroll
  for (int kb = 0; kb < 4; ++kb) {
    const int ko2 = (kb*32 + kq*8)*2;
    f16x8 Bh_[NT], Bl_[NT];
#pragma unroll
    for (int n = 0; n < NT; ++n) {
      int brow = (n0+n)*16 + l15;
      int boff = (brow*256 + ko2) ^ ((brow&7)<<4);   // weights: std swizzle
      Bh_[n] = *(const f16x8*)(gwH + boff);
      Bl_[n] = *(const f16x8*)(gwL + boff);
    }
#pragma unroll
    for (int m = 0; m < MT; ++m) {
      const int rr = (m0+m)*16 + l15;
      int row, f;
      if (MODE == 0)      { row = rr; f = rr & 7; }
      else if (MODE == 2) { int s = rr>>2; int w = base3(rr&3) + base3(blk);
                            row = s*9 + w; f = ((s&3)<<1) | (w&1); }
      else                { row = rr*4 + blk; f = rr & 7; }
      const int aoff = (row*256 + ko2) ^ (f<<4);
      f16x8 Ah = *(const f16x8*)(AHb + aoff);
      f16x8 Al = *(const f16x8*)(ALb + aoff);
#pragma unroll
      for (int n = 0; n < NT; ++n) {
        acc1[m][n] = MFMA(Ah, Bh_[n], acc1[m][n]);
        acc2[m][n] = MFMA(Al, Bh_[n], acc2[m][n]);
        acc2[m][n] = MFMA(Ah, Bl_[n], acc2[m][n]);
      }
    }
  }
}

// GEN 0: f=row&7; GEN 2: f=((s&3)<<1)|(w&1) (row=9s+w, s=(row*57)>>9 exact
// for row<144); GEN 4: f=(row>>2)&7.
template<int GEN>
__device__ __forceinline__ void wbvalG(char* ah, char* al, int row, int col, float v) {
  _Float16 h = (_Float16)v;
  _Float16 l = (_Float16)((v - (float)h) * LO_SCALE);
  int f;
  if (GEN == 0)      f = row & 7;
  else if (GEN == 2) { int s = (row*57)>>9; int w = row - s*9; f = ((s&3)<<1) | (w&1); }
  else               f = (row >> 2) & 7;
  int sb = (row*256 + col*2) ^ (f<<4);
  *(_Float16*)(ah + sb) = h;
  *(_Float16*)(al + sb) = l;
}

template<int MT, int NT, int GEN>
__device__ __forceinline__ void writeback(char* AHb, char* ALb,
    const float* __restrict__ biasG,
    int layer, int m0, int n0, int lane, f32x4 acc1[][NT], f32x4 acc2[][NT])
{
  const int l15 = lane & 15, rq = (lane >> 4) & 3;
#pragma unroll
  for (int m = 0; m < MT; ++m)
#pragma unroll
    for (int n = 0; n < NT; ++n) {
      int col = (n0+n)*16 + l15;
      float bb = biasG[layer*128 + col];
#pragma unroll
      for (int q = 0; q < 4; ++q) {
        int row = (m0+m)*16 + rq*4 + q;
        float v = acc1[m][n][q] + acc2[m][n][q]*LO_INV + bb;
        v = fmaxf(v, 0.f);
        wbvalG<GEN>(AHb, ALb, row, col, v);
      }
    }
}

__global__ __launch_bounds__(512, 2)
void conv_mfma(
    const float* __restrict__ x, const char* __restrict__ wsb,
    signed char* __restrict__ feat, int B, int wgPerChunk)
{
  extern __shared__ char lds[];
  char* AHb = lds + AH_OFF;
  char* ALb = lds + AL_OFF;

  const int tid  = threadIdx.x;
  const int lane = tid & 63;
  const int wave = tid >> 6;
  const int mslot = wave >> 2;          // 0-1
  const int nslot = wave & 3;           // 0-3

  const int wg = blockIdx.x;
  const int chunkG = wg / wgPerChunk;
  const int b0 = (wg - chunkG*wgPerChunk) * 16;
  const int g = (chunkG < 4) ? 0 : (chunkG < 12) ? 1 : 2;
  const char* gw = wsb + g*G_STRIDE;
  const float* biasG = (const float*)(gw + GBIAS);

  // ---- prologue: stage input patch into LDS ----
  {
    int s = tid >> 5, v = tid & 31;
    int ic = v >> 4, pos = v & 15;
    int i = pos >> 2, j = pos & 3;
    int tt = CH_T[chunkG], kk = CH_K[chunkG];
    int a = tt ? j : i, bb2 = tt ? i : j;
    int py, px;
    if      (kk == 0) { py = a;     px = bb2;   }
    else if (kk == 1) { py = bb2;   px = 3-a;   }
    else if (kk == 2) { py = 3-a;   px = 3-bb2; }
    else              { py = 3-bb2; px = a;     }
    int sy = CH_Y0[chunkG] + py, sx = CH_X0[chunkG] + px;
    ((float*)(lds+XIN_OFF))[s*32 + v] = x[((b0+s)*2 + ic)*49 + sy*7 + sx];
  }
  __syncthreads();                              // BAR A: XIN ready

  // ---- conv0 (VALU, K=8), weights/bias from global, writes gen0 ----
  {
    const float* xin = (const float*)(lds+XIN_OFF);
    const float* w0s = (const float*)(gw + GW0);
    int c = tid & 127;
    float wr[8];
#pragma unroll
    for (int k = 0; k < 8; ++k) wr[k] = w0s[k*128 + c];
    float b0c = biasG[c];
    int sg = tid >> 7;
#pragma unroll
    for (int si = 0; si < 4; ++si) {
      int s = sg*4 + si;
      float xv[32];
#pragma unroll
      for (int t2 = 0; t2 < 32; ++t2) xv[t2] = xin[s*32 + t2];
#pragma unroll
      for (int oy = 0; oy < 3; ++oy)
#pragma unroll
        for (int ox = 0; ox < 3; ++ox) {
          float acc0 = b0c;
#pragma unroll
          for (int ic2 = 0; ic2 < 2; ++ic2)
#pragma unroll
            for (int dy = 0; dy < 2; ++dy)
#pragma unroll
              for (int dx = 0; dx < 2; ++dx)
                acc0 = fmaf(xv[ic2*16 + (oy+dy)*4 + ox+dx], wr[ic2*4+dy*2+dx], acc0);
          wbvalG<0>(AHb, ALb, s*9 + oy*3 + ox, c, fmaxf(acc0, 0.f));
        }
    }
  }
  __syncthreads();                              // BAR B: gen0 ready

  // ---- conv1: reads gen0 (MODE 0), writes gen1 (GEN 2) ----
  {
    {
      f32x4 a1[4][2] = {}; f32x4 a2[4][2] = {};
      phaseF<4,2,0>(AHb, ALb, gw+GW1, gw+GW1+32768, mslot*4, nslot*2, lane, 0, a1, a2);
      __syncthreads();                          // BAR C: p0 reads done
      writeback<4,2,2>(AHb, ALb, biasG, 1, mslot*4, nslot*2, lane, a1, a2);
    }
    {
      // p1 reads gen0 rows 128-143 — disjoint from p0's WB rows 0-127
      f32x4 a1[1][1] = {}; f32x4 a2[1][1] = {};
      phaseF<1,1,0>(AHb, ALb, gw+GW1, gw+GW1+32768, 8, wave, lane, 0, a1, a2);
      __syncthreads();                          // BAR D: p1 reads + p0 WB done
      writeback<1,1,2>(AHb, ALb, biasG, 1, 8, wave, lane, a1, a2);
    }
  }
  __syncthreads();                              // BAR E: gen1 complete

  // ---- conv2: gathers gen1 (MODE 2), 4 blocks barrier-free, writes gen2 ----
  {
    f32x4 a1[2][2] = {}; f32x4 a2[2][2] = {};
#pragma unroll
    for (int blk = 0; blk < 4; ++blk)
      phaseF<2,2,2>(AHb, ALb, gw+GW2+blk*65536, gw+GW2+blk*65536+32768,
                    mslot*2, nslot*2, lane, blk, a1, a2);
    __syncthreads();                            // BAR F: all conv2 reads done
    writeback<2,2,0>(AHb, ALb, biasG, 2, mslot*2, nslot*2, lane, a1, a2);
  }
  __syncthreads();                              // BAR G: gen2 ready

  // ---- conv3: reads gen2 (MODE 0), writes gen3 (GEN 4) ----
  {
    f32x4 a1[2][2] = {}; f32x4 a2[2][2] = {};
    phaseF<2,2,0>(AHb, ALb, gw+GW3, gw+GW3+32768, mslot*2, nslot*2, lane, 0, a1, a2);
    __syncthreads();                            // BAR H: conv3 reads done
    writeback<2,2,4>(AHb, ALb, biasG, 3, mslot*2, nslot*2, lane, a1, a2);
  }
  __syncthreads();                              // BAR I: gen3 ready

  // ---- conv4: gathers gen3 (MODE 4), 4 blocks barrier-free, writes gen4 ----
  {
    f32x4 a1[1][1] = {}; f32x4 a2[1][1] = {};
#pragma unroll
    for (int blk = 0; blk < 4; ++blk)
      phaseF<1,1,4>(AHb, ALb, gw+GW4+blk*65536, gw+GW4+blk*65536+32768,
                    0, wave, lane, blk, a1, a2);
    __syncthreads();                            // BAR J: conv4 reads done
    writeback<1,1,0>(AHb, ALb, biasG, 4, 0, wave, lane, a1, a2);
  }
  __syncthreads();                              // BAR K: gen4 ready

  // ---- conv5: reads gen4 (MODE 0), quantize features (waves 0,1 only) ----
  if (wave < 2) {
    f32x4 a1[1][1] = {}; f32x4 a2[1][1] = {};
    phaseF<1,1,0>(AHb, ALb, gw+GW5, gw+GW5+8192, 0, wave, lane, 0, a1, a2);
    int c = wave*16 + (lane & 15);
    float bb = biasG[5*128 + c];
#pragma unroll
    for (int q = 0; q < 4; ++q) {
      int s = ((lane >> 4) & 3)*4 + q;
      float f = a1[0][0][q] + a2[0][0][q]*LO_INV + bb;
      f = fminf(fmaxf(f, -1.0f), 127.0f/128.0f);
      int qi = clampi((int)rintf(f * 128.0f), -128, 127);
      feat[((long)chunkG*B + b0 + s)*32 + c] = (signed char)qi;
    }
  }
}

// ---------------------------------------------------------------------------
// value MLP: exact integer arithmetic (unchanged, verified round 1)
// ---------------------------------------------------------------------------
__global__ __launch_bounds__(256) void mlp_kernel(
    const signed char* __restrict__ feat,
    const int* __restrict__ mw,
    float* __restrict__ out, int B)
{
  int b = blockIdx.x * blockDim.x + threadIdx.x;
  if (b >= B) return;
  int S[32];
#pragma unroll
  for (int c = 0; c < 32; ++c) S[c] = 0;
  for (int ch = 0; ch < 16; ++ch) {
    const signed char* f = feat + ((long)ch*B + b)*32;
#pragma unroll
    for (int c = 0; c < 32; ++c) S[c] += f[c];
  }
  int x1[32];
#pragma unroll
  for (int c = 0; c < 32; ++c) x1[c] = clampi(S[c], -128, 127);

  const int* wq0 = mw;        const int* bq0 = mw + 1024;
  const int* wq1 = mw + 1056; const int* bq1 = mw + 2080;
  const int* wq2 = mw + 2112; const int* bq2 = mw + 2208;

  int x2[32];
#pragma unroll
  for (int o = 0; o < 32; ++o) {
    int acc = bq0[o];
    for (int i = 0; i < 32; ++i) acc += x1[i] * wq0[o*32 + i];
    acc = clampi(acc, 0, 32512);
    int r = acc >> 8, fr = acc & 255;
    r += (fr > 128 || (fr == 128 && (r & 1))) ? 1 : 0;
    x2[o] = r;
  }
  int x3[32];
#pragma unroll
  for (int o = 0; o < 32; ++o) {
    int acc = bq1[o];
    for (int i = 0; i < 32; ++i) acc += x2[i] * wq1[o*32 + i];
    acc = clampi(acc, 0, 16256);
    int r = acc >> 7, fr = acc & 127;
    r += (fr > 64 || (fr == 64 && (r & 1))) ? 1 : 0;
    x3[o] = r;
  }
  for (int o = 0; o < 3; ++o) {
    int acc = bq2[o];
    for (int i = 0; i < 32; ++i) acc += x3[i] * wq2[o*32 + i];
    out[b*3 + o] = (float)acc / 16384.0f;
  }
}

__global__ void zero_kernel(float4* __restrict__ p, int n4) {
  int i = blockIdx.x * blockDim.x + threadIdx.x;
  if (i < n4) p[i] = make_float4(0.f, 0.f, 0.f, 0.f);
}

// ---------------------------------------------------------------------------
extern "C" void kernel_launch(void* const* d_in, const int* in_sizes, int n_in,
                              void* d_out, int out_size, void* d_ws, size_t ws_size,
                              hipStream_t stream)
{
  const float* x   = (const float*)d_in[0];
  const float* w0  = (const float*)d_in[1];
  const float* b0  = (const float*)d_in[2];
  const float* w1  = (const float*)d_in[3];
  const float* b1  = (const float*)d_in[4];
  const float* w2  = (const float*)d_in[5];
  const float* b2  = (const float*)d_in[6];
  const float* w3  = (const float*)d_in[7];
  const float* b3  = (const float*)d_in[8];
  const float* w4  = (const float*)d_in[9];
  const float* b4  = (const float*)d_in[10];
  const float* w5  = (const float*)d_in[11];
  const float* b5  = (const float*)d_in[12];
  const float* bn1 = (const float*)d_in[13];
  const float* bn2 = (const float*)d_in[14];
  const float* bn3 = (const float*)d_in[15];
  const float* bn4 = (const float*)d_in[16];
  const float* bn5 = (const float*)d_in[17];
  const float* vw0 = (const float*)d_in[18];
  const float* vb0 = (const float*)d_in[19];
  const float* vw1 = (const float*)d_in[20];
  const float* vb1 = (const float*)d_in[21];
  const float* vw2 = (const float*)d_in[22];
  const float* vb2 = (const float*)d_in[23];

  const int B = in_sizes[0] / 98;
  float* ws = (float*)d_ws;
  signed char* feat = (signed char*)d_ws + FEAT_OFF_BYTES;
  float* out = (float*)d_out;

  (void)hipFuncSetAttribute((const void*)conv_mfma,
                            hipFuncAttributeMaxDynamicSharedMemorySize, LDS_TOTAL);

  prep_kernel<<<(511395 + 255)/256, 256, 0, stream>>>(
      w0,b0,w1,b1,w2,b2,w3,b3,w4,b4,w5,b5,
      bn1,bn2,bn3,bn4,bn5, vw0,vb0,vw1,vb1,vw2,vb2, ws);

  conv_mfma<<<B, 512, LDS_TOTAL, stream>>>(
      x, (const char*)d_ws, feat, B, B/16);

  mlp_kernel<<<(B + 255)/256, 256, 0, stream>>>(feat, (const int*)d_ws + MLP_WORD_OFF, out, B);

  {
    int n4 = B*49/4;
    zero_kernel<<<(n4 + 255)/256, 256, 0, stream>>>((float4*)(out + 3*B), n4);
  }
}